// Round 4
// baseline (3150.827 us; speedup 1.0000x reference)
//
#include <hip/hip_runtime.h>
#include <hip/hip_bf16.h>
#include <math.h>

#define NN 65536
#define NE 1048576
#define NB 64
#define HD 128
#define NL 3

// ---- workspace layout (float offsets) ----
#define O_CSUM   0           // 64*3
#define O_CCNT   192         // 64
#define O_LCNT   256         // 64
#define O_GSUM   320         // 64*128 -> ends 8512
#define O_DEGI   8512        // 65536 ints -> ends 74048
#define O_POSREL 74048       // 65536*3 -> ends 270656
#define O_RC     270656      // 1048576 u32 (row<<16|col, sorted by row) -> ends 1319232
#define O_X      1319232     // 65536*128  (rowStart/cnt alias its head pre-init)
#define O_P      9707840     // 65536*128
#define O_Q      18096448    // 65536*128
#define O_MSUM   26485056    // 65536*128 -> ends 34873664
#define O_W2T    34873664    // 3*128*128 bf16 = 49152 ushort = 24576 float slots -> ends 34898240 (~139.6 MB)

typedef __attribute__((ext_vector_type(8))) short bf16x8;
typedef __attribute__((ext_vector_type(4))) float f32x4;

__device__ __forceinline__ void atomAdd(float* p, float v) {
    unsafeAtomicAdd(p, v);   // native global_atomic_add_f32 on gfx950
}

__device__ __forceinline__ unsigned short f2bf(float f) {
    union { __hip_bfloat16 h; unsigned short u; } cv;
    cv.h = __float2bfloat16(f);
    return cv.u;
}

// ---------------- stats: per-graph centroid sums, node counts, ligand counts --------------
__global__ __launch_bounds__(256) void stats_kernel(
    const float* __restrict__ pos, const int* __restrict__ batch,
    const int* __restrict__ ntype,
    float* __restrict__ csum, float* __restrict__ ccnt, float* __restrict__ lcnt)
{
    __shared__ float s[NB * 5];
    const int tid = threadIdx.x;
    for (int i = tid; i < NB * 5; i += 256) s[i] = 0.f;
    __syncthreads();
    const int n = blockIdx.x * 256 + tid;
    const int b = batch[n];
    atomicAdd(&s[b*5+0], pos[n*3+0]);
    atomicAdd(&s[b*5+1], pos[n*3+1]);
    atomicAdd(&s[b*5+2], pos[n*3+2]);
    atomicAdd(&s[b*5+3], 1.f);
    if (ntype[n] == 1) atomicAdd(&s[b*5+4], 1.f);
    __syncthreads();
    for (int i = tid; i < NB * 5; i += 256) {
        float v = s[i];
        if (v != 0.f) {
            int b2 = i / 5, f = i - b2*5;
            if (f < 3)       atomAdd(&csum[b2*3+f], v);
            else if (f == 3) atomAdd(&ccnt[b2], v);
            else             atomAdd(&lcnt[b2], v);
        }
    }
}

// ---------------- integer degree histogram of `row` ----------------
__global__ __launch_bounds__(256) void deg_kernel(const int* __restrict__ row, int* __restrict__ degi)
{
    const int e = blockIdx.x * 256 + threadIdx.x;
    atomicAdd(&degi[row[e]], 1);
}

// ---------------- single-block exclusive scan of degi[65536] -> rowStart ----------------
__global__ __launch_bounds__(1024) void scan_kernel(const int* __restrict__ degi, int* __restrict__ rowStart)
{
    __shared__ int s[1024];
    __shared__ int carry;
    const int tid = threadIdx.x;
    if (tid == 0) carry = 0;
    __syncthreads();
    for (int c = 0; c < NN / 1024; ++c) {
        const int v = degi[c*1024 + tid];
        s[tid] = v;
        __syncthreads();
        for (int off = 1; off < 1024; off <<= 1) {
            int t = (tid >= off) ? s[tid - off] : 0;
            __syncthreads();
            s[tid] += t;
            __syncthreads();
        }
        rowStart[c*1024 + tid] = carry + s[tid] - v;   // exclusive
        __syncthreads();
        if (tid == 1023) carry += s[1023];
        __syncthreads();
    }
}

// ---------------- counting-sort scatter: rcS[p] = (row<<16)|col, sorted by row --------------
__global__ __launch_bounds__(256) void scatter_kernel(
    const int* __restrict__ row, const int* __restrict__ col,
    const int* __restrict__ rowStart, int* __restrict__ cnt,
    unsigned int* __restrict__ rcS)
{
    const int e = blockIdx.x * 256 + threadIdx.x;
    const int r = row[e], c = col[e];
    const int p = rowStart[r] + atomicAdd(&cnt[r], 1);
    rcS[p] = ((unsigned)r << 16) | (unsigned)c;
}

// ---------------- pos_rel = pos - center[batch] ----------------
__global__ __launch_bounds__(256) void posrel_kernel(
    const float* __restrict__ pos, const int* __restrict__ batch,
    const float* __restrict__ csum, const float* __restrict__ ccnt,
    float* __restrict__ posrel)
{
    const int n = blockIdx.x * 256 + threadIdx.x;
    const int b = batch[n];
    const float inv = 1.f / fmaxf(ccnt[b], 1.f);
    posrel[n*3+0] = pos[n*3+0] - csum[b*3+0]*inv;
    posrel[n*3+1] = pos[n*3+1] - csum[b*3+1]*inv;
    posrel[n*3+2] = pos[n*3+2] - csum[b*3+2]*inv;
}

// ---------------- W2 -> transposed bf16: w2t[l][n][k] = bf16(W2_l[k][n]) ----------------
__global__ __launch_bounds__(256) void w2bf_kernel(const float* __restrict__ mw2,
                                                   unsigned short* __restrict__ w2t)
{
    const int idx = blockIdx.x * 256 + threadIdx.x;   // 49152 total
    const int l = idx >> 14, rem = idx & 16383, n = rem >> 7, k = rem & 127;
    w2t[idx] = f2bf(mw2[(l << 14) + k*128 + n]);
}

// ---------------- generic node-level GEMM: out[N,128] = A[N,K] @ W[K,128] (+bias)(+relu) ----
template<int AMODE, int K, bool RELU>
__global__ __launch_bounds__(256) void node_gemm(
    const float* __restrict__ A0, const float* __restrict__ A1,
    const int* __restrict__ Adeg, const int* __restrict__ zidx,
    const float* __restrict__ W, const float* __restrict__ bias,
    float* __restrict__ out)
{
    constexpr int KP = (K % 4) ? (K + 4 - (K % 4)) : K;
    __shared__ __align__(16) float Asm[32][KP];
    __shared__ __align__(16) float Wsm[32][128];
    const int tid = threadIdx.x;
    const int n0  = blockIdx.x * 32;
    const float4* __restrict__ A0f4 = (const float4*)A0;

    if constexpr (AMODE == 0) {
        for (int idx4 = tid; idx4 < 1024; idx4 += 256) {
            int i = idx4 >> 5, k4 = idx4 & 31;
            int zz = zidx[n0 + i];
            *(float4*)&Asm[i][k4*4] = A0f4[zz*32 + k4];   // emb row
        }
        if (tid < 96) { int i = tid / 3, d = tid - i*3; Asm[i][128+d] = A1[(n0+i)*3 + d]; }
        else if (tid < 128) { Asm[tid-96][131] = 0.f; }
    } else if constexpr (AMODE == 1) {
        for (int idx4 = tid; idx4 < 1024; idx4 += 256) {
            int i = idx4 >> 5, k4 = idx4 & 31;
            *(float4*)&Asm[i][k4*4] = A0f4[(n0+i)*32 + k4];
        }
    } else {
        const float4* __restrict__ A1f4 = (const float4*)A1;
        for (int idx4 = tid; idx4 < 1024; idx4 += 256) {
            int i = idx4 >> 5, k4 = idx4 & 31;
            *(float4*)&Asm[i][k4*4] = A0f4[(n0+i)*32 + k4];
            float inv = 1.f / fmaxf((float)Adeg[n0+i], 1.f);
            float4 m = A1f4[(n0+i)*32 + k4];
            m.x *= inv; m.y *= inv; m.z *= inv; m.w *= inv;
            *(float4*)&Asm[i][128 + k4*4] = m;
        }
    }

    const int tj = tid & 31;
    const int tn = tid >> 5;
    float acc[4][4];
    #pragma unroll
    for (int r = 0; r < 4; ++r)
        #pragma unroll
        for (int c = 0; c < 4; ++c) acc[r][c] = 0.f;

    const float4* __restrict__ Wf4 = (const float4*)W;
    #pragma unroll 1
    for (int kc = 0; kc < K; kc += 32) {
        const int kend = (K - kc < 32) ? (K - kc) : 32;
        __syncthreads();
        for (int idx4 = tid; idx4 < kend*32; idx4 += 256) {
            int kk = idx4 >> 5, j4 = idx4 & 31;
            *(float4*)&Wsm[kk][j4*4] = Wf4[(kc+kk)*32 + j4];
        }
        __syncthreads();
        for (int kk = 0; kk < kend; ++kk) {
            const float4 w = *(const float4*)&Wsm[kk][tj*4];
            const float a0 = Asm[tn*4+0][kc+kk];
            const float a1 = Asm[tn*4+1][kc+kk];
            const float a2 = Asm[tn*4+2][kc+kk];
            const float a3 = Asm[tn*4+3][kc+kk];
            acc[0][0] += a0*w.x; acc[0][1] += a0*w.y; acc[0][2] += a0*w.z; acc[0][3] += a0*w.w;
            acc[1][0] += a1*w.x; acc[1][1] += a1*w.y; acc[1][2] += a1*w.z; acc[1][3] += a1*w.w;
            acc[2][0] += a2*w.x; acc[2][1] += a2*w.y; acc[2][2] += a2*w.z; acc[2][3] += a2*w.w;
            acc[3][0] += a3*w.x; acc[3][1] += a3*w.y; acc[3][2] += a3*w.z; acc[3][3] += a3*w.w;
        }
    }

    float4 bias4 = make_float4(0.f, 0.f, 0.f, 0.f);
    if (bias) bias4 = ((const float4*)bias)[tj];
    #pragma unroll
    for (int r = 0; r < 4; ++r) {
        const int node = n0 + tn*4 + r;
        float4 o;
        o.x = acc[r][0] + bias4.x;
        o.y = acc[r][1] + bias4.y;
        o.z = acc[r][2] + bias4.z;
        o.w = acc[r][3] + bias4.w;
        if (RELU) {
            o.x = fmaxf(o.x, 0.f); o.y = fmaxf(o.y, 0.f);
            o.z = fmaxf(o.z, 0.f); o.w = fmaxf(o.w, 0.f);
        }
        ((float4*)out)[node*32 + tj] = o;
    }
}

// ---------------- fused edge kernel over ROW-SORTED edges, MFMA phase 2 ----------------
// h = relu(P[col]+Q[row]+dist*w1c+b1)  [fp32 -> bf16 LDS]
// m = relu(h@W2+b2)                    [bf16 MFMA, fp32 acc]
// msum[row] += m                       [LDS row-buckets -> global atomics]
__global__ __launch_bounds__(256) void edge_msg_kernel(
    const float* __restrict__ P, const float* __restrict__ Q,
    const float* __restrict__ posrel,
    const unsigned int* __restrict__ rcS,
    const float* __restrict__ w1c, const float* __restrict__ b1,
    const unsigned short* __restrict__ w2t,   // [128 n][128 k] bf16 (transposed)
    const float* __restrict__ b2,
    float* __restrict__ msum)
{
    __shared__ __align__(16) unsigned short Hs[64][136];    // bf16 H, pad 136 (2-way banks)
    __shared__ __align__(16) unsigned short W2Ts[128][72];  // bf16 W2T K-half, pad 72
    __shared__ __align__(16) float Macc[16][128];           // row buckets
    __shared__ __align__(16) float c1s[HD], b1s[HD], b2s[HD];
    __shared__ float dists[64];
    __shared__ int rows_s[64], cols_s[64], rid_s[64], bucketRow_s[64];
    __shared__ int nR_s;

    const int tid = threadIdx.x;
    const long e0 = (long)blockIdx.x * 64;

    // ---- setup (disjoint thread groups) ----
    if (tid < 128) {
        c1s[tid] = w1c[tid]; b1s[tid] = b1[tid]; b2s[tid] = b2[tid];
    } else if (tid < 192) {
        const int lane = tid - 128;            // wave 2, lanes 0..63
        const unsigned rc = rcS[e0 + lane];
        const int r = (int)(rc >> 16), c = (int)(rc & 0xffffu);
        rows_s[lane] = r; cols_s[lane] = c;
        const float dx = posrel[c*3+0] - posrel[r*3+0];
        const float dy = posrel[c*3+1] - posrel[r*3+1];
        const float dz = posrel[c*3+2] - posrel[r*3+2];
        dists[lane] = sqrtf(dx*dx + dy*dy + dz*dz);
        // distinct-row index via wave prefix sum over sorted rows
        const int prev = __shfl_up(r, 1, 64);
        int bsum = (lane > 0 && r != prev) ? 1 : 0;
        #pragma unroll
        for (int off = 1; off < 64; off <<= 1) {
            int u = __shfl_up(bsum, off, 64);
            if (lane >= off) bsum += u;
        }
        rid_s[lane] = bsum;
        bucketRow_s[bsum] = r;
        if (lane == 63) nR_s = bsum + 1;
    } else {
        for (int i = tid - 192; i < 2048; i += 64) ((float*)Macc)[i] = 0.f;
    }
    __syncthreads();   // S0

    const int j4 = tid & 31;   // float4 column group (phase 1)
    const int eg = tid >> 5;   // 0..7

    // ---- phase 1: H tile (fp32 math, bf16 store) ----
    {
        const float4 c14 = *(const float4*)&c1s[j4*4];
        const float4 b14 = *(const float4*)&b1s[j4*4];
        #pragma unroll
        for (int i = 0; i < 8; ++i) {
            const int e = eg*8 + i;
            const int c = cols_s[e], r = rows_s[e];
            const float4 p4 = ((const float4*)P)[c*32 + j4];
            const float4 q4 = ((const float4*)Q)[r*32 + j4];
            const float d = dists[e];
            ushort4 hb;
            hb.x = f2bf(fmaxf(p4.x + q4.x + d*c14.x + b14.x, 0.f));
            hb.y = f2bf(fmaxf(p4.y + q4.y + d*c14.y + b14.y, 0.f));
            hb.z = f2bf(fmaxf(p4.z + q4.z + d*c14.z + b14.z, 0.f));
            hb.w = f2bf(fmaxf(p4.w + q4.w + d*c14.w + b14.w, 0.f));
            *(ushort4*)&Hs[e][j4*4] = hb;
        }
    }
    // ---- stage W2T K-half 0 (k in [0,64)) ----
    {
        #pragma unroll
        for (int it = 0; it < 4; ++it) {
            const int idx8 = tid + it*256;         // 1024 ushort8 chunks
            const int n = idx8 >> 3, cch = idx8 & 7;
            *(ulonglong2*)&W2Ts[n][cch*8] = *(const ulonglong2*)&w2t[n*128 + cch*8];
        }
    }
    __syncthreads();   // S1

    const int l  = tid & 63;   // lane in wave
    const int w  = tid >> 6;   // wave id = edge-tile
    const int mr = l & 15;
    const int qd = l >> 4;

    f32x4 acc[8];
    #pragma unroll
    for (int t = 0; t < 8; ++t) acc[t] = (f32x4){0.f, 0.f, 0.f, 0.f};

    // ---- MFMA, K-half 0 ----
    {
        bf16x8 a0 = *(const bf16x8*)&Hs[w*16 + mr][ 0 + qd*8];
        bf16x8 a1 = *(const bf16x8*)&Hs[w*16 + mr][32 + qd*8];
        #pragma unroll
        for (int t = 0; t < 8; ++t) {
            bf16x8 bb0 = *(const bf16x8*)&W2Ts[t*16 + mr][ 0 + qd*8];
            bf16x8 bb1 = *(const bf16x8*)&W2Ts[t*16 + mr][32 + qd*8];
            acc[t] = __builtin_amdgcn_mfma_f32_16x16x32_bf16(a0, bb0, acc[t], 0, 0, 0);
            acc[t] = __builtin_amdgcn_mfma_f32_16x16x32_bf16(a1, bb1, acc[t], 0, 0, 0);
        }
    }
    __syncthreads();   // S2
    // ---- stage W2T K-half 1 (k in [64,128)) ----
    {
        #pragma unroll
        for (int it = 0; it < 4; ++it) {
            const int idx8 = tid + it*256;
            const int n = idx8 >> 3, cch = idx8 & 7;
            *(ulonglong2*)&W2Ts[n][cch*8] = *(const ulonglong2*)&w2t[n*128 + 64 + cch*8];
        }
    }
    __syncthreads();   // S3
    // ---- MFMA, K-half 1 ----
    {
        bf16x8 a0 = *(const bf16x8*)&Hs[w*16 + mr][64 + qd*8];
        bf16x8 a1 = *(const bf16x8*)&Hs[w*16 + mr][96 + qd*8];
        #pragma unroll
        for (int t = 0; t < 8; ++t) {
            bf16x8 bb0 = *(const bf16x8*)&W2Ts[t*16 + mr][ 0 + qd*8];
            bf16x8 bb1 = *(const bf16x8*)&W2Ts[t*16 + mr][32 + qd*8];
            acc[t] = __builtin_amdgcn_mfma_f32_16x16x32_bf16(a0, bb0, acc[t], 0, 0, 0);
            acc[t] = __builtin_amdgcn_mfma_f32_16x16x32_bf16(a1, bb1, acc[t], 0, 0, 0);
        }
    }

    // ---- phase 3: bias+relu, accumulate into row buckets (C/D: col=lane&15, row=quad*4+reg)
    const int nR = nR_s;
    #pragma unroll
    for (int t = 0; t < 8; ++t) {
        const int colg = t*16 + mr;
        const float bb = b2s[colg];
        if (nR <= 16) {
            #pragma unroll
            for (int r = 0; r < 4; ++r) {
                const int e = w*16 + qd*4 + r;
                const float v = fmaxf(acc[t][r] + bb, 0.f);
                atomicAdd(&Macc[rid_s[e]][colg], v);
            }
        } else {
            #pragma unroll
            for (int r = 0; r < 4; ++r) {
                const int e = w*16 + qd*4 + r;
                const float v = fmaxf(acc[t][r] + bb, 0.f);
                atomAdd(&msum[(long)rows_s[e]*HD + colg], v);
            }
        }
    }
    __syncthreads();   // S4

    // ---- emit buckets ----
    if (nR <= 16) {
        for (int idx = tid; idx < nR*32; idx += 256) {
            const int bk = idx >> 5, j = idx & 31;
            const float4 v = *(const float4*)&Macc[bk][j*4];
            float* dst = &msum[(long)bucketRow_s[bk]*HD + j*4];
            atomAdd(dst+0, v.x); atomAdd(dst+1, v.y);
            atomAdd(dst+2, v.z); atomAdd(dst+3, v.w);
        }
    }
}

// ---------------- ligand-masked per-graph sum of x ----------------
__global__ __launch_bounds__(256) void gsum_kernel(
    const float* __restrict__ x, const int* __restrict__ batch,
    const int* __restrict__ ntype, float* __restrict__ gsum)
{
    const int idx = blockIdx.x * 256 + threadIdx.x;
    const int n = idx >> 5, k4 = idx & 31;
    if (ntype[n] != 1) return;
    const int b = batch[n];
    const float4 v = ((const float4*)x)[n*32 + k4];
    float* dst = &gsum[b*HD + k4*4];
    atomAdd(dst+0, v.x); atomAdd(dst+1, v.y);
    atomAdd(dst+2, v.z); atomAdd(dst+3, v.w);
}

// ---------------- readout: hg = relu(g@ro_w1+b1); out = hg@ro_w2 + b2 ----------------
__global__ __launch_bounds__(128) void readout_kernel(
    const float* __restrict__ gsum, const float* __restrict__ lcnt,
    const float* __restrict__ w1, const float* __restrict__ b1,
    const float* __restrict__ w2, const float* __restrict__ b2,
    float* __restrict__ out)
{
    __shared__ float gs[HD];
    __shared__ float red[2];
    const int b = blockIdx.x, j = threadIdx.x;
    gs[j] = gsum[b*HD + j] / fmaxf(lcnt[b], 1.f);
    __syncthreads();
    float acc = b1[j];
    for (int k = 0; k < HD; ++k) acc += gs[k]*w1[k*HD + j];
    float hg = fmaxf(acc, 0.f) * w2[j];
    #pragma unroll
    for (int off = 32; off > 0; off >>= 1) hg += __shfl_down(hg, off, 64);
    if ((j & 63) == 0) red[j >> 6] = hg;
    __syncthreads();
    if (j == 0) out[b] = red[0] + red[1] + b2[0];
}

extern "C" void kernel_launch(void* const* d_in, const int* in_sizes, int n_in,
                              void* d_out, int out_size, void* d_ws, size_t ws_size,
                              hipStream_t stream)
{
    const float* pos   = (const float*)d_in[0];
    const int*   z     = (const int*)d_in[1];
    const int*   batch = (const int*)d_in[2];
    const int*   eidx  = (const int*)d_in[3];
    const int*   ntype = (const int*)d_in[4];
    const float* emb   = (const float*)d_in[5];
    const float* lin_w = (const float*)d_in[6];
    const float* lin_b = (const float*)d_in[7];
    const float* mw1   = (const float*)d_in[8];
    const float* mb1   = (const float*)d_in[9];
    const float* mw2   = (const float*)d_in[10];
    const float* mb2   = (const float*)d_in[11];
    const float* uw    = (const float*)d_in[12];
    const float* ub    = (const float*)d_in[13];
    const float* rw1   = (const float*)d_in[14];
    const float* rb1   = (const float*)d_in[15];
    const float* rw2   = (const float*)d_in[16];
    const float* rb2   = (const float*)d_in[17];

    const int* row = eidx;        // edge_index[0]
    const int* col = eidx + NE;   // edge_index[1]

    float* ws     = (float*)d_ws;
    float* csum   = ws + O_CSUM;
    float* ccnt   = ws + O_CCNT;
    float* lcnt   = ws + O_LCNT;
    float* gsum   = ws + O_GSUM;
    int*   degi   = (int*)(ws + O_DEGI);
    float* posrel = ws + O_POSREL;
    unsigned int* rcS = (unsigned int*)(ws + O_RC);
    float* x      = ws + O_X;
    float* Pb     = ws + O_P;
    float* Qb     = ws + O_Q;
    float* msum   = ws + O_MSUM;
    unsigned short* w2t = (unsigned short*)(ws + O_W2T);
    int* rowStart = (int*)x;
    int* cnt      = (int*)x + NN;

    (void)hipMemsetAsync(ws, 0, (size_t)(O_DEGI + NN) * sizeof(float), stream);
    (void)hipMemsetAsync(cnt, 0, (size_t)NN * sizeof(int), stream);

    stats_kernel  <<<NN/256, 256, 0, stream>>>(pos, batch, ntype, csum, ccnt, lcnt);
    deg_kernel    <<<NE/256, 256, 0, stream>>>(row, degi);
    posrel_kernel <<<NN/256, 256, 0, stream>>>(pos, batch, csum, ccnt, posrel);
    scan_kernel   <<<1, 1024, 0, stream>>>(degi, rowStart);
    scatter_kernel<<<NE/256, 256, 0, stream>>>(row, col, rowStart, cnt, rcS);
    w2bf_kernel   <<<192, 256, 0, stream>>>(mw2, w2t);

    node_gemm<0, 131, false><<<NN/32, 256, 0, stream>>>(emb, posrel, nullptr, z, lin_w, lin_b, x);

    for (int l = 0; l < NL; ++l) {
        const float* W1 = mw1 + (size_t)l*257*HD;
        node_gemm<1, 128, false><<<NN/32, 256, 0, stream>>>(x, nullptr, nullptr, nullptr, W1, nullptr, Pb);
        node_gemm<1, 128, false><<<NN/32, 256, 0, stream>>>(x, nullptr, nullptr, nullptr, W1 + 128*HD, nullptr, Qb);
        (void)hipMemsetAsync(msum, 0, (size_t)NN*HD*sizeof(float), stream);
        edge_msg_kernel<<<NE/64, 256, 0, stream>>>(Pb, Qb, posrel, rcS,
                                                   W1 + 256*HD, mb1 + l*HD,
                                                   w2t + (size_t)l*16384, mb2 + l*HD, msum);
        node_gemm<2, 256, true><<<NN/32, 256, 0, stream>>>(x, msum, degi, nullptr,
                                                           uw + (size_t)l*256*HD, ub + l*HD, x);
    }

    gsum_kernel   <<<NN*32/256, 256, 0, stream>>>(x, batch, ntype, gsum);
    readout_kernel<<<NB, 128, 0, stream>>>(gsum, lcnt, rw1, rb1, rw2, rb2, (float*)d_out);
}

// Round 5
// 2100.410 us; speedup vs baseline: 1.5001x; 1.5001x over previous
//
#include <hip/hip_runtime.h>
#include <hip/hip_bf16.h>
#include <math.h>

#define NN 65536
#define NE 1048576
#define NB 64
#define HD 128
#define NL 3

// ---- workspace layout (float offsets) ----
#define O_CSUM   0           // 64*3
#define O_CCNT   192         // 64
#define O_LCNT   256         // 64
#define O_GSUM   320         // 64*128 -> ends 8512
#define O_DEGI   8512        // 65536 ints -> ends 74048
#define O_POSREL 74048       // 65536*3 -> ends 270656
#define O_RC     270656      // 1048576 u32 (row<<16|col, sorted by row) -> ends 1319232
#define O_X      1319232     // 65536*128  (rowStart/cnt alias its head pre-init)
#define O_P      9707840     // 65536*128
#define O_Q      18096448    // 65536*128
#define O_MSUM   26485056    // 65536*128 -> ends 34873664
#define O_W2T    34873664    // 3*128*128 bf16 -> ends 34898240 (~139.6 MB)

typedef __attribute__((ext_vector_type(8))) short bf16x8;
typedef __attribute__((ext_vector_type(4))) float f32x4;

__device__ __forceinline__ void atomAdd(float* p, float v) {
    unsafeAtomicAdd(p, v);   // native global_atomic_add_f32 on gfx950
}

__device__ __forceinline__ unsigned short f2bf(float f) {
    union { __hip_bfloat16 h; unsigned short u; } cv;
    cv.h = __float2bfloat16(f);
    return cv.u;
}

// ---------------- stats: per-graph centroid sums, node counts, ligand counts --------------
__global__ __launch_bounds__(256) void stats_kernel(
    const float* __restrict__ pos, const int* __restrict__ batch,
    const int* __restrict__ ntype,
    float* __restrict__ csum, float* __restrict__ ccnt, float* __restrict__ lcnt)
{
    __shared__ float s[NB * 5];
    const int tid = threadIdx.x;
    for (int i = tid; i < NB * 5; i += 256) s[i] = 0.f;
    __syncthreads();
    const int n = blockIdx.x * 256 + tid;
    const int b = batch[n];
    atomicAdd(&s[b*5+0], pos[n*3+0]);
    atomicAdd(&s[b*5+1], pos[n*3+1]);
    atomicAdd(&s[b*5+2], pos[n*3+2]);
    atomicAdd(&s[b*5+3], 1.f);
    if (ntype[n] == 1) atomicAdd(&s[b*5+4], 1.f);
    __syncthreads();
    for (int i = tid; i < NB * 5; i += 256) {
        float v = s[i];
        if (v != 0.f) {
            int b2 = i / 5, f = i - b2*5;
            if (f < 3)       atomAdd(&csum[b2*3+f], v);
            else if (f == 3) atomAdd(&ccnt[b2], v);
            else             atomAdd(&lcnt[b2], v);
        }
    }
}

// ---------------- integer degree histogram of `row` ----------------
__global__ __launch_bounds__(256) void deg_kernel(const int* __restrict__ row, int* __restrict__ degi)
{
    const int e = blockIdx.x * 256 + threadIdx.x;
    atomicAdd(&degi[row[e]], 1);
}

// ---------------- single-block exclusive scan of degi[65536] -> rowStart ----------------
__global__ __launch_bounds__(1024) void scan_kernel(const int* __restrict__ degi, int* __restrict__ rowStart)
{
    __shared__ int s[1024];
    __shared__ int carry;
    const int tid = threadIdx.x;
    if (tid == 0) carry = 0;
    __syncthreads();
    for (int c = 0; c < NN / 1024; ++c) {
        const int v = degi[c*1024 + tid];
        s[tid] = v;
        __syncthreads();
        for (int off = 1; off < 1024; off <<= 1) {
            int t = (tid >= off) ? s[tid - off] : 0;
            __syncthreads();
            s[tid] += t;
            __syncthreads();
        }
        rowStart[c*1024 + tid] = carry + s[tid] - v;   // exclusive
        __syncthreads();
        if (tid == 1023) carry += s[1023];
        __syncthreads();
    }
}

// ---------------- counting-sort scatter: rcS[p] = (row<<16)|col, sorted by row --------------
__global__ __launch_bounds__(256) void scatter_kernel(
    const int* __restrict__ row, const int* __restrict__ col,
    const int* __restrict__ rowStart, int* __restrict__ cnt,
    unsigned int* __restrict__ rcS)
{
    const int e = blockIdx.x * 256 + threadIdx.x;
    const int r = row[e], c = col[e];
    const int p = rowStart[r] + atomicAdd(&cnt[r], 1);
    rcS[p] = ((unsigned)r << 16) | (unsigned)c;
}

// ---------------- pos_rel = pos - center[batch] ----------------
__global__ __launch_bounds__(256) void posrel_kernel(
    const float* __restrict__ pos, const int* __restrict__ batch,
    const float* __restrict__ csum, const float* __restrict__ ccnt,
    float* __restrict__ posrel)
{
    const int n = blockIdx.x * 256 + threadIdx.x;
    const int b = batch[n];
    const float inv = 1.f / fmaxf(ccnt[b], 1.f);
    posrel[n*3+0] = pos[n*3+0] - csum[b*3+0]*inv;
    posrel[n*3+1] = pos[n*3+1] - csum[b*3+1]*inv;
    posrel[n*3+2] = pos[n*3+2] - csum[b*3+2]*inv;
}

// ---------------- W2 -> transposed bf16: w2t[l][n][k] = bf16(W2_l[k][n]) ----------------
__global__ __launch_bounds__(256) void w2bf_kernel(const float* __restrict__ mw2,
                                                   unsigned short* __restrict__ w2t)
{
    const int idx = blockIdx.x * 256 + threadIdx.x;   // 49152 total
    const int l = idx >> 14, rem = idx & 16383, n = rem >> 7, k = rem & 127;
    w2t[idx] = f2bf(mw2[(l << 14) + k*128 + n]);
}

// ---------------- generic node-level GEMM: out[N,128] = A[N,K] @ W[K,128] (+bias)(+relu) ----
template<int AMODE, int K, bool RELU>
__global__ __launch_bounds__(256) void node_gemm(
    const float* __restrict__ A0, const float* __restrict__ A1,
    const int* __restrict__ Adeg, const int* __restrict__ zidx,
    const float* __restrict__ W, const float* __restrict__ bias,
    float* __restrict__ out)
{
    constexpr int KP = (K % 4) ? (K + 4 - (K % 4)) : K;
    __shared__ __align__(16) float Asm[32][KP];
    __shared__ __align__(16) float Wsm[32][128];
    const int tid = threadIdx.x;
    const int n0  = blockIdx.x * 32;
    const float4* __restrict__ A0f4 = (const float4*)A0;

    if constexpr (AMODE == 0) {
        for (int idx4 = tid; idx4 < 1024; idx4 += 256) {
            int i = idx4 >> 5, k4 = idx4 & 31;
            int zz = zidx[n0 + i];
            *(float4*)&Asm[i][k4*4] = A0f4[zz*32 + k4];   // emb row
        }
        if (tid < 96) { int i = tid / 3, d = tid - i*3; Asm[i][128+d] = A1[(n0+i)*3 + d]; }
        else if (tid < 128) { Asm[tid-96][131] = 0.f; }
    } else if constexpr (AMODE == 1) {
        for (int idx4 = tid; idx4 < 1024; idx4 += 256) {
            int i = idx4 >> 5, k4 = idx4 & 31;
            *(float4*)&Asm[i][k4*4] = A0f4[(n0+i)*32 + k4];
        }
    } else {
        const float4* __restrict__ A1f4 = (const float4*)A1;
        for (int idx4 = tid; idx4 < 1024; idx4 += 256) {
            int i = idx4 >> 5, k4 = idx4 & 31;
            *(float4*)&Asm[i][k4*4] = A0f4[(n0+i)*32 + k4];
            float inv = 1.f / fmaxf((float)Adeg[n0+i], 1.f);
            float4 m = A1f4[(n0+i)*32 + k4];
            m.x *= inv; m.y *= inv; m.z *= inv; m.w *= inv;
            *(float4*)&Asm[i][128 + k4*4] = m;
        }
    }

    const int tj = tid & 31;
    const int tn = tid >> 5;
    float acc[4][4];
    #pragma unroll
    for (int r = 0; r < 4; ++r)
        #pragma unroll
        for (int c = 0; c < 4; ++c) acc[r][c] = 0.f;

    const float4* __restrict__ Wf4 = (const float4*)W;
    #pragma unroll 1
    for (int kc = 0; kc < K; kc += 32) {
        const int kend = (K - kc < 32) ? (K - kc) : 32;
        __syncthreads();
        for (int idx4 = tid; idx4 < kend*32; idx4 += 256) {
            int kk = idx4 >> 5, j4 = idx4 & 31;
            *(float4*)&Wsm[kk][j4*4] = Wf4[(kc+kk)*32 + j4];
        }
        __syncthreads();
        for (int kk = 0; kk < kend; ++kk) {
            const float4 w = *(const float4*)&Wsm[kk][tj*4];
            const float a0 = Asm[tn*4+0][kc+kk];
            const float a1 = Asm[tn*4+1][kc+kk];
            const float a2 = Asm[tn*4+2][kc+kk];
            const float a3 = Asm[tn*4+3][kc+kk];
            acc[0][0] += a0*w.x; acc[0][1] += a0*w.y; acc[0][2] += a0*w.z; acc[0][3] += a0*w.w;
            acc[1][0] += a1*w.x; acc[1][1] += a1*w.y; acc[1][2] += a1*w.z; acc[1][3] += a1*w.w;
            acc[2][0] += a2*w.x; acc[2][1] += a2*w.y; acc[2][2] += a2*w.z; acc[2][3] += a2*w.w;
            acc[3][0] += a3*w.x; acc[3][1] += a3*w.y; acc[3][2] += a3*w.z; acc[3][3] += a3*w.w;
        }
    }

    float4 bias4 = make_float4(0.f, 0.f, 0.f, 0.f);
    if (bias) bias4 = ((const float4*)bias)[tj];
    #pragma unroll
    for (int r = 0; r < 4; ++r) {
        const int node = n0 + tn*4 + r;
        float4 o;
        o.x = acc[r][0] + bias4.x;
        o.y = acc[r][1] + bias4.y;
        o.z = acc[r][2] + bias4.z;
        o.w = acc[r][3] + bias4.w;
        if (RELU) {
            o.x = fmaxf(o.x, 0.f); o.y = fmaxf(o.y, 0.f);
            o.z = fmaxf(o.z, 0.f); o.w = fmaxf(o.w, 0.f);
        }
        ((float4*)out)[node*32 + tj] = o;
    }
}

// ---------------- fused edge kernel over ROW-SORTED edges, MFMA phase 2 ----------------
// 256 edges/block, 4 waves x 64 edges. H built directly into A-fragments (no LDS).
// m = relu(h@W2+b2); msum[row] += m via register run-aggregation + global atomics.
__global__ __launch_bounds__(256) void edge_msg_kernel(
    const float* __restrict__ P, const float* __restrict__ Q,
    const float* __restrict__ posrel,
    const unsigned int* __restrict__ rcS,
    const float* __restrict__ w1c, const float* __restrict__ b1,
    const unsigned short* __restrict__ w2t,   // [128 n][128 k] bf16 (transposed)
    const float* __restrict__ b2,
    float* __restrict__ msum)
{
    __shared__ __align__(16) unsigned short W2Ts[128][136];  // full W2T, pad 136
    __shared__ __align__(16) float c1s[HD], b1s[HD], b2s[HD];
    __shared__ float dists[256];
    __shared__ int rows_s[256], cols_s[256];

    const int tid = threadIdx.x;
    const long e0 = (long)blockIdx.x * 256;

    // ---- setup ----
    {
        const unsigned rc = rcS[e0 + tid];
        const int r = (int)(rc >> 16), c = (int)(rc & 0xffffu);
        rows_s[tid] = r; cols_s[tid] = c;
        const float dx = posrel[c*3+0] - posrel[r*3+0];
        const float dy = posrel[c*3+1] - posrel[r*3+1];
        const float dz = posrel[c*3+2] - posrel[r*3+2];
        dists[tid] = sqrtf(dx*dx + dy*dy + dz*dz);
    }
    if (tid < 128) { c1s[tid] = w1c[tid]; b1s[tid] = b1[tid]; b2s[tid] = b2[tid]; }
    #pragma unroll
    for (int it = 0; it < 8; ++it) {                  // 2048 ushort8 chunks of W2T
        const int idx8 = tid + it*256;
        const int n = idx8 >> 4, ch = idx8 & 15;
        *(ulonglong2*)&W2Ts[n][ch*8] = *(const ulonglong2*)&w2t[n*128 + ch*8];
    }
    __syncthreads();   // single barrier

    const int l  = tid & 63;   // lane
    const int w  = tid >> 6;   // wave id
    const int mr = l & 15;
    const int qd = l >> 4;
    const int ebase = w*64;

    // ---- build A-fragments: H[e][k] = relu(P[c][k]+Q[r][k]+d*w1c[k]+b1[k]) ----
    bf16x8 afr[4][4];
    int rowc[4][4];    // cached rows for C-tile aggregation: rowc[m][r] = rows_s[ebase+m*16+qd*4+r]
    #pragma unroll
    for (int m = 0; m < 4; ++m) {
        const int e = ebase + m*16 + mr;
        const int c = cols_s[e], r = rows_s[e];
        const float d = dists[e];
        #pragma unroll
        for (int kk = 0; kk < 4; ++kk) {
            const int kb = kk*32 + qd*8;
            const float4 p0 = ((const float4*)P)[c*32 + (kb>>2)];
            const float4 p1 = ((const float4*)P)[c*32 + (kb>>2) + 1];
            const float4 q0 = ((const float4*)Q)[r*32 + (kb>>2)];
            const float4 q1 = ((const float4*)Q)[r*32 + (kb>>2) + 1];
            const float4 c0 = *(const float4*)&c1s[kb];
            const float4 c1v = *(const float4*)&c1s[kb+4];
            const float4 b0 = *(const float4*)&b1s[kb];
            const float4 b1v = *(const float4*)&b1s[kb+4];
            union { bf16x8 v; unsigned short u[8]; } au;
            au.u[0] = f2bf(fmaxf(p0.x + q0.x + d*c0.x  + b0.x,  0.f));
            au.u[1] = f2bf(fmaxf(p0.y + q0.y + d*c0.y  + b0.y,  0.f));
            au.u[2] = f2bf(fmaxf(p0.z + q0.z + d*c0.z  + b0.z,  0.f));
            au.u[3] = f2bf(fmaxf(p0.w + q0.w + d*c0.w  + b0.w,  0.f));
            au.u[4] = f2bf(fmaxf(p1.x + q1.x + d*c1v.x + b1v.x, 0.f));
            au.u[5] = f2bf(fmaxf(p1.y + q1.y + d*c1v.y + b1v.y, 0.f));
            au.u[6] = f2bf(fmaxf(p1.z + q1.z + d*c1v.z + b1v.z, 0.f));
            au.u[7] = f2bf(fmaxf(p1.w + q1.w + d*c1v.w + b1v.w, 0.f));
            afr[m][kk] = au.v;
        }
        #pragma unroll
        for (int r4 = 0; r4 < 4; ++r4) rowc[m][r4] = rows_s[ebase + m*16 + qd*4 + r4];
    }

    // ---- per col-tile: load B-frags once, MFMA 4 m-tiles, scatter with run-aggregation ----
    #pragma unroll 1
    for (int t = 0; t < 8; ++t) {
        bf16x8 bfr[4];
        #pragma unroll
        for (int kk = 0; kk < 4; ++kk)
            bfr[kk] = *(const bf16x8*)&W2Ts[t*16 + mr][kk*32 + qd*8];
        const int colg = t*16 + mr;
        const float bb = b2s[colg];

        f32x4 acc[4];
        #pragma unroll
        for (int m = 0; m < 4; ++m) acc[m] = (f32x4){0.f, 0.f, 0.f, 0.f};
        #pragma unroll
        for (int kk = 0; kk < 4; ++kk)
            #pragma unroll
            for (int m = 0; m < 4; ++m)
                acc[m] = __builtin_amdgcn_mfma_f32_16x16x32_bf16(afr[m][kk], bfr[kk], acc[m], 0, 0, 0);

        #pragma unroll
        for (int m = 0; m < 4; ++m) {
            int rprev = -1;
            float run = 0.f;
            #pragma unroll
            for (int r4 = 0; r4 < 4; ++r4) {
                const int rw = rowc[m][r4];
                const float v = fmaxf(acc[m][r4] + bb, 0.f);
                if (rw != rprev) {
                    if (rprev >= 0) atomAdd(&msum[(long)rprev*HD + colg], run);
                    rprev = rw; run = v;
                } else {
                    run += v;
                }
            }
            atomAdd(&msum[(long)rprev*HD + colg], run);
        }
    }
}

// ---------------- ligand-masked per-graph sum of x ----------------
__global__ __launch_bounds__(256) void gsum_kernel(
    const float* __restrict__ x, const int* __restrict__ batch,
    const int* __restrict__ ntype, float* __restrict__ gsum)
{
    const int idx = blockIdx.x * 256 + threadIdx.x;
    const int n = idx >> 5, k4 = idx & 31;
    if (ntype[n] != 1) return;
    const int b = batch[n];
    const float4 v = ((const float4*)x)[n*32 + k4];
    float* dst = &gsum[b*HD + k4*4];
    atomAdd(dst+0, v.x); atomAdd(dst+1, v.y);
    atomAdd(dst+2, v.z); atomAdd(dst+3, v.w);
}

// ---------------- readout: hg = relu(g@ro_w1+b1); out = hg@ro_w2 + b2 ----------------
__global__ __launch_bounds__(128) void readout_kernel(
    const float* __restrict__ gsum, const float* __restrict__ lcnt,
    const float* __restrict__ w1, const float* __restrict__ b1,
    const float* __restrict__ w2, const float* __restrict__ b2,
    float* __restrict__ out)
{
    __shared__ float gs[HD];
    __shared__ float red[2];
    const int b = blockIdx.x, j = threadIdx.x;
    gs[j] = gsum[b*HD + j] / fmaxf(lcnt[b], 1.f);
    __syncthreads();
    float acc = b1[j];
    for (int k = 0; k < HD; ++k) acc += gs[k]*w1[k*HD + j];
    float hg = fmaxf(acc, 0.f) * w2[j];
    #pragma unroll
    for (int off = 32; off > 0; off >>= 1) hg += __shfl_down(hg, off, 64);
    if ((j & 63) == 0) red[j >> 6] = hg;
    __syncthreads();
    if (j == 0) out[b] = red[0] + red[1] + b2[0];
}

extern "C" void kernel_launch(void* const* d_in, const int* in_sizes, int n_in,
                              void* d_out, int out_size, void* d_ws, size_t ws_size,
                              hipStream_t stream)
{
    const float* pos   = (const float*)d_in[0];
    const int*   z     = (const int*)d_in[1];
    const int*   batch = (const int*)d_in[2];
    const int*   eidx  = (const int*)d_in[3];
    const int*   ntype = (const int*)d_in[4];
    const float* emb   = (const float*)d_in[5];
    const float* lin_w = (const float*)d_in[6];
    const float* lin_b = (const float*)d_in[7];
    const float* mw1   = (const float*)d_in[8];
    const float* mb1   = (const float*)d_in[9];
    const float* mw2   = (const float*)d_in[10];
    const float* mb2   = (const float*)d_in[11];
    const float* uw    = (const float*)d_in[12];
    const float* ub    = (const float*)d_in[13];
    const float* rw1   = (const float*)d_in[14];
    const float* rb1   = (const float*)d_in[15];
    const float* rw2   = (const float*)d_in[16];
    const float* rb2   = (const float*)d_in[17];

    const int* row = eidx;        // edge_index[0]
    const int* col = eidx + NE;   // edge_index[1]

    float* ws     = (float*)d_ws;
    float* csum   = ws + O_CSUM;
    float* ccnt   = ws + O_CCNT;
    float* lcnt   = ws + O_LCNT;
    float* gsum   = ws + O_GSUM;
    int*   degi   = (int*)(ws + O_DEGI);
    float* posrel = ws + O_POSREL;
    unsigned int* rcS = (unsigned int*)(ws + O_RC);
    float* x      = ws + O_X;
    float* Pb     = ws + O_P;
    float* Qb     = ws + O_Q;
    float* msum   = ws + O_MSUM;
    unsigned short* w2t = (unsigned short*)(ws + O_W2T);
    int* rowStart = (int*)x;
    int* cnt      = (int*)x + NN;

    (void)hipMemsetAsync(ws, 0, (size_t)(O_DEGI + NN) * sizeof(float), stream);
    (void)hipMemsetAsync(cnt, 0, (size_t)NN * sizeof(int), stream);

    stats_kernel  <<<NN/256, 256, 0, stream>>>(pos, batch, ntype, csum, ccnt, lcnt);
    deg_kernel    <<<NE/256, 256, 0, stream>>>(row, degi);
    posrel_kernel <<<NN/256, 256, 0, stream>>>(pos, batch, csum, ccnt, posrel);
    scan_kernel   <<<1, 1024, 0, stream>>>(degi, rowStart);
    scatter_kernel<<<NE/256, 256, 0, stream>>>(row, col, rowStart, cnt, rcS);
    w2bf_kernel   <<<192, 256, 0, stream>>>(mw2, w2t);

    node_gemm<0, 131, false><<<NN/32, 256, 0, stream>>>(emb, posrel, nullptr, z, lin_w, lin_b, x);

    for (int l = 0; l < NL; ++l) {
        const float* W1 = mw1 + (size_t)l*257*HD;
        node_gemm<1, 128, false><<<NN/32, 256, 0, stream>>>(x, nullptr, nullptr, nullptr, W1, nullptr, Pb);
        node_gemm<1, 128, false><<<NN/32, 256, 0, stream>>>(x, nullptr, nullptr, nullptr, W1 + 128*HD, nullptr, Qb);
        (void)hipMemsetAsync(msum, 0, (size_t)NN*HD*sizeof(float), stream);
        edge_msg_kernel<<<NE/256, 256, 0, stream>>>(Pb, Qb, posrel, rcS,
                                                    W1 + 256*HD, mb1 + l*HD,
                                                    w2t + (size_t)l*16384, mb2 + l*HD, msum);
        node_gemm<2, 256, true><<<NN/32, 256, 0, stream>>>(x, msum, degi, nullptr,
                                                           uw + (size_t)l*256*HD, ub + l*HD, x);
    }

    gsum_kernel   <<<NN*32/256, 256, 0, stream>>>(x, batch, ntype, gsum);
    readout_kernel<<<NB, 128, 0, stream>>>(gsum, lcnt, rw1, rb1, rw2, rb2, (float*)d_out);
}

// Round 6
// 2035.453 us; speedup vs baseline: 1.5480x; 1.0319x over previous
//
#include <hip/hip_runtime.h>
#include <hip/hip_bf16.h>
#include <math.h>

#define NN 65536
#define NE 1048576
#define NB 64
#define HD 128
#define NL 3

// ---- workspace layout (float offsets) ----
#define O_CSUM   0           // 64*3
#define O_CCNT   192         // 64
#define O_LCNT   256         // 64
#define O_GSUM   320         // 64*128 -> ends 8512
#define O_DEGI   8512        // 65536 ints -> ends 74048
#define O_POSREL 74048       // 65536*3 -> ends 270656
#define O_RC     270656      // 1048576 u32 (row<<16|col, sorted by row) -> ends 1319232
#define O_X      1319232     // 65536*128  (rowStart/cnt alias its head pre-init)
#define O_P      9707840     // 65536*128
#define O_Q      18096448    // 65536*128
#define O_MSUM   26485056    // 65536*128 -> ends 34873664
#define O_W2T    34873664    // 3*128*128 bf16 -> ends 34898240 (~139.6 MB)

typedef __attribute__((ext_vector_type(8))) short bf16x8;
typedef __attribute__((ext_vector_type(4))) float f32x4;

__device__ __forceinline__ void atomAdd(float* p, float v) {
    unsafeAtomicAdd(p, v);   // native global_atomic_add_f32 on gfx950
}

__device__ __forceinline__ unsigned short f2bf(float f) {
    union { __hip_bfloat16 h; unsigned short u; } cv;
    cv.h = __float2bfloat16(f);
    return cv.u;
}

__device__ __forceinline__ void fma4(float4& acc, float a, const float4 w) {
    acc.x += a*w.x; acc.y += a*w.y; acc.z += a*w.z; acc.w += a*w.w;
}

// ---------------- stats: per-graph centroid sums, node counts, ligand counts --------------
__global__ __launch_bounds__(256) void stats_kernel(
    const float* __restrict__ pos, const int* __restrict__ batch,
    const int* __restrict__ ntype,
    float* __restrict__ csum, float* __restrict__ ccnt, float* __restrict__ lcnt)
{
    __shared__ float s[NB * 5];
    const int tid = threadIdx.x;
    for (int i = tid; i < NB * 5; i += 256) s[i] = 0.f;
    __syncthreads();
    const int n = blockIdx.x * 256 + tid;
    const int b = batch[n];
    atomicAdd(&s[b*5+0], pos[n*3+0]);
    atomicAdd(&s[b*5+1], pos[n*3+1]);
    atomicAdd(&s[b*5+2], pos[n*3+2]);
    atomicAdd(&s[b*5+3], 1.f);
    if (ntype[n] == 1) atomicAdd(&s[b*5+4], 1.f);
    __syncthreads();
    for (int i = tid; i < NB * 5; i += 256) {
        float v = s[i];
        if (v != 0.f) {
            int b2 = i / 5, f = i - b2*5;
            if (f < 3)       atomAdd(&csum[b2*3+f], v);
            else if (f == 3) atomAdd(&ccnt[b2], v);
            else             atomAdd(&lcnt[b2], v);
        }
    }
}

// ---------------- integer degree histogram of `row` ----------------
__global__ __launch_bounds__(256) void deg_kernel(const int* __restrict__ row, int* __restrict__ degi)
{
    const int e = blockIdx.x * 256 + threadIdx.x;
    atomicAdd(&degi[row[e]], 1);
}

// ---------------- single-block exclusive scan of degi[65536] -> rowStart ----------------
__global__ __launch_bounds__(1024) void scan_kernel(const int* __restrict__ degi, int* __restrict__ rowStart)
{
    __shared__ int s[1024];
    __shared__ int carry;
    const int tid = threadIdx.x;
    if (tid == 0) carry = 0;
    __syncthreads();
    for (int c = 0; c < NN / 1024; ++c) {
        const int v = degi[c*1024 + tid];
        s[tid] = v;
        __syncthreads();
        for (int off = 1; off < 1024; off <<= 1) {
            int t = (tid >= off) ? s[tid - off] : 0;
            __syncthreads();
            s[tid] += t;
            __syncthreads();
        }
        rowStart[c*1024 + tid] = carry + s[tid] - v;   // exclusive
        __syncthreads();
        if (tid == 1023) carry += s[1023];
        __syncthreads();
    }
}

// ---------------- counting-sort scatter: rcS[p] = (row<<16)|col, sorted by row --------------
__global__ __launch_bounds__(256) void scatter_kernel(
    const int* __restrict__ row, const int* __restrict__ col,
    const int* __restrict__ rowStart, int* __restrict__ cnt,
    unsigned int* __restrict__ rcS)
{
    const int e = blockIdx.x * 256 + threadIdx.x;
    const int r = row[e], c = col[e];
    const int p = rowStart[r] + atomicAdd(&cnt[r], 1);
    rcS[p] = ((unsigned)r << 16) | (unsigned)c;
}

// ---------------- pos_rel = pos - center[batch] ----------------
__global__ __launch_bounds__(256) void posrel_kernel(
    const float* __restrict__ pos, const int* __restrict__ batch,
    const float* __restrict__ csum, const float* __restrict__ ccnt,
    float* __restrict__ posrel)
{
    const int n = blockIdx.x * 256 + threadIdx.x;
    const int b = batch[n];
    const float inv = 1.f / fmaxf(ccnt[b], 1.f);
    posrel[n*3+0] = pos[n*3+0] - csum[b*3+0]*inv;
    posrel[n*3+1] = pos[n*3+1] - csum[b*3+1]*inv;
    posrel[n*3+2] = pos[n*3+2] - csum[b*3+2]*inv;
}

// ---------------- W2 -> transposed bf16: w2t[l][n][k] = bf16(W2_l[k][n]) ----------------
__global__ __launch_bounds__(256) void w2bf_kernel(const float* __restrict__ mw2,
                                                   unsigned short* __restrict__ w2t)
{
    const int idx = blockIdx.x * 256 + threadIdx.x;   // 49152 total
    const int l = idx >> 14, rem = idx & 16383, n = rem >> 7, k = rem & 127;
    w2t[idx] = f2bf(mw2[(l << 14) + k*128 + n]);
}

// ---------------- lin_in: x = concat(emb[z], posrel) @ lin_in_w + b (K=131) ----------------
__global__ __launch_bounds__(256) void lin_in_gemm(
    const float* __restrict__ emb, const float* __restrict__ posrel,
    const int* __restrict__ zidx,
    const float* __restrict__ W, const float* __restrict__ bias,
    float* __restrict__ out)
{
    __shared__ __align__(16) float Asm[32][132];
    __shared__ __align__(16) float Wsm[32][128];
    const int tid = threadIdx.x;
    const int n0  = blockIdx.x * 32;
    const float4* __restrict__ A0f4 = (const float4*)emb;

    for (int idx4 = tid; idx4 < 1024; idx4 += 256) {
        int i = idx4 >> 5, k4 = idx4 & 31;
        int zz = zidx[n0 + i];
        *(float4*)&Asm[i][k4*4] = A0f4[zz*32 + k4];
    }
    if (tid < 96) { int i = tid / 3, d = tid - i*3; Asm[i][128+d] = posrel[(n0+i)*3 + d]; }
    else if (tid < 128) { Asm[tid-96][131] = 0.f; }

    const int tj = tid & 31;
    const int tn = tid >> 5;
    float acc[4][4];
    #pragma unroll
    for (int r = 0; r < 4; ++r)
        #pragma unroll
        for (int c = 0; c < 4; ++c) acc[r][c] = 0.f;

    const float4* __restrict__ Wf4 = (const float4*)W;
    #pragma unroll 1
    for (int kc = 0; kc < 131; kc += 32) {
        const int kend = (131 - kc < 32) ? (131 - kc) : 32;
        __syncthreads();
        for (int idx4 = tid; idx4 < kend*32; idx4 += 256) {
            int kk = idx4 >> 5, j4 = idx4 & 31;
            *(float4*)&Wsm[kk][j4*4] = Wf4[(kc+kk)*32 + j4];
        }
        __syncthreads();
        for (int kk = 0; kk < kend; ++kk) {
            const float4 w = *(const float4*)&Wsm[kk][tj*4];
            #pragma unroll
            for (int r = 0; r < 4; ++r) {
                const float a = Asm[tn*4+r][kc+kk];
                acc[r][0] += a*w.x; acc[r][1] += a*w.y; acc[r][2] += a*w.z; acc[r][3] += a*w.w;
            }
        }
    }

    const float4 bias4 = ((const float4*)bias)[tj];
    #pragma unroll
    for (int r = 0; r < 4; ++r) {
        const int node = n0 + tn*4 + r;
        float4 o;
        o.x = acc[r][0] + bias4.x; o.y = acc[r][1] + bias4.y;
        o.z = acc[r][2] + bias4.z; o.w = acc[r][3] + bias4.w;
        ((float4*)out)[node*32 + tj] = o;
    }
}

// ---------------- fused P/Q GEMM: P = x@W1[0:128], Q = x@W1[128:256] (no bias) -----------
// block: 64 nodes x 256 cols; thread tile: 4 nodes (strided 16) x 16 cols
__global__ __launch_bounds__(256) void pq_gemm(
    const float* __restrict__ x, const float* __restrict__ W1,
    float* __restrict__ P, float* __restrict__ Q)
{
    __shared__ __align__(16) float Asm[64][33];
    __shared__ __align__(16) float Wsm[32][256];
    const int tid = threadIdx.x;
    const int n0 = blockIdx.x * 64;
    const int cg = tid >> 4;      // 0..15: cols cg*16..+15
    const int ng = tid & 15;      // nodes ng + 16r
    const float4* __restrict__ xf4 = (const float4*)x;
    const float4* __restrict__ Wf4 = (const float4*)W1;

    float4 acc[4][4];
    #pragma unroll
    for (int r = 0; r < 4; ++r)
        #pragma unroll
        for (int q = 0; q < 4; ++q) acc[r][q] = make_float4(0.f, 0.f, 0.f, 0.f);

    #pragma unroll 1
    for (int kc = 0; kc < 128; kc += 32) {
        __syncthreads();
        #pragma unroll
        for (int it = 0; it < 2; ++it) {      // A: 64x32 = 512 float4
            int idx4 = tid + it*256;
            int i = idx4 >> 3, k4 = idx4 & 7;
            *(float4*)&Asm[i][k4*4] = xf4[(n0+i)*32 + (kc>>2) + k4];
        }
        #pragma unroll
        for (int it = 0; it < 8; ++it) {      // W: 32x256 = 2048 float4
            int idx4 = tid + it*256;
            int kk = idx4 >> 6, j4 = idx4 & 63;
            float4 v = (j4 < 32) ? Wf4[(kc+kk)*32 + j4] : Wf4[(128+kc+kk)*32 + (j4-32)];
            *(float4*)&Wsm[kk][j4*4] = v;
        }
        __syncthreads();
        #pragma unroll 4
        for (int kk = 0; kk < 32; ++kk) {
            float a[4];
            #pragma unroll
            for (int r = 0; r < 4; ++r) a[r] = Asm[ng + 16*r][kk];
            float4 wv[4];
            #pragma unroll
            for (int q = 0; q < 4; ++q) wv[q] = *(const float4*)&Wsm[kk][cg*16 + q*4];
            #pragma unroll
            for (int r = 0; r < 4; ++r)
                #pragma unroll
                for (int q = 0; q < 4; ++q) fma4(acc[r][q], a[r], wv[q]);
        }
    }

    float4* outP = (float4*)P;
    float4* outQ = (float4*)Q;
    #pragma unroll
    for (int r = 0; r < 4; ++r) {
        const int node = n0 + ng + 16*r;
        #pragma unroll
        for (int q = 0; q < 4; ++q) {
            if (cg < 8) outP[node*32 + cg*4 + q] = acc[r][q];
            else        outQ[node*32 + (cg-8)*4 + q] = acc[r][q];
        }
    }
}

// ---------------- update GEMM: x = relu(concat(x, msum/deg) @ W + b), K=256 ----------------
// block: 128 nodes x 128 cols; thread tile: 4 nodes (strided 32) x 16 cols
__global__ __launch_bounds__(256) void upd_gemm(
    const float* __restrict__ x, const float* __restrict__ msum,
    const int* __restrict__ degi,
    const float* __restrict__ W, const float* __restrict__ bias,
    float* __restrict__ xout)
{
    __shared__ __align__(16) float Asm[128][33];
    __shared__ __align__(16) float Wsm[32][128];
    const int tid = threadIdx.x;
    const int n0 = blockIdx.x * 128;
    const int cg = tid >> 5;      // 0..7: cols cg*16..+15
    const int ng = tid & 31;      // nodes ng + 32r
    const float4* __restrict__ xf4 = (const float4*)x;
    const float4* __restrict__ mf4 = (const float4*)msum;
    const float4* __restrict__ Wf4 = (const float4*)W;

    float4 acc[4][4];
    #pragma unroll
    for (int r = 0; r < 4; ++r)
        #pragma unroll
        for (int q = 0; q < 4; ++q) acc[r][q] = make_float4(0.f, 0.f, 0.f, 0.f);

    #pragma unroll 1
    for (int kc = 0; kc < 256; kc += 32) {
        __syncthreads();
        #pragma unroll
        for (int it = 0; it < 4; ++it) {      // A: 128x32 = 1024 float4
            int idx4 = tid + it*256;
            int i = idx4 >> 3, k4 = idx4 & 7;
            float4 v;
            if (kc < 128) {
                v = xf4[(n0+i)*32 + (kc>>2) + k4];
            } else {
                v = mf4[(n0+i)*32 + ((kc-128)>>2) + k4];
                const float inv = 1.f / fmaxf((float)degi[n0+i], 1.f);
                v.x *= inv; v.y *= inv; v.z *= inv; v.w *= inv;
            }
            *(float4*)&Asm[i][k4*4] = v;
        }
        #pragma unroll
        for (int it = 0; it < 4; ++it) {      // W: 32x128 = 1024 float4
            int idx4 = tid + it*256;
            int kk = idx4 >> 5, j4 = idx4 & 31;
            *(float4*)&Wsm[kk][j4*4] = Wf4[(kc+kk)*32 + j4];
        }
        __syncthreads();
        #pragma unroll 4
        for (int kk = 0; kk < 32; ++kk) {
            float a[4];
            #pragma unroll
            for (int r = 0; r < 4; ++r) a[r] = Asm[ng + 32*r][kk];
            float4 wv[4];
            #pragma unroll
            for (int q = 0; q < 4; ++q) wv[q] = *(const float4*)&Wsm[kk][cg*16 + q*4];
            #pragma unroll
            for (int r = 0; r < 4; ++r)
                #pragma unroll
                for (int q = 0; q < 4; ++q) fma4(acc[r][q], a[r], wv[q]);
        }
    }

    float4* outx = (float4*)xout;
    #pragma unroll
    for (int r = 0; r < 4; ++r) {
        const int node = n0 + ng + 32*r;
        #pragma unroll
        for (int q = 0; q < 4; ++q) {
            const float4 b4 = ((const float4*)bias)[cg*4 + q];
            float4 o;
            o.x = fmaxf(acc[r][q].x + b4.x, 0.f);
            o.y = fmaxf(acc[r][q].y + b4.y, 0.f);
            o.z = fmaxf(acc[r][q].z + b4.z, 0.f);
            o.w = fmaxf(acc[r][q].w + b4.w, 0.f);
            outx[node*32 + cg*4 + q] = o;
        }
    }
}

// ---------------- fused edge kernel over ROW-SORTED edges, MFMA phase 2 ----------------
// 256 edges/block, 4 waves x 64 edges. Per-lane metadata from global (gathers issue
// pre-barrier, overlap W2T staging). Scatter via register run-aggregation + atomics.
__global__ __launch_bounds__(256) void edge_msg_kernel(
    const float* __restrict__ P, const float* __restrict__ Q,
    const float* __restrict__ posrel,
    const unsigned int* __restrict__ rcS,
    const float* __restrict__ w1c, const float* __restrict__ b1,
    const unsigned short* __restrict__ w2t,   // [128 n][128 k] bf16 (transposed)
    const float* __restrict__ b2,
    float* __restrict__ msum)
{
    __shared__ __align__(16) unsigned short W2Ts[128][136];

    const int tid = threadIdx.x;
    const long e0 = (long)blockIdx.x * 256;
    const int l  = tid & 63;
    const int w  = tid >> 6;
    const int mr = l & 15;
    const int qd = l >> 4;
    const int ebase = w*64;

    // ---- stage W2T into LDS (independent; overlaps everything below) ----
    #pragma unroll
    for (int it = 0; it < 8; ++it) {
        const int idx8 = tid + it*256;
        const int n = idx8 >> 4, ch = idx8 & 15;
        *(ulonglong2*)&W2Ts[n][ch*8] = *(const ulonglong2*)&w2t[n*128 + ch*8];
    }

    // ---- per-lane edge metadata straight from global ----
    int ecol[4], erow[4], rowc[4][4];
    float edist[4];
    #pragma unroll
    for (int m = 0; m < 4; ++m) {
        const unsigned rc = rcS[e0 + ebase + m*16 + mr];
        erow[m] = (int)(rc >> 16); ecol[m] = (int)(rc & 0xffffu);
        #pragma unroll
        for (int r4 = 0; r4 < 4; ++r4)
            rowc[m][r4] = (int)(rcS[e0 + ebase + m*16 + qd*4 + r4] >> 16);
    }
    #pragma unroll
    for (int m = 0; m < 4; ++m) {
        const int c = ecol[m], r = erow[m];
        const float dx = posrel[c*3+0] - posrel[r*3+0];
        const float dy = posrel[c*3+1] - posrel[r*3+1];
        const float dz = posrel[c*3+2] - posrel[r*3+2];
        edist[m] = sqrtf(dx*dx + dy*dy + dz*dz);
    }

    // ---- build A-fragments (P/Q gathers issue pre-barrier) ----
    bf16x8 afr[4][4];
    const float4* __restrict__ Pf4 = (const float4*)P;
    const float4* __restrict__ Qf4 = (const float4*)Q;
    const float4* __restrict__ c1f4 = (const float4*)w1c;
    const float4* __restrict__ b1f4 = (const float4*)b1;
    #pragma unroll
    for (int kk = 0; kk < 4; ++kk) {
        const int kb4 = (kk*32 + qd*8) >> 2;
        const float4 c0  = c1f4[kb4],   c1v = c1f4[kb4+1];
        const float4 b0  = b1f4[kb4],   b1v = b1f4[kb4+1];
        #pragma unroll
        for (int m = 0; m < 4; ++m) {
            const float4 p0 = Pf4[ecol[m]*32 + kb4];
            const float4 p1 = Pf4[ecol[m]*32 + kb4 + 1];
            const float4 q0 = Qf4[erow[m]*32 + kb4];
            const float4 q1 = Qf4[erow[m]*32 + kb4 + 1];
            const float d = edist[m];
            union { bf16x8 v; unsigned short u[8]; } au;
            au.u[0] = f2bf(fmaxf(p0.x + q0.x + d*c0.x  + b0.x,  0.f));
            au.u[1] = f2bf(fmaxf(p0.y + q0.y + d*c0.y  + b0.y,  0.f));
            au.u[2] = f2bf(fmaxf(p0.z + q0.z + d*c0.z  + b0.z,  0.f));
            au.u[3] = f2bf(fmaxf(p0.w + q0.w + d*c0.w  + b0.w,  0.f));
            au.u[4] = f2bf(fmaxf(p1.x + q1.x + d*c1v.x + b1v.x, 0.f));
            au.u[5] = f2bf(fmaxf(p1.y + q1.y + d*c1v.y + b1v.y, 0.f));
            au.u[6] = f2bf(fmaxf(p1.z + q1.z + d*c1v.z + b1v.z, 0.f));
            au.u[7] = f2bf(fmaxf(p1.w + q1.w + d*c1v.w + b1v.w, 0.f));
            afr[m][kk] = au.v;
        }
    }
    __syncthreads();   // only waits for W2T staging

    // ---- per col-tile: B-frags once, MFMA 4 m-tiles, scatter with run-aggregation ----
    #pragma unroll 1
    for (int t = 0; t < 8; ++t) {
        bf16x8 bfr[4];
        #pragma unroll
        for (int kk = 0; kk < 4; ++kk)
            bfr[kk] = *(const bf16x8*)&W2Ts[t*16 + mr][kk*32 + qd*8];
        const int colg = t*16 + mr;
        const float bb = b2[colg];

        f32x4 acc[4];
        #pragma unroll
        for (int m = 0; m < 4; ++m) acc[m] = (f32x4){0.f, 0.f, 0.f, 0.f};
        #pragma unroll
        for (int kk = 0; kk < 4; ++kk)
            #pragma unroll
            for (int m = 0; m < 4; ++m)
                acc[m] = __builtin_amdgcn_mfma_f32_16x16x32_bf16(afr[m][kk], bfr[kk], acc[m], 0, 0, 0);

        #pragma unroll
        for (int m = 0; m < 4; ++m) {
            int rprev = -1;
            float run = 0.f;
            #pragma unroll
            for (int r4 = 0; r4 < 4; ++r4) {
                const int rw = rowc[m][r4];
                const float v = fmaxf(acc[m][r4] + bb, 0.f);
                if (rw != rprev) {
                    if (rprev >= 0) atomAdd(&msum[(long)rprev*HD + colg], run);
                    rprev = rw; run = v;
                } else {
                    run += v;
                }
            }
            atomAdd(&msum[(long)rprev*HD + colg], run);
        }
    }
}

// ---------------- ligand-masked per-graph sum of x ----------------
__global__ __launch_bounds__(256) void gsum_kernel(
    const float* __restrict__ x, const int* __restrict__ batch,
    const int* __restrict__ ntype, float* __restrict__ gsum)
{
    const int idx = blockIdx.x * 256 + threadIdx.x;
    const int n = idx >> 5, k4 = idx & 31;
    if (ntype[n] != 1) return;
    const int b = batch[n];
    const float4 v = ((const float4*)x)[n*32 + k4];
    float* dst = &gsum[b*HD + k4*4];
    atomAdd(dst+0, v.x); atomAdd(dst+1, v.y);
    atomAdd(dst+2, v.z); atomAdd(dst+3, v.w);
}

// ---------------- readout: hg = relu(g@ro_w1+b1); out = hg@ro_w2 + b2 ----------------
__global__ __launch_bounds__(128) void readout_kernel(
    const float* __restrict__ gsum, const float* __restrict__ lcnt,
    const float* __restrict__ w1, const float* __restrict__ b1,
    const float* __restrict__ w2, const float* __restrict__ b2,
    float* __restrict__ out)
{
    __shared__ float gs[HD];
    __shared__ float red[2];
    const int b = blockIdx.x, j = threadIdx.x;
    gs[j] = gsum[b*HD + j] / fmaxf(lcnt[b], 1.f);
    __syncthreads();
    float acc = b1[j];
    for (int k = 0; k < HD; ++k) acc += gs[k]*w1[k*HD + j];
    float hg = fmaxf(acc, 0.f) * w2[j];
    #pragma unroll
    for (int off = 32; off > 0; off >>= 1) hg += __shfl_down(hg, off, 64);
    if ((j & 63) == 0) red[j >> 6] = hg;
    __syncthreads();
    if (j == 0) out[b] = red[0] + red[1] + b2[0];
}

extern "C" void kernel_launch(void* const* d_in, const int* in_sizes, int n_in,
                              void* d_out, int out_size, void* d_ws, size_t ws_size,
                              hipStream_t stream)
{
    const float* pos   = (const float*)d_in[0];
    const int*   z     = (const int*)d_in[1];
    const int*   batch = (const int*)d_in[2];
    const int*   eidx  = (const int*)d_in[3];
    const int*   ntype = (const int*)d_in[4];
    const float* emb   = (const float*)d_in[5];
    const float* lin_w = (const float*)d_in[6];
    const float* lin_b = (const float*)d_in[7];
    const float* mw1   = (const float*)d_in[8];
    const float* mb1   = (const float*)d_in[9];
    const float* mw2   = (const float*)d_in[10];
    const float* mb2   = (const float*)d_in[11];
    const float* uw    = (const float*)d_in[12];
    const float* ub    = (const float*)d_in[13];
    const float* rw1   = (const float*)d_in[14];
    const float* rb1   = (const float*)d_in[15];
    const float* rw2   = (const float*)d_in[16];
    const float* rb2   = (const float*)d_in[17];

    const int* row = eidx;        // edge_index[0]
    const int* col = eidx + NE;   // edge_index[1]

    float* ws     = (float*)d_ws;
    float* csum   = ws + O_CSUM;
    float* ccnt   = ws + O_CCNT;
    float* lcnt   = ws + O_LCNT;
    float* gsum   = ws + O_GSUM;
    int*   degi   = (int*)(ws + O_DEGI);
    float* posrel = ws + O_POSREL;
    unsigned int* rcS = (unsigned int*)(ws + O_RC);
    float* x      = ws + O_X;
    float* Pb     = ws + O_P;
    float* Qb     = ws + O_Q;
    float* msum   = ws + O_MSUM;
    unsigned short* w2t = (unsigned short*)(ws + O_W2T);
    int* rowStart = (int*)x;
    int* cnt      = (int*)x + NN;

    (void)hipMemsetAsync(ws, 0, (size_t)(O_DEGI + NN) * sizeof(float), stream);
    (void)hipMemsetAsync(cnt, 0, (size_t)NN * sizeof(int), stream);

    stats_kernel  <<<NN/256, 256, 0, stream>>>(pos, batch, ntype, csum, ccnt, lcnt);
    deg_kernel    <<<NE/256, 256, 0, stream>>>(row, degi);
    posrel_kernel <<<NN/256, 256, 0, stream>>>(pos, batch, csum, ccnt, posrel);
    scan_kernel   <<<1, 1024, 0, stream>>>(degi, rowStart);
    scatter_kernel<<<NE/256, 256, 0, stream>>>(row, col, rowStart, cnt, rcS);
    w2bf_kernel   <<<192, 256, 0, stream>>>(mw2, w2t);

    lin_in_gemm<<<NN/32, 256, 0, stream>>>(emb, posrel, z, lin_w, lin_b, x);

    for (int l = 0; l < NL; ++l) {
        const float* W1 = mw1 + (size_t)l*257*HD;
        pq_gemm<<<NN/64, 256, 0, stream>>>(x, W1, Pb, Qb);
        (void)hipMemsetAsync(msum, 0, (size_t)NN*HD*sizeof(float), stream);
        edge_msg_kernel<<<NE/256, 256, 0, stream>>>(Pb, Qb, posrel, rcS,
                                                    W1 + 256*HD, mb1 + l*HD,
                                                    w2t + (size_t)l*16384, mb2 + l*HD, msum);
        upd_gemm<<<NN/128, 256, 0, stream>>>(x, msum, degi,
                                             uw + (size_t)l*256*HD, ub + l*HD, x);
    }

    gsum_kernel   <<<NN*32/256, 256, 0, stream>>>(x, batch, ntype, gsum);
    readout_kernel<<<NB, 128, 0, stream>>>(gsum, lcnt, rw1, rb1, rw2, rb2, (float*)d_out);
}

// Round 7
// 2033.146 us; speedup vs baseline: 1.5497x; 1.0011x over previous
//
#include <hip/hip_runtime.h>
#include <hip/hip_bf16.h>
#include <math.h>

#define NN 65536
#define NE 1048576
#define NB 64
#define HD 128
#define NL 3

// ---- workspace layout (float offsets) ----
#define O_CSUM   0           // 64*3
#define O_CCNT   192         // 64
#define O_LCNT   256         // 64
#define O_GSUM   320         // 64*128 -> ends 8512
#define O_DEGI   8512        // 65536 ints -> ends 74048
#define O_POSREL 74048       // 65536*3 -> ends 270656
#define O_RC     270656      // 1048576 u32 (row<<16|col, sorted by row) -> ends 1319232
#define O_X      1319232     // 65536*128  (rowStart/cnt alias its head pre-init)
#define O_P      9707840     // 65536*128
#define O_Q      18096448    // 65536*128
#define O_MSUM   26485056    // 65536*128 -> ends 34873664
#define O_W2T    34873664    // 3*128*128 bf16 -> ends 34898240 (~139.6 MB)

typedef __attribute__((ext_vector_type(8))) short bf16x8;
typedef __attribute__((ext_vector_type(4))) float f32x4;

__device__ __forceinline__ void atomAdd(float* p, float v) {
    unsafeAtomicAdd(p, v);   // native global_atomic_add_f32 on gfx950
}

__device__ __forceinline__ unsigned short f2bf(float f) {
    union { __hip_bfloat16 h; unsigned short u; } cv;
    cv.h = __float2bfloat16(f);
    return cv.u;
}

__device__ __forceinline__ void fma4(float4& acc, float a, const float4 w) {
    acc.x += a*w.x; acc.y += a*w.y; acc.z += a*w.z; acc.w += a*w.w;
}

// ---------------- stats: per-graph centroid sums, node counts, ligand counts --------------
__global__ __launch_bounds__(256) void stats_kernel(
    const float* __restrict__ pos, const int* __restrict__ batch,
    const int* __restrict__ ntype,
    float* __restrict__ csum, float* __restrict__ ccnt, float* __restrict__ lcnt)
{
    __shared__ float s[NB * 5];
    const int tid = threadIdx.x;
    for (int i = tid; i < NB * 5; i += 256) s[i] = 0.f;
    __syncthreads();
    const int n = blockIdx.x * 256 + tid;
    const int b = batch[n];
    atomicAdd(&s[b*5+0], pos[n*3+0]);
    atomicAdd(&s[b*5+1], pos[n*3+1]);
    atomicAdd(&s[b*5+2], pos[n*3+2]);
    atomicAdd(&s[b*5+3], 1.f);
    if (ntype[n] == 1) atomicAdd(&s[b*5+4], 1.f);
    __syncthreads();
    for (int i = tid; i < NB * 5; i += 256) {
        float v = s[i];
        if (v != 0.f) {
            int b2 = i / 5, f = i - b2*5;
            if (f < 3)       atomAdd(&csum[b2*3+f], v);
            else if (f == 3) atomAdd(&ccnt[b2], v);
            else             atomAdd(&lcnt[b2], v);
        }
    }
}

// ---------------- integer degree histogram of `row` ----------------
__global__ __launch_bounds__(256) void deg_kernel(const int* __restrict__ row, int* __restrict__ degi)
{
    const int e = blockIdx.x * 256 + threadIdx.x;
    atomicAdd(&degi[row[e]], 1);
}

// ---------------- single-block exclusive scan of degi[65536] -> rowStart ----------------
__global__ __launch_bounds__(1024) void scan_kernel(const int* __restrict__ degi, int* __restrict__ rowStart)
{
    __shared__ int s[1024];
    __shared__ int carry;
    const int tid = threadIdx.x;
    if (tid == 0) carry = 0;
    __syncthreads();
    for (int c = 0; c < NN / 1024; ++c) {
        const int v = degi[c*1024 + tid];
        s[tid] = v;
        __syncthreads();
        for (int off = 1; off < 1024; off <<= 1) {
            int t = (tid >= off) ? s[tid - off] : 0;
            __syncthreads();
            s[tid] += t;
            __syncthreads();
        }
        rowStart[c*1024 + tid] = carry + s[tid] - v;   // exclusive
        __syncthreads();
        if (tid == 1023) carry += s[1023];
        __syncthreads();
    }
}

// ---------------- counting-sort scatter: rcS[p] = (row<<16)|col, sorted by row --------------
__global__ __launch_bounds__(256) void scatter_kernel(
    const int* __restrict__ row, const int* __restrict__ col,
    const int* __restrict__ rowStart, int* __restrict__ cnt,
    unsigned int* __restrict__ rcS)
{
    const int e = blockIdx.x * 256 + threadIdx.x;
    const int r = row[e], c = col[e];
    const int p = rowStart[r] + atomicAdd(&cnt[r], 1);
    rcS[p] = ((unsigned)r << 16) | (unsigned)c;
}

// ---------------- pos_rel = pos - center[batch] ----------------
__global__ __launch_bounds__(256) void posrel_kernel(
    const float* __restrict__ pos, const int* __restrict__ batch,
    const float* __restrict__ csum, const float* __restrict__ ccnt,
    float* __restrict__ posrel)
{
    const int n = blockIdx.x * 256 + threadIdx.x;
    const int b = batch[n];
    const float inv = 1.f / fmaxf(ccnt[b], 1.f);
    posrel[n*3+0] = pos[n*3+0] - csum[b*3+0]*inv;
    posrel[n*3+1] = pos[n*3+1] - csum[b*3+1]*inv;
    posrel[n*3+2] = pos[n*3+2] - csum[b*3+2]*inv;
}

// ---------------- W2 -> transposed bf16: w2t[l][n][k] = bf16(W2_l[k][n]) ----------------
__global__ __launch_bounds__(256) void w2bf_kernel(const float* __restrict__ mw2,
                                                   unsigned short* __restrict__ w2t)
{
    const int idx = blockIdx.x * 256 + threadIdx.x;   // 49152 total
    const int l = idx >> 14, rem = idx & 16383, n = rem >> 7, k = rem & 127;
    w2t[idx] = f2bf(mw2[(l << 14) + k*128 + n]);
}

// ---------------- lin_in: x = concat(emb[z], posrel) @ lin_in_w + b (K=131) ----------------
__global__ __launch_bounds__(256) void lin_in_gemm(
    const float* __restrict__ emb, const float* __restrict__ posrel,
    const int* __restrict__ zidx,
    const float* __restrict__ W, const float* __restrict__ bias,
    float* __restrict__ out)
{
    __shared__ __align__(16) float Asm[32][132];
    __shared__ __align__(16) float Wsm[32][128];
    const int tid = threadIdx.x;
    const int n0  = blockIdx.x * 32;
    const float4* __restrict__ A0f4 = (const float4*)emb;

    for (int idx4 = tid; idx4 < 1024; idx4 += 256) {
        int i = idx4 >> 5, k4 = idx4 & 31;
        int zz = zidx[n0 + i];
        *(float4*)&Asm[i][k4*4] = A0f4[zz*32 + k4];
    }
    if (tid < 96) { int i = tid / 3, d = tid - i*3; Asm[i][128+d] = posrel[(n0+i)*3 + d]; }
    else if (tid < 128) { Asm[tid-96][131] = 0.f; }

    const int tj = tid & 31;
    const int tn = tid >> 5;
    float acc[4][4];
    #pragma unroll
    for (int r = 0; r < 4; ++r)
        #pragma unroll
        for (int c = 0; c < 4; ++c) acc[r][c] = 0.f;

    const float4* __restrict__ Wf4 = (const float4*)W;
    #pragma unroll 1
    for (int kc = 0; kc < 131; kc += 32) {
        const int kend = (131 - kc < 32) ? (131 - kc) : 32;
        __syncthreads();
        for (int idx4 = tid; idx4 < kend*32; idx4 += 256) {
            int kk = idx4 >> 5, j4 = idx4 & 31;
            *(float4*)&Wsm[kk][j4*4] = Wf4[(kc+kk)*32 + j4];
        }
        __syncthreads();
        for (int kk = 0; kk < kend; ++kk) {
            const float4 w = *(const float4*)&Wsm[kk][tj*4];
            #pragma unroll
            for (int r = 0; r < 4; ++r) {
                const float a = Asm[tn*4+r][kc+kk];
                acc[r][0] += a*w.x; acc[r][1] += a*w.y; acc[r][2] += a*w.z; acc[r][3] += a*w.w;
            }
        }
    }

    const float4 bias4 = ((const float4*)bias)[tj];
    #pragma unroll
    for (int r = 0; r < 4; ++r) {
        const int node = n0 + tn*4 + r;
        float4 o;
        o.x = acc[r][0] + bias4.x; o.y = acc[r][1] + bias4.y;
        o.z = acc[r][2] + bias4.z; o.w = acc[r][3] + bias4.w;
        ((float4*)out)[node*32 + tj] = o;
    }
}

// ---------------- fused P/Q GEMM: P = x@W1[0:128], Q = x@W1[128:256] (no bias) -----------
__global__ __launch_bounds__(256) void pq_gemm(
    const float* __restrict__ x, const float* __restrict__ W1,
    float* __restrict__ P, float* __restrict__ Q)
{
    __shared__ __align__(16) float Asm[64][33];
    __shared__ __align__(16) float Wsm[32][256];
    const int tid = threadIdx.x;
    const int n0 = blockIdx.x * 64;
    const int cg = tid >> 4;      // 0..15: cols cg*16..+15
    const int ng = tid & 15;      // nodes ng + 16r
    const float4* __restrict__ xf4 = (const float4*)x;
    const float4* __restrict__ Wf4 = (const float4*)W1;

    float4 acc[4][4];
    #pragma unroll
    for (int r = 0; r < 4; ++r)
        #pragma unroll
        for (int q = 0; q < 4; ++q) acc[r][q] = make_float4(0.f, 0.f, 0.f, 0.f);

    #pragma unroll 1
    for (int kc = 0; kc < 128; kc += 32) {
        __syncthreads();
        #pragma unroll
        for (int it = 0; it < 2; ++it) {
            int idx4 = tid + it*256;
            int i = idx4 >> 3, k4 = idx4 & 7;
            *(float4*)&Asm[i][k4*4] = xf4[(n0+i)*32 + (kc>>2) + k4];
        }
        #pragma unroll
        for (int it = 0; it < 8; ++it) {
            int idx4 = tid + it*256;
            int kk = idx4 >> 6, j4 = idx4 & 63;
            float4 v = (j4 < 32) ? Wf4[(kc+kk)*32 + j4] : Wf4[(128+kc+kk)*32 + (j4-32)];
            *(float4*)&Wsm[kk][j4*4] = v;
        }
        __syncthreads();
        #pragma unroll 4
        for (int kk = 0; kk < 32; ++kk) {
            float a[4];
            #pragma unroll
            for (int r = 0; r < 4; ++r) a[r] = Asm[ng + 16*r][kk];
            float4 wv[4];
            #pragma unroll
            for (int q = 0; q < 4; ++q) wv[q] = *(const float4*)&Wsm[kk][cg*16 + q*4];
            #pragma unroll
            for (int r = 0; r < 4; ++r)
                #pragma unroll
                for (int q = 0; q < 4; ++q) fma4(acc[r][q], a[r], wv[q]);
        }
    }

    float4* outP = (float4*)P;
    float4* outQ = (float4*)Q;
    #pragma unroll
    for (int r = 0; r < 4; ++r) {
        const int node = n0 + ng + 16*r;
        #pragma unroll
        for (int q = 0; q < 4; ++q) {
            if (cg < 8) outP[node*32 + cg*4 + q] = acc[r][q];
            else        outQ[node*32 + (cg-8)*4 + q] = acc[r][q];
        }
    }
}

// ---------------- update GEMM: x = relu(concat(x, msum/deg) @ W + b), K=256 ----------------
__global__ __launch_bounds__(256) void upd_gemm(
    const float* __restrict__ x, const float* __restrict__ msum,
    const int* __restrict__ degi,
    const float* __restrict__ W, const float* __restrict__ bias,
    float* __restrict__ xout)
{
    __shared__ __align__(16) float Asm[128][33];
    __shared__ __align__(16) float Wsm[32][128];
    const int tid = threadIdx.x;
    const int n0 = blockIdx.x * 128;
    const int cg = tid >> 5;      // 0..7: cols cg*16..+15
    const int ng = tid & 31;      // nodes ng + 32r
    const float4* __restrict__ xf4 = (const float4*)x;
    const float4* __restrict__ mf4 = (const float4*)msum;
    const float4* __restrict__ Wf4 = (const float4*)W;

    float4 acc[4][4];
    #pragma unroll
    for (int r = 0; r < 4; ++r)
        #pragma unroll
        for (int q = 0; q < 4; ++q) acc[r][q] = make_float4(0.f, 0.f, 0.f, 0.f);

    #pragma unroll 1
    for (int kc = 0; kc < 256; kc += 32) {
        __syncthreads();
        #pragma unroll
        for (int it = 0; it < 4; ++it) {
            int idx4 = tid + it*256;
            int i = idx4 >> 3, k4 = idx4 & 7;
            float4 v;
            if (kc < 128) {
                v = xf4[(n0+i)*32 + (kc>>2) + k4];
            } else {
                v = mf4[(n0+i)*32 + ((kc-128)>>2) + k4];
                const float inv = 1.f / fmaxf((float)degi[n0+i], 1.f);
                v.x *= inv; v.y *= inv; v.z *= inv; v.w *= inv;
            }
            *(float4*)&Asm[i][k4*4] = v;
        }
        #pragma unroll
        for (int it = 0; it < 4; ++it) {
            int idx4 = tid + it*256;
            int kk = idx4 >> 5, j4 = idx4 & 31;
            *(float4*)&Wsm[kk][j4*4] = Wf4[(kc+kk)*32 + j4];
        }
        __syncthreads();
        #pragma unroll 4
        for (int kk = 0; kk < 32; ++kk) {
            float a[4];
            #pragma unroll
            for (int r = 0; r < 4; ++r) a[r] = Asm[ng + 32*r][kk];
            float4 wv[4];
            #pragma unroll
            for (int q = 0; q < 4; ++q) wv[q] = *(const float4*)&Wsm[kk][cg*16 + q*4];
            #pragma unroll
            for (int r = 0; r < 4; ++r)
                #pragma unroll
                for (int q = 0; q < 4; ++q) fma4(acc[r][q], a[r], wv[q]);
        }
    }

    float4* outx = (float4*)xout;
    #pragma unroll
    for (int r = 0; r < 4; ++r) {
        const int node = n0 + ng + 32*r;
        #pragma unroll
        for (int q = 0; q < 4; ++q) {
            const float4 b4 = ((const float4*)bias)[cg*4 + q];
            float4 o;
            o.x = fmaxf(acc[r][q].x + b4.x, 0.f);
            o.y = fmaxf(acc[r][q].y + b4.y, 0.f);
            o.z = fmaxf(acc[r][q].z + b4.z, 0.f);
            o.w = fmaxf(acc[r][q].w + b4.w, 0.f);
            outx[node*32 + cg*4 + q] = o;
        }
    }
}

// ---------------- fused edge kernel over ROW-SORTED edges, MFMA phase 2 ----------------
// NO LDS, NO BARRIER: W2T read through L1 (32 KB, fits), waves fully independent.
// 256 edges/block, 4 waves x 64 edges. Scatter via register run-aggregation + atomics.
__global__ __launch_bounds__(256) void edge_msg_kernel(
    const float* __restrict__ P, const float* __restrict__ Q,
    const float* __restrict__ posrel,
    const unsigned int* __restrict__ rcS,
    const float* __restrict__ w1c, const float* __restrict__ b1,
    const unsigned short* __restrict__ w2t,   // [128 n][128 k] bf16 (transposed)
    const float* __restrict__ b2,
    float* __restrict__ msum)
{
    const int tid = threadIdx.x;
    const long e0 = (long)blockIdx.x * 256;
    const int l  = tid & 63;
    const int w  = tid >> 6;
    const int mr = l & 15;
    const int qd = l >> 4;
    const int ebase = w*64;

    // ---- per-lane edge metadata straight from global ----
    int ecol[4], erow[4], rowc[4][4];
    float edist[4];
    #pragma unroll
    for (int m = 0; m < 4; ++m) {
        const unsigned rc = rcS[e0 + ebase + m*16 + mr];
        erow[m] = (int)(rc >> 16); ecol[m] = (int)(rc & 0xffffu);
        #pragma unroll
        for (int r4 = 0; r4 < 4; ++r4)
            rowc[m][r4] = (int)(rcS[e0 + ebase + m*16 + qd*4 + r4] >> 16);
    }
    #pragma unroll
    for (int m = 0; m < 4; ++m) {
        const int c = ecol[m], r = erow[m];
        const float dx = posrel[c*3+0] - posrel[r*3+0];
        const float dy = posrel[c*3+1] - posrel[r*3+1];
        const float dz = posrel[c*3+2] - posrel[r*3+2];
        edist[m] = sqrtf(dx*dx + dy*dy + dz*dz);
    }

    // ---- build A-fragments ----
    bf16x8 afr[4][4];
    const float4* __restrict__ Pf4 = (const float4*)P;
    const float4* __restrict__ Qf4 = (const float4*)Q;
    const float4* __restrict__ c1f4 = (const float4*)w1c;
    const float4* __restrict__ b1f4 = (const float4*)b1;
    #pragma unroll
    for (int kk = 0; kk < 4; ++kk) {
        const int kb4 = (kk*32 + qd*8) >> 2;
        const float4 c0  = c1f4[kb4],   c1v = c1f4[kb4+1];
        const float4 b0  = b1f4[kb4],   b1v = b1f4[kb4+1];
        #pragma unroll
        for (int m = 0; m < 4; ++m) {
            const float4 p0 = Pf4[ecol[m]*32 + kb4];
            const float4 p1 = Pf4[ecol[m]*32 + kb4 + 1];
            const float4 q0 = Qf4[erow[m]*32 + kb4];
            const float4 q1 = Qf4[erow[m]*32 + kb4 + 1];
            const float d = edist[m];
            union { bf16x8 v; unsigned short u[8]; } au;
            au.u[0] = f2bf(fmaxf(p0.x + q0.x + d*c0.x  + b0.x,  0.f));
            au.u[1] = f2bf(fmaxf(p0.y + q0.y + d*c0.y  + b0.y,  0.f));
            au.u[2] = f2bf(fmaxf(p0.z + q0.z + d*c0.z  + b0.z,  0.f));
            au.u[3] = f2bf(fmaxf(p0.w + q0.w + d*c0.w  + b0.w,  0.f));
            au.u[4] = f2bf(fmaxf(p1.x + q1.x + d*c1v.x + b1v.x, 0.f));
            au.u[5] = f2bf(fmaxf(p1.y + q1.y + d*c1v.y + b1v.y, 0.f));
            au.u[6] = f2bf(fmaxf(p1.z + q1.z + d*c1v.z + b1v.z, 0.f));
            au.u[7] = f2bf(fmaxf(p1.w + q1.w + d*c1v.w + b1v.w, 0.f));
            afr[m][kk] = au.v;
        }
    }

    // ---- per col-tile (software-pipelined B loads from global, L1-resident) ----
    const bf16x8* __restrict__ w2tv = (const bf16x8*)w2t;   // [n][16] bf16x8 chunks
    bf16x8 bfr[4];
    #pragma unroll
    for (int kk = 0; kk < 4; ++kk)
        bfr[kk] = w2tv[(0*16 + mr)*16 + kk*4 + qd];

    #pragma unroll 1
    for (int t = 0; t < 8; ++t) {
        bf16x8 bnext[4];
        if (t < 7) {
            #pragma unroll
            for (int kk = 0; kk < 4; ++kk)
                bnext[kk] = w2tv[((t+1)*16 + mr)*16 + kk*4 + qd];
        }
        const int colg = t*16 + mr;
        const float bb = b2[colg];

        f32x4 acc[4];
        #pragma unroll
        for (int m = 0; m < 4; ++m) acc[m] = (f32x4){0.f, 0.f, 0.f, 0.f};
        #pragma unroll
        for (int kk = 0; kk < 4; ++kk)
            #pragma unroll
            for (int m = 0; m < 4; ++m)
                acc[m] = __builtin_amdgcn_mfma_f32_16x16x32_bf16(afr[m][kk], bfr[kk], acc[m], 0, 0, 0);

        #pragma unroll
        for (int m = 0; m < 4; ++m) {
            int rprev = -1;
            float run = 0.f;
            #pragma unroll
            for (int r4 = 0; r4 < 4; ++r4) {
                const int rw = rowc[m][r4];
                const float v = fmaxf(acc[m][r4] + bb, 0.f);
                if (rw != rprev) {
                    if (rprev >= 0) atomAdd(&msum[(long)rprev*HD + colg], run);
                    rprev = rw; run = v;
                } else {
                    run += v;
                }
            }
            atomAdd(&msum[(long)rprev*HD + colg], run);
        }
        #pragma unroll
        for (int kk = 0; kk < 4; ++kk) bfr[kk] = bnext[kk];
    }
}

// ---------------- ligand-masked per-graph sum of x ----------------
__global__ __launch_bounds__(256) void gsum_kernel(
    const float* __restrict__ x, const int* __restrict__ batch,
    const int* __restrict__ ntype, float* __restrict__ gsum)
{
    const int idx = blockIdx.x * 256 + threadIdx.x;
    const int n = idx >> 5, k4 = idx & 31;
    if (ntype[n] != 1) return;
    const int b = batch[n];
    const float4 v = ((const float4*)x)[n*32 + k4];
    float* dst = &gsum[b*HD + k4*4];
    atomAdd(dst+0, v.x); atomAdd(dst+1, v.y);
    atomAdd(dst+2, v.z); atomAdd(dst+3, v.w);
}

// ---------------- readout: hg = relu(g@ro_w1+b1); out = hg@ro_w2 + b2 ----------------
__global__ __launch_bounds__(128) void readout_kernel(
    const float* __restrict__ gsum, const float* __restrict__ lcnt,
    const float* __restrict__ w1, const float* __restrict__ b1,
    const float* __restrict__ w2, const float* __restrict__ b2,
    float* __restrict__ out)
{
    __shared__ float gs[HD];
    __shared__ float red[2];
    const int b = blockIdx.x, j = threadIdx.x;
    gs[j] = gsum[b*HD + j] / fmaxf(lcnt[b], 1.f);
    __syncthreads();
    float acc = b1[j];
    for (int k = 0; k < HD; ++k) acc += gs[k]*w1[k*HD + j];
    float hg = fmaxf(acc, 0.f) * w2[j];
    #pragma unroll
    for (int off = 32; off > 0; off >>= 1) hg += __shfl_down(hg, off, 64);
    if ((j & 63) == 0) red[j >> 6] = hg;
    __syncthreads();
    if (j == 0) out[b] = red[0] + red[1] + b2[0];
}

extern "C" void kernel_launch(void* const* d_in, const int* in_sizes, int n_in,
                              void* d_out, int out_size, void* d_ws, size_t ws_size,
                              hipStream_t stream)
{
    const float* pos   = (const float*)d_in[0];
    const int*   z     = (const int*)d_in[1];
    const int*   batch = (const int*)d_in[2];
    const int*   eidx  = (const int*)d_in[3];
    const int*   ntype = (const int*)d_in[4];
    const float* emb   = (const float*)d_in[5];
    const float* lin_w = (const float*)d_in[6];
    const float* lin_b = (const float*)d_in[7];
    const float* mw1   = (const float*)d_in[8];
    const float* mb1   = (const float*)d_in[9];
    const float* mw2   = (const float*)d_in[10];
    const float* mb2   = (const float*)d_in[11];
    const float* uw    = (const float*)d_in[12];
    const float* ub    = (const float*)d_in[13];
    const float* rw1   = (const float*)d_in[14];
    const float* rb1   = (const float*)d_in[15];
    const float* rw2   = (const float*)d_in[16];
    const float* rb2   = (const float*)d_in[17];

    const int* row = eidx;        // edge_index[0]
    const int* col = eidx + NE;   // edge_index[1]

    float* ws     = (float*)d_ws;
    float* csum   = ws + O_CSUM;
    float* ccnt   = ws + O_CCNT;
    float* lcnt   = ws + O_LCNT;
    float* gsum   = ws + O_GSUM;
    int*   degi   = (int*)(ws + O_DEGI);
    float* posrel = ws + O_POSREL;
    unsigned int* rcS = (unsigned int*)(ws + O_RC);
    float* x      = ws + O_X;
    float* Pb     = ws + O_P;
    float* Qb     = ws + O_Q;
    float* msum   = ws + O_MSUM;
    unsigned short* w2t = (unsigned short*)(ws + O_W2T);
    int* rowStart = (int*)x;
    int* cnt      = (int*)x + NN;

    (void)hipMemsetAsync(ws, 0, (size_t)(O_DEGI + NN) * sizeof(float), stream);
    (void)hipMemsetAsync(cnt, 0, (size_t)NN * sizeof(int), stream);

    stats_kernel  <<<NN/256, 256, 0, stream>>>(pos, batch, ntype, csum, ccnt, lcnt);
    deg_kernel    <<<NE/256, 256, 0, stream>>>(row, degi);
    posrel_kernel <<<NN/256, 256, 0, stream>>>(pos, batch, csum, ccnt, posrel);
    scan_kernel   <<<1, 1024, 0, stream>>>(degi, rowStart);
    scatter_kernel<<<NE/256, 256, 0, stream>>>(row, col, rowStart, cnt, rcS);
    w2bf_kernel   <<<192, 256, 0, stream>>>(mw2, w2t);

    lin_in_gemm<<<NN/32, 256, 0, stream>>>(emb, posrel, z, lin_w, lin_b, x);

    for (int l = 0; l < NL; ++l) {
        const float* W1 = mw1 + (size_t)l*257*HD;
        pq_gemm<<<NN/64, 256, 0, stream>>>(x, W1, Pb, Qb);
        (void)hipMemsetAsync(msum, 0, (size_t)NN*HD*sizeof(float), stream);
        edge_msg_kernel<<<NE/256, 256, 0, stream>>>(Pb, Qb, posrel, rcS,
                                                    W1 + 256*HD, mb1 + l*HD,
                                                    w2t + (size_t)l*16384, mb2 + l*HD, msum);
        upd_gemm<<<NN/128, 256, 0, stream>>>(x, msum, degi,
                                             uw + (size_t)l*256*HD, ub + l*HD, x);
    }

    gsum_kernel   <<<NN*32/256, 256, 0, stream>>>(x, batch, ntype, gsum);
    readout_kernel<<<NB, 128, 0, stream>>>(gsum, lcnt, rw1, rb1, rw2, rb2, (float*)d_out);
}

// Round 8
// 1458.580 us; speedup vs baseline: 2.1602x; 1.3939x over previous
//
#include <hip/hip_runtime.h>
#include <hip/hip_bf16.h>
#include <math.h>

#define NN 65536
#define NE 1048576
#define NB 64
#define HD 128
#define NL 3

// ---- workspace layout (float offsets) ----
#define O_CSUM   0           // 64*3
#define O_CCNT   192         // 64
#define O_LCNT   256         // 64
#define O_GSUM   320         // 64*128 -> ends 8512
#define O_DEGI   8512        // 65536 ints -> ends 74048
#define O_POSREL 74048       // 65536*3 -> ends 270656
#define O_RC     270656      // 1048576 u32 (row<<16|col, sorted by row) -> ends 1319232
#define O_X      1319232     // 65536*128  (rowStart/cnt alias its head pre-init)
#define O_P      9707840     // 65536*128
#define O_Q      18096448    // 65536*128
#define O_MSUM   26485056    // 65536*128 -> ends 34873664
#define O_W2T    34873664    // 3*128*128 bf16 -> ends 34898240 (~139.6 MB)

typedef __attribute__((ext_vector_type(8))) short bf16x8;
typedef __attribute__((ext_vector_type(4))) float f32x4;

__device__ __forceinline__ void atomAdd(float* p, float v) {
    unsafeAtomicAdd(p, v);   // native global_atomic_add_f32 on gfx950
}

__device__ __forceinline__ unsigned short f2bf(float f) {
    union { __hip_bfloat16 h; unsigned short u; } cv;
    cv.h = __float2bfloat16(f);
    return cv.u;
}

__device__ __forceinline__ void fma4(float4& acc, float a, const float4 w) {
    acc.x += a*w.x; acc.y += a*w.y; acc.z += a*w.z; acc.w += a*w.w;
}

// ---------------- stats: per-graph centroid sums, node counts, ligand counts --------------
__global__ __launch_bounds__(256) void stats_kernel(
    const float* __restrict__ pos, const int* __restrict__ batch,
    const int* __restrict__ ntype,
    float* __restrict__ csum, float* __restrict__ ccnt, float* __restrict__ lcnt)
{
    __shared__ float s[NB * 5];
    const int tid = threadIdx.x;
    for (int i = tid; i < NB * 5; i += 256) s[i] = 0.f;
    __syncthreads();
    const int n = blockIdx.x * 256 + tid;
    const int b = batch[n];
    atomicAdd(&s[b*5+0], pos[n*3+0]);
    atomicAdd(&s[b*5+1], pos[n*3+1]);
    atomicAdd(&s[b*5+2], pos[n*3+2]);
    atomicAdd(&s[b*5+3], 1.f);
    if (ntype[n] == 1) atomicAdd(&s[b*5+4], 1.f);
    __syncthreads();
    for (int i = tid; i < NB * 5; i += 256) {
        float v = s[i];
        if (v != 0.f) {
            int b2 = i / 5, f = i - b2*5;
            if (f < 3)       atomAdd(&csum[b2*3+f], v);
            else if (f == 3) atomAdd(&ccnt[b2], v);
            else             atomAdd(&lcnt[b2], v);
        }
    }
}

// ---------------- integer degree histogram of `row` ----------------
__global__ __launch_bounds__(256) void deg_kernel(const int* __restrict__ row, int* __restrict__ degi)
{
    const int e = blockIdx.x * 256 + threadIdx.x;
    atomicAdd(&degi[row[e]], 1);
}

// ---------------- single-block exclusive scan of degi[65536] -> rowStart ----------------
__global__ __launch_bounds__(1024) void scan_kernel(const int* __restrict__ degi, int* __restrict__ rowStart)
{
    __shared__ int s[1024];
    __shared__ int carry;
    const int tid = threadIdx.x;
    if (tid == 0) carry = 0;
    __syncthreads();
    for (int c = 0; c < NN / 1024; ++c) {
        const int v = degi[c*1024 + tid];
        s[tid] = v;
        __syncthreads();
        for (int off = 1; off < 1024; off <<= 1) {
            int t = (tid >= off) ? s[tid - off] : 0;
            __syncthreads();
            s[tid] += t;
            __syncthreads();
        }
        rowStart[c*1024 + tid] = carry + s[tid] - v;   // exclusive
        __syncthreads();
        if (tid == 1023) carry += s[1023];
        __syncthreads();
    }
}

// ---------------- counting-sort scatter: rcS[p] = (row<<16)|col, sorted by row --------------
__global__ __launch_bounds__(256) void scatter_kernel(
    const int* __restrict__ row, const int* __restrict__ col,
    const int* __restrict__ rowStart, int* __restrict__ cnt,
    unsigned int* __restrict__ rcS)
{
    const int e = blockIdx.x * 256 + threadIdx.x;
    const int r = row[e], c = col[e];
    const int p = rowStart[r] + atomicAdd(&cnt[r], 1);
    rcS[p] = ((unsigned)r << 16) | (unsigned)c;
}

// ---------------- pos_rel = pos - center[batch] ----------------
__global__ __launch_bounds__(256) void posrel_kernel(
    const float* __restrict__ pos, const int* __restrict__ batch,
    const float* __restrict__ csum, const float* __restrict__ ccnt,
    float* __restrict__ posrel)
{
    const int n = blockIdx.x * 256 + threadIdx.x;
    const int b = batch[n];
    const float inv = 1.f / fmaxf(ccnt[b], 1.f);
    posrel[n*3+0] = pos[n*3+0] - csum[b*3+0]*inv;
    posrel[n*3+1] = pos[n*3+1] - csum[b*3+1]*inv;
    posrel[n*3+2] = pos[n*3+2] - csum[b*3+2]*inv;
}

// ---------------- W2 -> transposed bf16: w2t[l][n][k] = bf16(W2_l[k][n]) ----------------
__global__ __launch_bounds__(256) void w2bf_kernel(const float* __restrict__ mw2,
                                                   unsigned short* __restrict__ w2t)
{
    const int idx = blockIdx.x * 256 + threadIdx.x;   // 49152 total
    const int l = idx >> 14, rem = idx & 16383, n = rem >> 7, k = rem & 127;
    w2t[idx] = f2bf(mw2[(l << 14) + k*128 + n]);
}

// ---------------- lin_in: x = concat(emb[z], posrel) @ lin_in_w + b (K=131) ----------------
__global__ __launch_bounds__(256) void lin_in_gemm(
    const float* __restrict__ emb, const float* __restrict__ posrel,
    const int* __restrict__ zidx,
    const float* __restrict__ W, const float* __restrict__ bias,
    float* __restrict__ out)
{
    __shared__ __align__(16) float Asm[32][132];
    __shared__ __align__(16) float Wsm[32][128];
    const int tid = threadIdx.x;
    const int n0  = blockIdx.x * 32;
    const float4* __restrict__ A0f4 = (const float4*)emb;

    for (int idx4 = tid; idx4 < 1024; idx4 += 256) {
        int i = idx4 >> 5, k4 = idx4 & 31;
        int zz = zidx[n0 + i];
        *(float4*)&Asm[i][k4*4] = A0f4[zz*32 + k4];
    }
    if (tid < 96) { int i = tid / 3, d = tid - i*3; Asm[i][128+d] = posrel[(n0+i)*3 + d]; }
    else if (tid < 128) { Asm[tid-96][131] = 0.f; }

    const int tj = tid & 31;
    const int tn = tid >> 5;
    float acc[4][4];
    #pragma unroll
    for (int r = 0; r < 4; ++r)
        #pragma unroll
        for (int c = 0; c < 4; ++c) acc[r][c] = 0.f;

    const float4* __restrict__ Wf4 = (const float4*)W;
    #pragma unroll 1
    for (int kc = 0; kc < 131; kc += 32) {
        const int kend = (131 - kc < 32) ? (131 - kc) : 32;
        __syncthreads();
        for (int idx4 = tid; idx4 < kend*32; idx4 += 256) {
            int kk = idx4 >> 5, j4 = idx4 & 31;
            *(float4*)&Wsm[kk][j4*4] = Wf4[(kc+kk)*32 + j4];
        }
        __syncthreads();
        for (int kk = 0; kk < kend; ++kk) {
            const float4 w = *(const float4*)&Wsm[kk][tj*4];
            #pragma unroll
            for (int r = 0; r < 4; ++r) {
                const float a = Asm[tn*4+r][kc+kk];
                acc[r][0] += a*w.x; acc[r][1] += a*w.y; acc[r][2] += a*w.z; acc[r][3] += a*w.w;
            }
        }
    }

    const float4 bias4 = ((const float4*)bias)[tj];
    #pragma unroll
    for (int r = 0; r < 4; ++r) {
        const int node = n0 + tn*4 + r;
        float4 o;
        o.x = acc[r][0] + bias4.x; o.y = acc[r][1] + bias4.y;
        o.z = acc[r][2] + bias4.z; o.w = acc[r][3] + bias4.w;
        ((float4*)out)[node*32 + tj] = o;
    }
}

// ---------------- fused P/Q GEMM: P = x@W1[0:128], Q = x@W1[128:256] (no bias) -----------
__global__ __launch_bounds__(256) void pq_gemm(
    const float* __restrict__ x, const float* __restrict__ W1,
    float* __restrict__ P, float* __restrict__ Q)
{
    __shared__ __align__(16) float Asm[64][33];
    __shared__ __align__(16) float Wsm[32][256];
    const int tid = threadIdx.x;
    const int n0 = blockIdx.x * 64;
    const int cg = tid >> 4;      // 0..15: cols cg*16..+15
    const int ng = tid & 15;      // nodes ng + 16r
    const float4* __restrict__ xf4 = (const float4*)x;
    const float4* __restrict__ Wf4 = (const float4*)W1;

    float4 acc[4][4];
    #pragma unroll
    for (int r = 0; r < 4; ++r)
        #pragma unroll
        for (int q = 0; q < 4; ++q) acc[r][q] = make_float4(0.f, 0.f, 0.f, 0.f);

    #pragma unroll 1
    for (int kc = 0; kc < 128; kc += 32) {
        __syncthreads();
        #pragma unroll
        for (int it = 0; it < 2; ++it) {
            int idx4 = tid + it*256;
            int i = idx4 >> 3, k4 = idx4 & 7;
            *(float4*)&Asm[i][k4*4] = xf4[(n0+i)*32 + (kc>>2) + k4];
        }
        #pragma unroll
        for (int it = 0; it < 8; ++it) {
            int idx4 = tid + it*256;
            int kk = idx4 >> 6, j4 = idx4 & 63;
            float4 v = (j4 < 32) ? Wf4[(kc+kk)*32 + j4] : Wf4[(128+kc+kk)*32 + (j4-32)];
            *(float4*)&Wsm[kk][j4*4] = v;
        }
        __syncthreads();
        #pragma unroll 4
        for (int kk = 0; kk < 32; ++kk) {
            float a[4];
            #pragma unroll
            for (int r = 0; r < 4; ++r) a[r] = Asm[ng + 16*r][kk];
            float4 wv[4];
            #pragma unroll
            for (int q = 0; q < 4; ++q) wv[q] = *(const float4*)&Wsm[kk][cg*16 + q*4];
            #pragma unroll
            for (int r = 0; r < 4; ++r)
                #pragma unroll
                for (int q = 0; q < 4; ++q) fma4(acc[r][q], a[r], wv[q]);
        }
    }

    float4* outP = (float4*)P;
    float4* outQ = (float4*)Q;
    #pragma unroll
    for (int r = 0; r < 4; ++r) {
        const int node = n0 + ng + 16*r;
        #pragma unroll
        for (int q = 0; q < 4; ++q) {
            if (cg < 8) outP[node*32 + cg*4 + q] = acc[r][q];
            else        outQ[node*32 + (cg-8)*4 + q] = acc[r][q];
        }
    }
}

// ---------------- update GEMM: x = relu(concat(x, msum/deg) @ W + b), K=256 ----------------
__global__ __launch_bounds__(256) void upd_gemm(
    const float* __restrict__ x, const float* __restrict__ msum,
    const int* __restrict__ degi,
    const float* __restrict__ W, const float* __restrict__ bias,
    float* __restrict__ xout)
{
    __shared__ __align__(16) float Asm[128][33];
    __shared__ __align__(16) float Wsm[32][128];
    const int tid = threadIdx.x;
    const int n0 = blockIdx.x * 128;
    const int cg = tid >> 5;      // 0..7: cols cg*16..+15
    const int ng = tid & 31;      // nodes ng + 32r
    const float4* __restrict__ xf4 = (const float4*)x;
    const float4* __restrict__ mf4 = (const float4*)msum;
    const float4* __restrict__ Wf4 = (const float4*)W;

    float4 acc[4][4];
    #pragma unroll
    for (int r = 0; r < 4; ++r)
        #pragma unroll
        for (int q = 0; q < 4; ++q) acc[r][q] = make_float4(0.f, 0.f, 0.f, 0.f);

    #pragma unroll 1
    for (int kc = 0; kc < 256; kc += 32) {
        __syncthreads();
        #pragma unroll
        for (int it = 0; it < 4; ++it) {
            int idx4 = tid + it*256;
            int i = idx4 >> 3, k4 = idx4 & 7;
            float4 v;
            if (kc < 128) {
                v = xf4[(n0+i)*32 + (kc>>2) + k4];
            } else {
                v = mf4[(n0+i)*32 + ((kc-128)>>2) + k4];
                const float inv = 1.f / fmaxf((float)degi[n0+i], 1.f);
                v.x *= inv; v.y *= inv; v.z *= inv; v.w *= inv;
            }
            *(float4*)&Asm[i][k4*4] = v;
        }
        #pragma unroll
        for (int it = 0; it < 4; ++it) {
            int idx4 = tid + it*256;
            int kk = idx4 >> 5, j4 = idx4 & 31;
            *(float4*)&Wsm[kk][j4*4] = Wf4[(kc+kk)*32 + j4];
        }
        __syncthreads();
        #pragma unroll 4
        for (int kk = 0; kk < 32; ++kk) {
            float a[4];
            #pragma unroll
            for (int r = 0; r < 4; ++r) a[r] = Asm[ng + 32*r][kk];
            float4 wv[4];
            #pragma unroll
            for (int q = 0; q < 4; ++q) wv[q] = *(const float4*)&Wsm[kk][cg*16 + q*4];
            #pragma unroll
            for (int r = 0; r < 4; ++r)
                #pragma unroll
                for (int q = 0; q < 4; ++q) fma4(acc[r][q], a[r], wv[q]);
        }
    }

    float4* outx = (float4*)xout;
    #pragma unroll
    for (int r = 0; r < 4; ++r) {
        const int node = n0 + ng + 32*r;
        #pragma unroll
        for (int q = 0; q < 4; ++q) {
            const float4 b4 = ((const float4*)bias)[cg*4 + q];
            float4 o;
            o.x = fmaxf(acc[r][q].x + b4.x, 0.f);
            o.y = fmaxf(acc[r][q].y + b4.y, 0.f);
            o.z = fmaxf(acc[r][q].z + b4.z, 0.f);
            o.w = fmaxf(acc[r][q].w + b4.w, 0.f);
            outx[node*32 + cg*4 + q] = o;
        }
    }
}

// ---------------- fused edge kernel over ROW-SORTED edges, MFMA phase 2 ----------------
// NO LDS, NO BARRIER. Edge->slot remap g(m,i) = (i>>2)*16 + m*4 + (i&3) makes each
// lane's 16 C-edges per col CONTIGUOUS in sorted order -> run-aggregation across all 16
// -> ~2.4x fewer global atomics (the measured ceiling of rounds 5-7).
__global__ __launch_bounds__(256) void edge_msg_kernel(
    const float* __restrict__ P, const float* __restrict__ Q,
    const float* __restrict__ posrel,
    const unsigned int* __restrict__ rcS,
    const float* __restrict__ w1c, const float* __restrict__ b1,
    const unsigned short* __restrict__ w2t,   // [128 n][128 k] bf16 (transposed)
    const float* __restrict__ b2,
    float* __restrict__ msum)
{
    const int tid = threadIdx.x;
    const long e0 = (long)blockIdx.x * 256;
    const int l  = tid & 63;
    const int w  = tid >> 6;
    const int mr = l & 15;
    const int qd = l >> 4;
    const long ebase = e0 + w*64;

    // ---- A-side edges: eA[m] = ebase + (mr>>2)*16 + m*4 + (mr&3) ----
    const int aoff = ((mr >> 2) << 4) + (mr & 3);
    int ecol[4], erow[4];
    float edist[4];
    #pragma unroll
    for (int m = 0; m < 4; ++m) {
        const unsigned rc = rcS[ebase + aoff + m*4];
        erow[m] = (int)(rc >> 16); ecol[m] = (int)(rc & 0xffffu);
    }
    #pragma unroll
    for (int m = 0; m < 4; ++m) {
        const int c = ecol[m], r = erow[m];
        const float dx = posrel[c*3+0] - posrel[r*3+0];
        const float dy = posrel[c*3+1] - posrel[r*3+1];
        const float dz = posrel[c*3+2] - posrel[r*3+2];
        edist[m] = sqrtf(dx*dx + dy*dy + dz*dz);
    }

    // ---- scatter rows: 16 contiguous edges at ebase + qd*16 (uint4 x4 loads) ----
    unsigned rcv[16];
    {
        const uint4* rc4 = (const uint4*)&rcS[ebase + qd*16];
        #pragma unroll
        for (int i = 0; i < 4; ++i) {
            const uint4 v = rc4[i];
            rcv[i*4+0] = v.x >> 16; rcv[i*4+1] = v.y >> 16;
            rcv[i*4+2] = v.z >> 16; rcv[i*4+3] = v.w >> 16;
        }
    }

    // ---- build A-fragments ----
    bf16x8 afr[4][4];
    const float4* __restrict__ Pf4 = (const float4*)P;
    const float4* __restrict__ Qf4 = (const float4*)Q;
    const float4* __restrict__ c1f4 = (const float4*)w1c;
    const float4* __restrict__ b1f4 = (const float4*)b1;
    #pragma unroll
    for (int kk = 0; kk < 4; ++kk) {
        const int kb4 = (kk*32 + qd*8) >> 2;
        const float4 c0  = c1f4[kb4],   c1v = c1f4[kb4+1];
        const float4 b0  = b1f4[kb4],   b1v = b1f4[kb4+1];
        #pragma unroll
        for (int m = 0; m < 4; ++m) {
            const float4 p0 = Pf4[ecol[m]*32 + kb4];
            const float4 p1 = Pf4[ecol[m]*32 + kb4 + 1];
            const float4 q0 = Qf4[erow[m]*32 + kb4];
            const float4 q1 = Qf4[erow[m]*32 + kb4 + 1];
            const float d = edist[m];
            union { bf16x8 v; unsigned short u[8]; } au;
            au.u[0] = f2bf(fmaxf(p0.x + q0.x + d*c0.x  + b0.x,  0.f));
            au.u[1] = f2bf(fmaxf(p0.y + q0.y + d*c0.y  + b0.y,  0.f));
            au.u[2] = f2bf(fmaxf(p0.z + q0.z + d*c0.z  + b0.z,  0.f));
            au.u[3] = f2bf(fmaxf(p0.w + q0.w + d*c0.w  + b0.w,  0.f));
            au.u[4] = f2bf(fmaxf(p1.x + q1.x + d*c1v.x + b1v.x, 0.f));
            au.u[5] = f2bf(fmaxf(p1.y + q1.y + d*c1v.y + b1v.y, 0.f));
            au.u[6] = f2bf(fmaxf(p1.z + q1.z + d*c1v.z + b1v.z, 0.f));
            au.u[7] = f2bf(fmaxf(p1.w + q1.w + d*c1v.w + b1v.w, 0.f));
            afr[m][kk] = au.v;
        }
    }

    // ---- per col-tile (software-pipelined B loads from global, L1-resident) ----
    const bf16x8* __restrict__ w2tv = (const bf16x8*)w2t;   // [n][16] bf16x8 chunks
    bf16x8 bfr[4];
    #pragma unroll
    for (int kk = 0; kk < 4; ++kk)
        bfr[kk] = w2tv[(0*16 + mr)*16 + kk*4 + qd];

    #pragma unroll 1
    for (int t = 0; t < 8; ++t) {
        bf16x8 bnext[4];
        if (t < 7) {
            #pragma unroll
            for (int kk = 0; kk < 4; ++kk)
                bnext[kk] = w2tv[((t+1)*16 + mr)*16 + kk*4 + qd];
        }
        const int colg = t*16 + mr;
        const float bb = b2[colg];

        f32x4 acc[4];
        #pragma unroll
        for (int m = 0; m < 4; ++m) acc[m] = (f32x4){0.f, 0.f, 0.f, 0.f};
        #pragma unroll
        for (int kk = 0; kk < 4; ++kk)
            #pragma unroll
            for (int m = 0; m < 4; ++m)
                acc[m] = __builtin_amdgcn_mfma_f32_16x16x32_bf16(afr[m][kk], bfr[kk], acc[m], 0, 0, 0);

        // C row i of m-tile m = edge g(m, qd*4+r) = ebase + qd*16 + m*4 + r
        // flattened order j = m*4 + r matches sorted-edge order -> one run across all 16
        int rprev = -1;
        float run = 0.f;
        #pragma unroll
        for (int m = 0; m < 4; ++m) {
            #pragma unroll
            for (int r4 = 0; r4 < 4; ++r4) {
                const int rw = (int)rcv[m*4 + r4];
                const float v = fmaxf(acc[m][r4] + bb, 0.f);
                if (rw != rprev) {
                    if (rprev >= 0) atomAdd(&msum[(long)rprev*HD + colg], run);
                    rprev = rw; run = v;
                } else {
                    run += v;
                }
            }
        }
        atomAdd(&msum[(long)rprev*HD + colg], run);

        #pragma unroll
        for (int kk = 0; kk < 4; ++kk) bfr[kk] = bnext[kk];
    }
}

// ---------------- ligand-masked per-graph sum of x ----------------
__global__ __launch_bounds__(256) void gsum_kernel(
    const float* __restrict__ x, const int* __restrict__ batch,
    const int* __restrict__ ntype, float* __restrict__ gsum)
{
    const int idx = blockIdx.x * 256 + threadIdx.x;
    const int n = idx >> 5, k4 = idx & 31;
    if (ntype[n] != 1) return;
    const int b = batch[n];
    const float4 v = ((const float4*)x)[n*32 + k4];
    float* dst = &gsum[b*HD + k4*4];
    atomAdd(dst+0, v.x); atomAdd(dst+1, v.y);
    atomAdd(dst+2, v.z); atomAdd(dst+3, v.w);
}

// ---------------- readout: hg = relu(g@ro_w1+b1); out = hg@ro_w2 + b2 ----------------
__global__ __launch_bounds__(128) void readout_kernel(
    const float* __restrict__ gsum, const float* __restrict__ lcnt,
    const float* __restrict__ w1, const float* __restrict__ b1,
    const float* __restrict__ w2, const float* __restrict__ b2,
    float* __restrict__ out)
{
    __shared__ float gs[HD];
    __shared__ float red[2];
    const int b = blockIdx.x, j = threadIdx.x;
    gs[j] = gsum[b*HD + j] / fmaxf(lcnt[b], 1.f);
    __syncthreads();
    float acc = b1[j];
    for (int k = 0; k < HD; ++k) acc += gs[k]*w1[k*HD + j];
    float hg = fmaxf(acc, 0.f) * w2[j];
    #pragma unroll
    for (int off = 32; off > 0; off >>= 1) hg += __shfl_down(hg, off, 64);
    if ((j & 63) == 0) red[j >> 6] = hg;
    __syncthreads();
    if (j == 0) out[b] = red[0] + red[1] + b2[0];
}

extern "C" void kernel_launch(void* const* d_in, const int* in_sizes, int n_in,
                              void* d_out, int out_size, void* d_ws, size_t ws_size,
                              hipStream_t stream)
{
    const float* pos   = (const float*)d_in[0];
    const int*   z     = (const int*)d_in[1];
    const int*   batch = (const int*)d_in[2];
    const int*   eidx  = (const int*)d_in[3];
    const int*   ntype = (const int*)d_in[4];
    const float* emb   = (const float*)d_in[5];
    const float* lin_w = (const float*)d_in[6];
    const float* lin_b = (const float*)d_in[7];
    const float* mw1   = (const float*)d_in[8];
    const float* mb1   = (const float*)d_in[9];
    const float* mw2   = (const float*)d_in[10];
    const float* mb2   = (const float*)d_in[11];
    const float* uw    = (const float*)d_in[12];
    const float* ub    = (const float*)d_in[13];
    const float* rw1   = (const float*)d_in[14];
    const float* rb1   = (const float*)d_in[15];
    const float* rw2   = (const float*)d_in[16];
    const float* rb2   = (const float*)d_in[17];

    const int* row = eidx;        // edge_index[0]
    const int* col = eidx + NE;   // edge_index[1]

    float* ws     = (float*)d_ws;
    float* csum   = ws + O_CSUM;
    float* ccnt   = ws + O_CCNT;
    float* lcnt   = ws + O_LCNT;
    float* gsum   = ws + O_GSUM;
    int*   degi   = (int*)(ws + O_DEGI);
    float* posrel = ws + O_POSREL;
    unsigned int* rcS = (unsigned int*)(ws + O_RC);
    float* x      = ws + O_X;
    float* Pb     = ws + O_P;
    float* Qb     = ws + O_Q;
    float* msum   = ws + O_MSUM;
    unsigned short* w2t = (unsigned short*)(ws + O_W2T);
    int* rowStart = (int*)x;
    int* cnt      = (int*)x + NN;

    (void)hipMemsetAsync(ws, 0, (size_t)(O_DEGI + NN) * sizeof(float), stream);
    (void)hipMemsetAsync(cnt, 0, (size_t)NN * sizeof(int), stream);

    stats_kernel  <<<NN/256, 256, 0, stream>>>(pos, batch, ntype, csum, ccnt, lcnt);
    deg_kernel    <<<NE/256, 256, 0, stream>>>(row, degi);
    posrel_kernel <<<NN/256, 256, 0, stream>>>(pos, batch, csum, ccnt, posrel);
    scan_kernel   <<<1, 1024, 0, stream>>>(degi, rowStart);
    scatter_kernel<<<NE/256, 256, 0, stream>>>(row, col, rowStart, cnt, rcS);
    w2bf_kernel   <<<192, 256, 0, stream>>>(mw2, w2t);

    lin_in_gemm<<<NN/32, 256, 0, stream>>>(emb, posrel, z, lin_w, lin_b, x);

    for (int l = 0; l < NL; ++l) {
        const float* W1 = mw1 + (size_t)l*257*HD;
        pq_gemm<<<NN/64, 256, 0, stream>>>(x, W1, Pb, Qb);
        (void)hipMemsetAsync(msum, 0, (size_t)NN*HD*sizeof(float), stream);
        edge_msg_kernel<<<NE/256, 256, 0, stream>>>(Pb, Qb, posrel, rcS,
                                                    W1 + 256*HD, mb1 + l*HD,
                                                    w2t + (size_t)l*16384, mb2 + l*HD, msum);
        upd_gemm<<<NN/128, 256, 0, stream>>>(x, msum, degi,
                                             uw + (size_t)l*256*HD, ub + l*HD, x);
    }

    gsum_kernel   <<<NN*32/256, 256, 0, stream>>>(x, batch, ntype, gsum);
    readout_kernel<<<NB, 128, 0, stream>>>(gsum, lcnt, rw1, rb1, rw2, rb2, (float*)d_out);
}

// Round 10
// 1245.588 us; speedup vs baseline: 2.5296x; 1.1710x over previous
//
#include <hip/hip_runtime.h>
#include <hip/hip_bf16.h>
#include <math.h>

#define NN 65536
#define NE 1048576
#define NB 64
#define HD 128
#define NL 3

// ---- workspace layout (float offsets) ----
#define O_CSUM   0
#define O_CCNT   192
#define O_LCNT   256
#define O_GSUM   320         // -> 8512
#define O_DEGI   8512        // -> 74048
#define O_POSREL 74048       // -> 270656
#define O_RC     270656      // -> 1319232
#define O_XHI    1319232     // NN*128 ushort = 4194304 float slots -> 5513536
#define O_XLO    5513536     // -> 9707840
#define O_P      9707840     // -> 18096448
#define O_Q      18096448    // -> 26485056
#define O_MSUM   26485056    // -> 34873664
#define O_W2T    34873664    // 3*128*128 bf16 -> 34898240
#define O_W1TH   34898240    // 3*256*128 bf16 -> 34947392
#define O_W1TL   34947392    // -> 34996544
#define O_WUTH   34996544    // 3*128*256 bf16 -> 35045696
#define O_WUTL   35045696    // -> 35094848
#define O_CHK    35094848    // 256 ints -> 35095104 (~140.4 MB)

typedef __attribute__((ext_vector_type(8))) short bf16x8;
typedef __attribute__((ext_vector_type(4))) float f32x4;

__device__ __forceinline__ void atomAdd(float* p, float v) { unsafeAtomicAdd(p, v); }

__device__ __forceinline__ unsigned short f2bf(float f) {
    union { __hip_bfloat16 h; unsigned short u; } cv;
    cv.h = __float2bfloat16(f);
    return cv.u;
}
__device__ __forceinline__ float bf2f(unsigned short u) {
    union { float f; unsigned v; } c; c.v = ((unsigned)u) << 16; return c.f;
}
__device__ __forceinline__ void split2(float v, unsigned short& h, unsigned short& l) {
    h = f2bf(v); l = f2bf(v - bf2f(h));
}

// ---------------- stats ----------------
__global__ __launch_bounds__(256) void stats_kernel(
    const float* __restrict__ pos, const int* __restrict__ batch,
    const int* __restrict__ ntype,
    float* __restrict__ csum, float* __restrict__ ccnt, float* __restrict__ lcnt)
{
    __shared__ float s[NB * 5];
    const int tid = threadIdx.x;
    for (int i = tid; i < NB * 5; i += 256) s[i] = 0.f;
    __syncthreads();
    const int n = blockIdx.x * 256 + tid;
    const int b = batch[n];
    atomicAdd(&s[b*5+0], pos[n*3+0]);
    atomicAdd(&s[b*5+1], pos[n*3+1]);
    atomicAdd(&s[b*5+2], pos[n*3+2]);
    atomicAdd(&s[b*5+3], 1.f);
    if (ntype[n] == 1) atomicAdd(&s[b*5+4], 1.f);
    __syncthreads();
    for (int i = tid; i < NB * 5; i += 256) {
        float v = s[i];
        if (v != 0.f) {
            int b2 = i / 5, f = i - b2*5;
            if (f < 3)       atomAdd(&csum[b2*3+f], v);
            else if (f == 3) atomAdd(&ccnt[b2], v);
            else             atomAdd(&lcnt[b2], v);
        }
    }
}

// ---------------- degree histogram ----------------
__global__ __launch_bounds__(256) void deg_kernel(const int* __restrict__ row, int* __restrict__ degi)
{
    const int e = blockIdx.x * 256 + threadIdx.x;
    atomicAdd(&degi[row[e]], 1);
}

// ---------------- two-level scan ----------------
__global__ __launch_bounds__(256) void scanA_kernel(const int* __restrict__ degi, int* __restrict__ chunkSum)
{
    __shared__ int red[4];
    const int t = threadIdx.x, b = blockIdx.x;
    int v = degi[b*256 + t];
    #pragma unroll
    for (int off = 32; off > 0; off >>= 1) v += __shfl_down(v, off, 64);
    if ((t & 63) == 0) red[t >> 6] = v;
    __syncthreads();
    if (t == 0) chunkSum[b] = red[0] + red[1] + red[2] + red[3];
}

__global__ __launch_bounds__(256) void scanB_kernel(int* __restrict__ chunkSum)
{
    __shared__ int s[256];
    const int t = threadIdx.x;
    const int v = chunkSum[t];
    s[t] = v;
    __syncthreads();
    #pragma unroll
    for (int off = 1; off < 256; off <<= 1) {
        int u = (t >= off) ? s[t - off] : 0;
        __syncthreads();
        s[t] += u;
        __syncthreads();
    }
    chunkSum[t] = s[t] - v;   // exclusive
}

__global__ __launch_bounds__(256) void scanC_kernel(const int* __restrict__ degi,
                                                    const int* __restrict__ chunkOff,
                                                    int* __restrict__ rowStart)
{
    __shared__ int s[256];
    const int t = threadIdx.x, b = blockIdx.x;
    const int v = degi[b*256 + t];
    s[t] = v;
    __syncthreads();
    #pragma unroll
    for (int off = 1; off < 256; off <<= 1) {
        int u = (t >= off) ? s[t - off] : 0;
        __syncthreads();
        s[t] += u;
        __syncthreads();
    }
    rowStart[b*256 + t] = chunkOff[b] + s[t] - v;
}

// ---------------- counting-sort scatter ----------------
__global__ __launch_bounds__(256) void scatter_kernel(
    const int* __restrict__ row, const int* __restrict__ col,
    const int* __restrict__ rowStart, int* __restrict__ cnt,
    unsigned int* __restrict__ rcS)
{
    const int e = blockIdx.x * 256 + threadIdx.x;
    const int r = row[e], c = col[e];
    const int p = rowStart[r] + atomicAdd(&cnt[r], 1);
    rcS[p] = ((unsigned)r << 16) | (unsigned)c;
}

// ---------------- pos_rel ----------------
__global__ __launch_bounds__(256) void posrel_kernel(
    const float* __restrict__ pos, const int* __restrict__ batch,
    const float* __restrict__ csum, const float* __restrict__ ccnt,
    float* __restrict__ posrel)
{
    const int n = blockIdx.x * 256 + threadIdx.x;
    const int b = batch[n];
    const float inv = 1.f / fmaxf(ccnt[b], 1.f);
    posrel[n*3+0] = pos[n*3+0] - csum[b*3+0]*inv;
    posrel[n*3+1] = pos[n*3+1] - csum[b*3+1]*inv;
    posrel[n*3+2] = pos[n*3+2] - csum[b*3+2]*inv;
}

// ---------------- W2 -> transposed bf16 ----------------
__global__ __launch_bounds__(256) void w2bf_kernel(const float* __restrict__ mw2,
                                                   unsigned short* __restrict__ w2t)
{
    const int idx = blockIdx.x * 256 + threadIdx.x;   // 49152
    const int l = idx >> 14, rem = idx & 16383, n = rem >> 7, k = rem & 127;
    w2t[idx] = f2bf(mw2[(l << 14) + k*128 + n]);
}

// ---------------- W1T / WuT hi/lo prep (98304 threads) ----------------
__global__ __launch_bounds__(256) void wprep_kernel(
    const float* __restrict__ mw1, const float* __restrict__ uw,
    unsigned short* __restrict__ w1th, unsigned short* __restrict__ w1tl,
    unsigned short* __restrict__ wuth, unsigned short* __restrict__ wutl)
{
    const int idx = blockIdx.x * 256 + threadIdx.x;   // 98304
    {   // W1T: [l][c<256][k<128]; c<128: mw1[l][k][c] (P); c>=128: mw1[l][128+k][c-128] (Q)
        const int l = idx >> 15, rem = idx & 32767, c = rem >> 7, k = rem & 127;
        const int kk = (c < 128) ? k : (128 + k);
        const int cc = c & 127;
        const float v = mw1[l*257*128 + kk*128 + cc];
        unsigned short h, lo; split2(v, h, lo);
        w1th[idx] = h; w1tl[idx] = lo;
    }
    {   // WuT: [l][c<128][k<256] = uw[l][k][c]
        const int l = idx >> 15, rem = idx & 32767, c = rem >> 8, k = rem & 255;
        const float v = uw[l*256*128 + k*128 + c];
        unsigned short h, lo; split2(v, h, lo);
        wuth[idx] = h; wutl[idx] = lo;
    }
}

// ---------------- lin_in: x = concat(emb[z], posrel) @ W + b -> xhi/xlo ----------------
__global__ __launch_bounds__(256) void lin_in_gemm(
    const float* __restrict__ emb, const float* __restrict__ posrel,
    const int* __restrict__ zidx,
    const float* __restrict__ W, const float* __restrict__ bias,
    unsigned short* __restrict__ xhi, unsigned short* __restrict__ xlo)
{
    __shared__ __align__(16) float Asm[32][132];
    __shared__ __align__(16) float Wsm[32][128];
    const int tid = threadIdx.x;
    const int n0  = blockIdx.x * 32;
    const float4* __restrict__ A0f4 = (const float4*)emb;

    for (int idx4 = tid; idx4 < 1024; idx4 += 256) {
        int i = idx4 >> 5, k4 = idx4 & 31;
        int zz = zidx[n0 + i];
        *(float4*)&Asm[i][k4*4] = A0f4[zz*32 + k4];
    }
    if (tid < 96) { int i = tid / 3, d = tid - i*3; Asm[i][128+d] = posrel[(n0+i)*3 + d]; }
    else if (tid < 128) { Asm[tid-96][131] = 0.f; }

    const int tj = tid & 31;
    const int tn = tid >> 5;
    float acc[4][4];
    #pragma unroll
    for (int r = 0; r < 4; ++r)
        #pragma unroll
        for (int c = 0; c < 4; ++c) acc[r][c] = 0.f;

    const float4* __restrict__ Wf4 = (const float4*)W;
    #pragma unroll 1
    for (int kc = 0; kc < 131; kc += 32) {
        const int kend = (131 - kc < 32) ? (131 - kc) : 32;
        __syncthreads();
        for (int idx4 = tid; idx4 < kend*32; idx4 += 256) {
            int kk = idx4 >> 5, j4 = idx4 & 31;
            *(float4*)&Wsm[kk][j4*4] = Wf4[(kc+kk)*32 + j4];
        }
        __syncthreads();
        for (int kk = 0; kk < kend; ++kk) {
            const float4 w = *(const float4*)&Wsm[kk][tj*4];
            #pragma unroll
            for (int r = 0; r < 4; ++r) {
                const float a = Asm[tn*4+r][kc+kk];
                acc[r][0] += a*w.x; acc[r][1] += a*w.y; acc[r][2] += a*w.z; acc[r][3] += a*w.w;
            }
        }
    }

    const float4 bias4 = ((const float4*)bias)[tj];
    #pragma unroll
    for (int r = 0; r < 4; ++r) {
        const int node = n0 + tn*4 + r;
        const float o[4] = { acc[r][0] + bias4.x, acc[r][1] + bias4.y,
                             acc[r][2] + bias4.z, acc[r][3] + bias4.w };
        ushort4 h4, l4;
        split2(o[0], h4.x, l4.x); split2(o[1], h4.y, l4.y);
        split2(o[2], h4.z, l4.z); split2(o[3], h4.w, l4.w);
        *(ushort4*)&xhi[node*HD + tj*4] = h4;
        *(ushort4*)&xlo[node*HD + tj*4] = l4;
    }
}

// ---------------- pq GEMM (MFMA, split-bf16 3-pass): P|Q = x @ W1[0:256] ----------------
// block: 64 nodes x 256 cols; wave w -> cols w*64..+63; no LDS, no barriers.
__global__ __launch_bounds__(256) void pq_gemm(
    const unsigned short* __restrict__ xhi, const unsigned short* __restrict__ xlo,
    const unsigned short* __restrict__ w1th, const unsigned short* __restrict__ w1tl,
    float* __restrict__ P, float* __restrict__ Q)
{
    const int tid = threadIdx.x;
    const int l = tid & 63, w = tid >> 6;
    const int mr = l & 15, qd = l >> 4;
    const int n0 = blockIdx.x * 64;
    const int c0 = w * 64;

    f32x4 acc[4][4];
    #pragma unroll
    for (int mt = 0; mt < 4; ++mt)
        #pragma unroll
        for (int nt = 0; nt < 4; ++nt) acc[mt][nt] = (f32x4){0.f,0.f,0.f,0.f};

    #pragma unroll
    for (int ks = 0; ks < 4; ++ks) {
        const int kof = ks*32 + qd*8;
        bf16x8 ah[4], al[4], bh[4], bl[4];
        #pragma unroll
        for (int mt = 0; mt < 4; ++mt) {
            const int node = n0 + mt*16 + mr;
            ah[mt] = *(const bf16x8*)&xhi[node*HD + kof];
            al[mt] = *(const bf16x8*)&xlo[node*HD + kof];
        }
        #pragma unroll
        for (int nt = 0; nt < 4; ++nt) {
            const int c = c0 + nt*16 + mr;
            bh[nt] = *(const bf16x8*)&w1th[c*HD + kof];
            bl[nt] = *(const bf16x8*)&w1tl[c*HD + kof];
        }
        #pragma unroll
        for (int mt = 0; mt < 4; ++mt)
            #pragma unroll
            for (int nt = 0; nt < 4; ++nt) {
                acc[mt][nt] = __builtin_amdgcn_mfma_f32_16x16x32_bf16(ah[mt], bh[nt], acc[mt][nt], 0,0,0);
                acc[mt][nt] = __builtin_amdgcn_mfma_f32_16x16x32_bf16(ah[mt], bl[nt], acc[mt][nt], 0,0,0);
                acc[mt][nt] = __builtin_amdgcn_mfma_f32_16x16x32_bf16(al[mt], bh[nt], acc[mt][nt], 0,0,0);
            }
    }

    float* __restrict__ dst = (w < 2) ? P : Q;
    const int cbase = (w < 2) ? c0 : c0 - 128;
    #pragma unroll
    for (int mt = 0; mt < 4; ++mt)
        #pragma unroll
        for (int nt = 0; nt < 4; ++nt) {
            const int cc = cbase + nt*16 + mr;
            #pragma unroll
            for (int r = 0; r < 4; ++r) {
                const int node = n0 + mt*16 + qd*4 + r;
                dst[(long)node*HD + cc] = acc[mt][nt][r];
            }
        }
}

// ---------------- update GEMM (MFMA, split-bf16 3-pass), K=256, relu, -> xhi/xlo --------
__global__ __launch_bounds__(256) void upd_gemm(
    unsigned short* __restrict__ xhi, unsigned short* __restrict__ xlo,
    const float* __restrict__ msum, const int* __restrict__ degi,
    const unsigned short* __restrict__ wuth, const unsigned short* __restrict__ wutl,
    const float* __restrict__ bias)
{
    const int tid = threadIdx.x;
    const int l = tid & 63, w = tid >> 6;
    const int mr = l & 15, qd = l >> 4;
    const int n0 = blockIdx.x * 64 + w*16;
    const int node = n0 + mr;
    const float inv = 1.f / fmaxf((float)degi[node], 1.f);

    f32x4 acc[8];
    #pragma unroll
    for (int nt = 0; nt < 8; ++nt) acc[nt] = (f32x4){0.f,0.f,0.f,0.f};

    #pragma unroll 1
    for (int ks = 0; ks < 8; ++ks) {
        const int kof = ks*32 + qd*8;
        bf16x8 ah, al;
        if (ks < 4) {
            ah = *(const bf16x8*)&xhi[node*HD + kof];
            al = *(const bf16x8*)&xlo[node*HD + kof];
        } else {
            const int mk = kof - 128;
            const float4 v0 = *(const float4*)&msum[(long)node*HD + mk];
            const float4 v1 = *(const float4*)&msum[(long)node*HD + mk + 4];
            union { bf16x8 v; unsigned short u[8]; } hh, ll;
            float vv[8] = { v0.x*inv, v0.y*inv, v0.z*inv, v0.w*inv,
                            v1.x*inv, v1.y*inv, v1.z*inv, v1.w*inv };
            #pragma unroll
            for (int i = 0; i < 8; ++i) split2(vv[i], hh.u[i], ll.u[i]);
            ah = hh.v; al = ll.v;
        }
        #pragma unroll
        for (int nt = 0; nt < 8; ++nt) {
            const int c = nt*16 + mr;
            const bf16x8 bh = *(const bf16x8*)&wuth[c*256 + kof];
            const bf16x8 bl = *(const bf16x8*)&wutl[c*256 + kof];
            acc[nt] = __builtin_amdgcn_mfma_f32_16x16x32_bf16(ah, bh, acc[nt], 0,0,0);
            acc[nt] = __builtin_amdgcn_mfma_f32_16x16x32_bf16(ah, bl, acc[nt], 0,0,0);
            acc[nt] = __builtin_amdgcn_mfma_f32_16x16x32_bf16(al, bh, acc[nt], 0,0,0);
        }
    }

    #pragma unroll
    for (int nt = 0; nt < 8; ++nt) {
        const int c = nt*16 + mr;
        const float bb = bias[c];
        #pragma unroll
        for (int r = 0; r < 4; ++r) {
            const int nd = n0 + qd*4 + r;
            const float o = fmaxf(acc[nt][r] + bb, 0.f);
            unsigned short h, lo; split2(o, h, lo);
            xhi[nd*HD + c] = h;
            xlo[nd*HD + c] = lo;
        }
    }
}

// ---------------- fused edge kernel (unchanged from round 8) ----------------
__global__ __launch_bounds__(256) void edge_msg_kernel(
    const float* __restrict__ P, const float* __restrict__ Q,
    const float* __restrict__ posrel,
    const unsigned int* __restrict__ rcS,
    const float* __restrict__ w1c, const float* __restrict__ b1,
    const unsigned short* __restrict__ w2t,
    const float* __restrict__ b2,
    float* __restrict__ msum)
{
    const int tid = threadIdx.x;
    const long e0 = (long)blockIdx.x * 256;
    const int l  = tid & 63;
    const int w  = tid >> 6;
    const int mr = l & 15;
    const int qd = l >> 4;
    const long ebase = e0 + w*64;

    const int aoff = ((mr >> 2) << 4) + (mr & 3);
    int ecol[4], erow[4];
    float edist[4];
    #pragma unroll
    for (int m = 0; m < 4; ++m) {
        const unsigned rc = rcS[ebase + aoff + m*4];
        erow[m] = (int)(rc >> 16); ecol[m] = (int)(rc & 0xffffu);
    }
    #pragma unroll
    for (int m = 0; m < 4; ++m) {
        const int c = ecol[m], r = erow[m];
        const float dx = posrel[c*3+0] - posrel[r*3+0];
        const float dy = posrel[c*3+1] - posrel[r*3+1];
        const float dz = posrel[c*3+2] - posrel[r*3+2];
        edist[m] = sqrtf(dx*dx + dy*dy + dz*dz);
    }

    unsigned rcv[16];
    {
        const uint4* rc4 = (const uint4*)&rcS[ebase + qd*16];
        #pragma unroll
        for (int i = 0; i < 4; ++i) {
            const uint4 v = rc4[i];
            rcv[i*4+0] = v.x >> 16; rcv[i*4+1] = v.y >> 16;
            rcv[i*4+2] = v.z >> 16; rcv[i*4+3] = v.w >> 16;
        }
    }

    bf16x8 afr[4][4];
    const float4* __restrict__ Pf4 = (const float4*)P;
    const float4* __restrict__ Qf4 = (const float4*)Q;
    const float4* __restrict__ c1f4 = (const float4*)w1c;
    const float4* __restrict__ b1f4 = (const float4*)b1;
    #pragma unroll
    for (int kk = 0; kk < 4; ++kk) {
        const int kb4 = (kk*32 + qd*8) >> 2;
        const float4 c0  = c1f4[kb4],   c1v = c1f4[kb4+1];
        const float4 b0  = b1f4[kb4],   b1v = b1f4[kb4+1];
        #pragma unroll
        for (int m = 0; m < 4; ++m) {
            const float4 p0 = Pf4[ecol[m]*32 + kb4];
            const float4 p1 = Pf4[ecol[m]*32 + kb4 + 1];
            const float4 q0 = Qf4[erow[m]*32 + kb4];
            const float4 q1 = Qf4[erow[m]*32 + kb4 + 1];
            const float d = edist[m];
            union { bf16x8 v; unsigned short u[8]; } au;
            au.u[0] = f2bf(fmaxf(p0.x + q0.x + d*c0.x  + b0.x,  0.f));
            au.u[1] = f2bf(fmaxf(p0.y + q0.y + d*c0.y  + b0.y,  0.f));
            au.u[2] = f2bf(fmaxf(p0.z + q0.z + d*c0.z  + b0.z,  0.f));
            au.u[3] = f2bf(fmaxf(p0.w + q0.w + d*c0.w  + b0.w,  0.f));
            au.u[4] = f2bf(fmaxf(p1.x + q1.x + d*c1v.x + b1v.x, 0.f));
            au.u[5] = f2bf(fmaxf(p1.y + q1.y + d*c1v.y + b1v.y, 0.f));
            au.u[6] = f2bf(fmaxf(p1.z + q1.z + d*c1v.z + b1v.z, 0.f));
            au.u[7] = f2bf(fmaxf(p1.w + q1.w + d*c1v.w + b1v.w, 0.f));
            afr[m][kk] = au.v;
        }
    }

    const bf16x8* __restrict__ w2tv = (const bf16x8*)w2t;
    bf16x8 bfr[4];
    #pragma unroll
    for (int kk = 0; kk < 4; ++kk)
        bfr[kk] = w2tv[(0*16 + mr)*16 + kk*4 + qd];

    #pragma unroll 1
    for (int t = 0; t < 8; ++t) {
        bf16x8 bnext[4];
        if (t < 7) {
            #pragma unroll
            for (int kk = 0; kk < 4; ++kk)
                bnext[kk] = w2tv[((t+1)*16 + mr)*16 + kk*4 + qd];
        }
        const int colg = t*16 + mr;
        const float bb = b2[colg];

        f32x4 acc[4];
        #pragma unroll
        for (int m = 0; m < 4; ++m) acc[m] = (f32x4){0.f, 0.f, 0.f, 0.f};
        #pragma unroll
        for (int kk = 0; kk < 4; ++kk)
            #pragma unroll
            for (int m = 0; m < 4; ++m)
                acc[m] = __builtin_amdgcn_mfma_f32_16x16x32_bf16(afr[m][kk], bfr[kk], acc[m], 0, 0, 0);

        int rprev = -1;
        float run = 0.f;
        #pragma unroll
        for (int m = 0; m < 4; ++m) {
            #pragma unroll
            for (int r4 = 0; r4 < 4; ++r4) {
                const int rw = (int)rcv[m*4 + r4];
                const float v = fmaxf(acc[m][r4] + bb, 0.f);
                if (rw != rprev) {
                    if (rprev >= 0) atomAdd(&msum[(long)rprev*HD + colg], run);
                    rprev = rw; run = v;
                } else {
                    run += v;
                }
            }
        }
        atomAdd(&msum[(long)rprev*HD + colg], run);

        #pragma unroll
        for (int kk = 0; kk < 4; ++kk) bfr[kk] = bnext[kk];
    }
}

// ---------------- ligand-masked per-graph sum of x (from hi/lo) ----------------
__global__ __launch_bounds__(256) void gsum_kernel(
    const unsigned short* __restrict__ xhi, const unsigned short* __restrict__ xlo,
    const int* __restrict__ batch,
    const int* __restrict__ ntype, float* __restrict__ gsum)
{
    const int idx = blockIdx.x * 256 + threadIdx.x;
    const int n = idx >> 5, k4 = idx & 31;
    if (ntype[n] != 1) return;
    const int b = batch[n];
    const ushort4 h = *(const ushort4*)&xhi[n*HD + k4*4];
    const ushort4 lo = *(const ushort4*)&xlo[n*HD + k4*4];
    float* dst = &gsum[b*HD + k4*4];
    atomAdd(dst+0, bf2f(h.x) + bf2f(lo.x));
    atomAdd(dst+1, bf2f(h.y) + bf2f(lo.y));
    atomAdd(dst+2, bf2f(h.z) + bf2f(lo.z));
    atomAdd(dst+3, bf2f(h.w) + bf2f(lo.w));
}

// ---------------- readout ----------------
__global__ __launch_bounds__(128) void readout_kernel(
    const float* __restrict__ gsum, const float* __restrict__ lcnt,
    const float* __restrict__ w1, const float* __restrict__ b1,
    const float* __restrict__ w2, const float* __restrict__ b2,
    float* __restrict__ out)
{
    __shared__ float gs[HD];
    __shared__ float red[2];
    const int b = blockIdx.x, j = threadIdx.x;
    gs[j] = gsum[b*HD + j] / fmaxf(lcnt[b], 1.f);
    __syncthreads();
    float acc = b1[j];
    for (int k = 0; k < HD; ++k) acc += gs[k]*w1[k*HD + j];
    float hg = fmaxf(acc, 0.f) * w2[j];
    #pragma unroll
    for (int off = 32; off > 0; off >>= 1) hg += __shfl_down(hg, off, 64);
    if ((j & 63) == 0) red[j >> 6] = hg;
    __syncthreads();
    if (j == 0) out[b] = red[0] + red[1] + b2[0];
}

extern "C" void kernel_launch(void* const* d_in, const int* in_sizes, int n_in,
                              void* d_out, int out_size, void* d_ws, size_t ws_size,
                              hipStream_t stream)
{
    const float* pos   = (const float*)d_in[0];
    const int*   z     = (const int*)d_in[1];
    const int*   batch = (const int*)d_in[2];
    const int*   eidx  = (const int*)d_in[3];
    const int*   ntype = (const int*)d_in[4];
    const float* emb   = (const float*)d_in[5];
    const float* lin_w = (const float*)d_in[6];
    const float* lin_b = (const float*)d_in[7];
    const float* mw1   = (const float*)d_in[8];
    const float* mb1   = (const float*)d_in[9];
    const float* mw2   = (const float*)d_in[10];
    const float* mb2   = (const float*)d_in[11];
    const float* uw    = (const float*)d_in[12];
    const float* ub    = (const float*)d_in[13];
    const float* rw1   = (const float*)d_in[14];
    const float* rb1   = (const float*)d_in[15];
    const float* rw2   = (const float*)d_in[16];
    const float* rb2   = (const float*)d_in[17];

    const int* row = eidx;
    const int* col = eidx + NE;

    float* ws     = (float*)d_ws;
    float* csum   = ws + O_CSUM;
    float* ccnt   = ws + O_CCNT;
    float* lcnt   = ws + O_LCNT;
    float* gsum   = ws + O_GSUM;
    int*   degi   = (int*)(ws + O_DEGI);
    float* posrel = ws + O_POSREL;
    unsigned int* rcS = (unsigned int*)(ws + O_RC);
    unsigned short* xhi = (unsigned short*)(ws + O_XHI);
    unsigned short* xlo = (unsigned short*)(ws + O_XLO);
    float* Pb     = ws + O_P;
    float* Qb     = ws + O_Q;
    float* msum   = ws + O_MSUM;
    unsigned short* w2t  = (unsigned short*)(ws + O_W2T);
    unsigned short* w1th = (unsigned short*)(ws + O_W1TH);
    unsigned short* w1tl = (unsigned short*)(ws + O_W1TL);
    unsigned short* wuth = (unsigned short*)(ws + O_WUTH);
    unsigned short* wutl = (unsigned short*)(ws + O_WUTL);
    int* chunkSum = (int*)(ws + O_CHK);
    int* rowStart = (int*)xhi;           // alias xhi head pre-lin_in
    int* cnt      = (int*)xhi + NN;

    (void)hipMemsetAsync(ws, 0, (size_t)(O_DEGI + NN) * sizeof(float), stream);
    (void)hipMemsetAsync(cnt, 0, (size_t)NN * sizeof(int), stream);

    stats_kernel  <<<NN/256, 256, 0, stream>>>(pos, batch, ntype, csum, ccnt, lcnt);
    deg_kernel    <<<NE/256, 256, 0, stream>>>(row, degi);
    posrel_kernel <<<NN/256, 256, 0, stream>>>(pos, batch, csum, ccnt, posrel);
    scanA_kernel  <<<256, 256, 0, stream>>>(degi, chunkSum);
    scanB_kernel  <<<1, 256, 0, stream>>>(chunkSum);
    scanC_kernel  <<<256, 256, 0, stream>>>(degi, chunkSum, rowStart);
    scatter_kernel<<<NE/256, 256, 0, stream>>>(row, col, rowStart, cnt, rcS);
    w2bf_kernel   <<<192, 256, 0, stream>>>(mw2, w2t);
    wprep_kernel  <<<384, 256, 0, stream>>>(mw1, uw, w1th, w1tl, wuth, wutl);

    lin_in_gemm<<<NN/32, 256, 0, stream>>>(emb, posrel, z, lin_w, lin_b, xhi, xlo);

    for (int l = 0; l < NL; ++l) {
        const float* W1 = mw1 + (size_t)l*257*HD;
        pq_gemm<<<NN/64, 256, 0, stream>>>(xhi, xlo, w1th + (size_t)l*32768, w1tl + (size_t)l*32768, Pb, Qb);
        (void)hipMemsetAsync(msum, 0, (size_t)NN*HD*sizeof(float), stream);
        edge_msg_kernel<<<NE/256, 256, 0, stream>>>(Pb, Qb, posrel, rcS,
                                                    W1 + 256*HD, mb1 + l*HD,
                                                    w2t + (size_t)l*16384, mb2 + l*HD, msum);
        upd_gemm<<<NN/64, 256, 0, stream>>>(xhi, xlo, msum, degi,
                                            wuth + (size_t)l*32768, wutl + (size_t)l*32768,
                                            ub + l*HD);
    }

    gsum_kernel   <<<NN*32/256, 256, 0, stream>>>(xhi, xlo, batch, ntype, gsum);
    readout_kernel<<<NB, 128, 0, stream>>>(gsum, lcnt, rw1, rb1, rw2, rb2, (float*)d_out);
}

// Round 11
// 1146.812 us; speedup vs baseline: 2.7475x; 1.0861x over previous
//
#include <hip/hip_runtime.h>
#include <hip/hip_bf16.h>
#include <hip/hip_fp16.h>
#include <math.h>

#define NN 65536
#define NE 1048576
#define NB 64
#define HD 128
#define NL 3

// ---- workspace layout (float offsets) ----
#define O_CSUM   0
#define O_CCNT   192
#define O_LCNT   256
#define O_GSUM   320         // -> 8512
#define O_DEGI   8512        // -> 74048
#define O_POSREL 74048       // -> 270656
#define O_RC     270656      // -> 1319232
#define O_XHI    1319232     // NN*128 ushort -> 5513536
#define O_XLO    5513536     // -> 9707840
#define O_P      9707840     // NN*128 fp16 (uses half the slot) -> 18096448
#define O_Q      18096448    // -> 26485056
#define O_MSUM   26485056    // -> 34873664
#define O_W2T    34873664    // 3*128*128 bf16 -> 34898240
#define O_W1TH   34898240    // -> 34947392
#define O_W1TL   34947392    // -> 34996544
#define O_WUTH   34996544    // -> 35045696
#define O_WUTL   35045696    // -> 35094848
#define O_CHK    35094848    // 256 ints -> 35095104 (~140.4 MB)

typedef __attribute__((ext_vector_type(8))) short bf16x8;
typedef __attribute__((ext_vector_type(8))) unsigned short u16x8;
typedef __attribute__((ext_vector_type(4))) float f32x4;

__device__ __forceinline__ void atomAdd(float* p, float v) { unsafeAtomicAdd(p, v); }

__device__ __forceinline__ unsigned short f2bf(float f) {
    union { __hip_bfloat16 h; unsigned short u; } cv;
    cv.h = __float2bfloat16(f);
    return cv.u;
}
__device__ __forceinline__ float bf2f(unsigned short u) {
    union { float f; unsigned v; } c; c.v = ((unsigned)u) << 16; return c.f;
}
__device__ __forceinline__ void split2(float v, unsigned short& h, unsigned short& l) {
    h = f2bf(v); l = f2bf(v - bf2f(h));
}
__device__ __forceinline__ unsigned short f2h(float f) {
    union { __half h; unsigned short u; } c; c.h = __float2half(f); return c.u;
}
__device__ __forceinline__ float h2f(unsigned short u) {
    union { __half h; unsigned short u; } c; c.u = u; return __half2float(c.h);
}

// ---------------- stats ----------------
__global__ __launch_bounds__(256) void stats_kernel(
    const float* __restrict__ pos, const int* __restrict__ batch,
    const int* __restrict__ ntype,
    float* __restrict__ csum, float* __restrict__ ccnt, float* __restrict__ lcnt)
{
    __shared__ float s[NB * 5];
    const int tid = threadIdx.x;
    for (int i = tid; i < NB * 5; i += 256) s[i] = 0.f;
    __syncthreads();
    const int n = blockIdx.x * 256 + tid;
    const int b = batch[n];
    atomicAdd(&s[b*5+0], pos[n*3+0]);
    atomicAdd(&s[b*5+1], pos[n*3+1]);
    atomicAdd(&s[b*5+2], pos[n*3+2]);
    atomicAdd(&s[b*5+3], 1.f);
    if (ntype[n] == 1) atomicAdd(&s[b*5+4], 1.f);
    __syncthreads();
    for (int i = tid; i < NB * 5; i += 256) {
        float v = s[i];
        if (v != 0.f) {
            int b2 = i / 5, f = i - b2*5;
            if (f < 3)       atomAdd(&csum[b2*3+f], v);
            else if (f == 3) atomAdd(&ccnt[b2], v);
            else             atomAdd(&lcnt[b2], v);
        }
    }
}

// ---------------- degree histogram ----------------
__global__ __launch_bounds__(256) void deg_kernel(const int* __restrict__ row, int* __restrict__ degi)
{
    const int e = blockIdx.x * 256 + threadIdx.x;
    atomicAdd(&degi[row[e]], 1);
}

// ---------------- two-level scan ----------------
__global__ __launch_bounds__(256) void scanA_kernel(const int* __restrict__ degi, int* __restrict__ chunkSum)
{
    __shared__ int red[4];
    const int t = threadIdx.x, b = blockIdx.x;
    int v = degi[b*256 + t];
    #pragma unroll
    for (int off = 32; off > 0; off >>= 1) v += __shfl_down(v, off, 64);
    if ((t & 63) == 0) red[t >> 6] = v;
    __syncthreads();
    if (t == 0) chunkSum[b] = red[0] + red[1] + red[2] + red[3];
}

__global__ __launch_bounds__(256) void scanB_kernel(int* __restrict__ chunkSum)
{
    __shared__ int s[256];
    const int t = threadIdx.x;
    const int v = chunkSum[t];
    s[t] = v;
    __syncthreads();
    #pragma unroll
    for (int off = 1; off < 256; off <<= 1) {
        int u = (t >= off) ? s[t - off] : 0;
        __syncthreads();
        s[t] += u;
        __syncthreads();
    }
    chunkSum[t] = s[t] - v;   // exclusive
}

__global__ __launch_bounds__(256) void scanC_kernel(const int* __restrict__ degi,
                                                    const int* __restrict__ chunkOff,
                                                    int* __restrict__ rowStart)
{
    __shared__ int s[256];
    const int t = threadIdx.x, b = blockIdx.x;
    const int v = degi[b*256 + t];
    s[t] = v;
    __syncthreads();
    #pragma unroll
    for (int off = 1; off < 256; off <<= 1) {
        int u = (t >= off) ? s[t - off] : 0;
        __syncthreads();
        s[t] += u;
        __syncthreads();
    }
    rowStart[b*256 + t] = chunkOff[b] + s[t] - v;
}

// ---------------- counting-sort scatter ----------------
__global__ __launch_bounds__(256) void scatter_kernel(
    const int* __restrict__ row, const int* __restrict__ col,
    const int* __restrict__ rowStart, int* __restrict__ cnt,
    unsigned int* __restrict__ rcS)
{
    const int e = blockIdx.x * 256 + threadIdx.x;
    const int r = row[e], c = col[e];
    const int p = rowStart[r] + atomicAdd(&cnt[r], 1);
    rcS[p] = ((unsigned)r << 16) | (unsigned)c;
}

// ---------------- pos_rel ----------------
__global__ __launch_bounds__(256) void posrel_kernel(
    const float* __restrict__ pos, const int* __restrict__ batch,
    const float* __restrict__ csum, const float* __restrict__ ccnt,
    float* __restrict__ posrel)
{
    const int n = blockIdx.x * 256 + threadIdx.x;
    const int b = batch[n];
    const float inv = 1.f / fmaxf(ccnt[b], 1.f);
    posrel[n*3+0] = pos[n*3+0] - csum[b*3+0]*inv;
    posrel[n*3+1] = pos[n*3+1] - csum[b*3+1]*inv;
    posrel[n*3+2] = pos[n*3+2] - csum[b*3+2]*inv;
}

// ---------------- weight prep: W2T bf16 + W1T/WuT hi/lo (98304 threads) ----------------
__global__ __launch_bounds__(256) void wprep_kernel(
    const float* __restrict__ mw1, const float* __restrict__ uw,
    const float* __restrict__ mw2,
    unsigned short* __restrict__ w1th, unsigned short* __restrict__ w1tl,
    unsigned short* __restrict__ wuth, unsigned short* __restrict__ wutl,
    unsigned short* __restrict__ w2t)
{
    const int idx = blockIdx.x * 256 + threadIdx.x;   // 98304
    {   // W1T: [l][c<256][k<128]; c<128: mw1[l][k][c] (P); c>=128: mw1[l][128+k][c-128] (Q)
        const int l = idx >> 15, rem = idx & 32767, c = rem >> 7, k = rem & 127;
        const int kk = (c < 128) ? k : (128 + k);
        const int cc = c & 127;
        const float v = mw1[l*257*128 + kk*128 + cc];
        unsigned short h, lo; split2(v, h, lo);
        w1th[idx] = h; w1tl[idx] = lo;
    }
    {   // WuT: [l][c<128][k<256] = uw[l][k][c]
        const int l = idx >> 15, rem = idx & 32767, c = rem >> 8, k = rem & 255;
        const float v = uw[l*256*128 + k*128 + c];
        unsigned short h, lo; split2(v, h, lo);
        wuth[idx] = h; wutl[idx] = lo;
    }
    if (idx < 49152) {   // W2T: [l][n][k] = mw2[l][k][n]
        const int l = idx >> 14, rem = idx & 16383, n = rem >> 7, k = rem & 127;
        w2t[idx] = f2bf(mw2[(l << 14) + k*128 + n]);
    }
}

// ---------------- lin_in: x = concat(emb[z], posrel) @ W + b -> xhi/xlo ----------------
__global__ __launch_bounds__(256) void lin_in_gemm(
    const float* __restrict__ emb, const float* __restrict__ posrel,
    const int* __restrict__ zidx,
    const float* __restrict__ W, const float* __restrict__ bias,
    unsigned short* __restrict__ xhi, unsigned short* __restrict__ xlo)
{
    __shared__ __align__(16) float Asm[32][132];
    __shared__ __align__(16) float Wsm[32][128];
    const int tid = threadIdx.x;
    const int n0  = blockIdx.x * 32;
    const float4* __restrict__ A0f4 = (const float4*)emb;

    for (int idx4 = tid; idx4 < 1024; idx4 += 256) {
        int i = idx4 >> 5, k4 = idx4 & 31;
        int zz = zidx[n0 + i];
        *(float4*)&Asm[i][k4*4] = A0f4[zz*32 + k4];
    }
    if (tid < 96) { int i = tid / 3, d = tid - i*3; Asm[i][128+d] = posrel[(n0+i)*3 + d]; }
    else if (tid < 128) { Asm[tid-96][131] = 0.f; }

    const int tj = tid & 31;
    const int tn = tid >> 5;
    float acc[4][4];
    #pragma unroll
    for (int r = 0; r < 4; ++r)
        #pragma unroll
        for (int c = 0; c < 4; ++c) acc[r][c] = 0.f;

    const float4* __restrict__ Wf4 = (const float4*)W;
    #pragma unroll 1
    for (int kc = 0; kc < 131; kc += 32) {
        const int kend = (131 - kc < 32) ? (131 - kc) : 32;
        __syncthreads();
        for (int idx4 = tid; idx4 < kend*32; idx4 += 256) {
            int kk = idx4 >> 5, j4 = idx4 & 31;
            *(float4*)&Wsm[kk][j4*4] = Wf4[(kc+kk)*32 + j4];
        }
        __syncthreads();
        for (int kk = 0; kk < kend; ++kk) {
            const float4 w = *(const float4*)&Wsm[kk][tj*4];
            #pragma unroll
            for (int r = 0; r < 4; ++r) {
                const float a = Asm[tn*4+r][kc+kk];
                acc[r][0] += a*w.x; acc[r][1] += a*w.y; acc[r][2] += a*w.z; acc[r][3] += a*w.w;
            }
        }
    }

    const float4 bias4 = ((const float4*)bias)[tj];
    #pragma unroll
    for (int r = 0; r < 4; ++r) {
        const int node = n0 + tn*4 + r;
        const float o[4] = { acc[r][0] + bias4.x, acc[r][1] + bias4.y,
                             acc[r][2] + bias4.z, acc[r][3] + bias4.w };
        ushort4 h4, l4;
        split2(o[0], h4.x, l4.x); split2(o[1], h4.y, l4.y);
        split2(o[2], h4.z, l4.z); split2(o[3], h4.w, l4.w);
        *(ushort4*)&xhi[node*HD + tj*4] = h4;
        *(ushort4*)&xlo[node*HD + tj*4] = l4;
    }
}

// ---------------- pq GEMM (MFMA, split-bf16 3-pass): P|Q(fp16) = x @ W1[0:256] ----------
__global__ __launch_bounds__(256) void pq_gemm(
    const unsigned short* __restrict__ xhi, const unsigned short* __restrict__ xlo,
    const unsigned short* __restrict__ w1th, const unsigned short* __restrict__ w1tl,
    unsigned short* __restrict__ Ph, unsigned short* __restrict__ Qh)
{
    const int tid = threadIdx.x;
    const int l = tid & 63, w = tid >> 6;
    const int mr = l & 15, qd = l >> 4;
    const int n0 = blockIdx.x * 64;
    const int c0 = w * 64;

    f32x4 acc[4][4];
    #pragma unroll
    for (int mt = 0; mt < 4; ++mt)
        #pragma unroll
        for (int nt = 0; nt < 4; ++nt) acc[mt][nt] = (f32x4){0.f,0.f,0.f,0.f};

    #pragma unroll
    for (int ks = 0; ks < 4; ++ks) {
        const int kof = ks*32 + qd*8;
        bf16x8 ah[4], al[4], bh[4], bl[4];
        #pragma unroll
        for (int mt = 0; mt < 4; ++mt) {
            const int node = n0 + mt*16 + mr;
            ah[mt] = *(const bf16x8*)&xhi[node*HD + kof];
            al[mt] = *(const bf16x8*)&xlo[node*HD + kof];
        }
        #pragma unroll
        for (int nt = 0; nt < 4; ++nt) {
            const int c = c0 + nt*16 + mr;
            bh[nt] = *(const bf16x8*)&w1th[c*HD + kof];
            bl[nt] = *(const bf16x8*)&w1tl[c*HD + kof];
        }
        #pragma unroll
        for (int mt = 0; mt < 4; ++mt)
            #pragma unroll
            for (int nt = 0; nt < 4; ++nt) {
                acc[mt][nt] = __builtin_amdgcn_mfma_f32_16x16x32_bf16(ah[mt], bh[nt], acc[mt][nt], 0,0,0);
                acc[mt][nt] = __builtin_amdgcn_mfma_f32_16x16x32_bf16(ah[mt], bl[nt], acc[mt][nt], 0,0,0);
                acc[mt][nt] = __builtin_amdgcn_mfma_f32_16x16x32_bf16(al[mt], bh[nt], acc[mt][nt], 0,0,0);
            }
    }

    unsigned short* __restrict__ dst = (w < 2) ? Ph : Qh;
    const int cbase = (w < 2) ? c0 : c0 - 128;
    #pragma unroll
    for (int mt = 0; mt < 4; ++mt)
        #pragma unroll
        for (int nt = 0; nt < 4; ++nt) {
            const int cc = cbase + nt*16 + mr;
            #pragma unroll
            for (int r = 0; r < 4; ++r) {
                const int node = n0 + mt*16 + qd*4 + r;
                dst[(long)node*HD + cc] = f2h(acc[mt][nt][r]);
            }
        }
}

// ---------------- update GEMM (MFMA, split-bf16 3-pass), K=256, relu, -> xhi/xlo --------
__global__ __launch_bounds__(256) void upd_gemm(
    unsigned short* __restrict__ xhi, unsigned short* __restrict__ xlo,
    const float* __restrict__ msum, const int* __restrict__ degi,
    const unsigned short* __restrict__ wuth, const unsigned short* __restrict__ wutl,
    const float* __restrict__ bias)
{
    const int tid = threadIdx.x;
    const int l = tid & 63, w = tid >> 6;
    const int mr = l & 15, qd = l >> 4;
    const int n0 = blockIdx.x * 64 + w*16;
    const int node = n0 + mr;
    const float inv = 1.f / fmaxf((float)degi[node], 1.f);

    f32x4 acc[8];
    #pragma unroll
    for (int nt = 0; nt < 8; ++nt) acc[nt] = (f32x4){0.f,0.f,0.f,0.f};

    #pragma unroll 1
    for (int ks = 0; ks < 8; ++ks) {
        const int kof = ks*32 + qd*8;
        bf16x8 ah, al;
        if (ks < 4) {
            ah = *(const bf16x8*)&xhi[node*HD + kof];
            al = *(const bf16x8*)&xlo[node*HD + kof];
        } else {
            const int mk = kof - 128;
            const float4 v0 = *(const float4*)&msum[(long)node*HD + mk];
            const float4 v1 = *(const float4*)&msum[(long)node*HD + mk + 4];
            union { bf16x8 v; unsigned short u[8]; } hh, ll;
            float vv[8] = { v0.x*inv, v0.y*inv, v0.z*inv, v0.w*inv,
                            v1.x*inv, v1.y*inv, v1.z*inv, v1.w*inv };
            #pragma unroll
            for (int i = 0; i < 8; ++i) split2(vv[i], hh.u[i], ll.u[i]);
            ah = hh.v; al = ll.v;
        }
        #pragma unroll
        for (int nt = 0; nt < 8; ++nt) {
            const int c = nt*16 + mr;
            const bf16x8 bh = *(const bf16x8*)&wuth[c*256 + kof];
            const bf16x8 bl = *(const bf16x8*)&wutl[c*256 + kof];
            acc[nt] = __builtin_amdgcn_mfma_f32_16x16x32_bf16(ah, bh, acc[nt], 0,0,0);
            acc[nt] = __builtin_amdgcn_mfma_f32_16x16x32_bf16(ah, bl, acc[nt], 0,0,0);
            acc[nt] = __builtin_amdgcn_mfma_f32_16x16x32_bf16(al, bh, acc[nt], 0,0,0);
        }
    }

    #pragma unroll
    for (int nt = 0; nt < 8; ++nt) {
        const int c = nt*16 + mr;
        const float bb = bias[c];
        #pragma unroll
        for (int r = 0; r < 4; ++r) {
            const int nd = n0 + qd*4 + r;
            const float o = fmaxf(acc[nt][r] + bb, 0.f);
            unsigned short h, lo; split2(o, h, lo);
            xhi[nd*HD + c] = h;
            xlo[nd*HD + c] = lo;
        }
    }
}

// ---------------- fused edge kernel (fp16 P/Q gathers) ----------------
__global__ __launch_bounds__(256) void edge_msg_kernel(
    const unsigned short* __restrict__ Ph, const unsigned short* __restrict__ Qh,
    const float* __restrict__ posrel,
    const unsigned int* __restrict__ rcS,
    const float* __restrict__ w1c, const float* __restrict__ b1,
    const unsigned short* __restrict__ w2t,
    const float* __restrict__ b2,
    float* __restrict__ msum)
{
    const int tid = threadIdx.x;
    const long e0 = (long)blockIdx.x * 256;
    const int l  = tid & 63;
    const int w  = tid >> 6;
    const int mr = l & 15;
    const int qd = l >> 4;
    const long ebase = e0 + w*64;

    const int aoff = ((mr >> 2) << 4) + (mr & 3);
    int ecol[4], erow[4];
    float edist[4];
    #pragma unroll
    for (int m = 0; m < 4; ++m) {
        const unsigned rc = rcS[ebase + aoff + m*4];
        erow[m] = (int)(rc >> 16); ecol[m] = (int)(rc & 0xffffu);
    }
    #pragma unroll
    for (int m = 0; m < 4; ++m) {
        const int c = ecol[m], r = erow[m];
        const float dx = posrel[c*3+0] - posrel[r*3+0];
        const float dy = posrel[c*3+1] - posrel[r*3+1];
        const float dz = posrel[c*3+2] - posrel[r*3+2];
        edist[m] = sqrtf(dx*dx + dy*dy + dz*dz);
    }

    unsigned rcv[16];
    {
        const uint4* rc4 = (const uint4*)&rcS[ebase + qd*16];
        #pragma unroll
        for (int i = 0; i < 4; ++i) {
            const uint4 v = rc4[i];
            rcv[i*4+0] = v.x >> 16; rcv[i*4+1] = v.y >> 16;
            rcv[i*4+2] = v.z >> 16; rcv[i*4+3] = v.w >> 16;
        }
    }

    bf16x8 afr[4][4];
    const float4* __restrict__ c1f4 = (const float4*)w1c;
    const float4* __restrict__ b1f4 = (const float4*)b1;
    #pragma unroll
    for (int kk = 0; kk < 4; ++kk) {
        const int kof = kk*32 + qd*8;
        const int kb4 = kof >> 2;
        const float4 c0  = c1f4[kb4],   c1v = c1f4[kb4+1];
        const float4 b0  = b1f4[kb4],   b1v = b1f4[kb4+1];
        const float carr[8] = { c0.x, c0.y, c0.z, c0.w, c1v.x, c1v.y, c1v.z, c1v.w };
        const float barr[8] = { b0.x, b0.y, b0.z, b0.w, b1v.x, b1v.y, b1v.z, b1v.w };
        #pragma unroll
        for (int m = 0; m < 4; ++m) {
            const u16x8 pu = *(const u16x8*)&Ph[(long)ecol[m]*HD + kof];
            const u16x8 qu = *(const u16x8*)&Qh[(long)erow[m]*HD + kof];
            const float d = edist[m];
            union { bf16x8 v; unsigned short u[8]; } au;
            #pragma unroll
            for (int i = 0; i < 8; ++i)
                au.u[i] = f2bf(fmaxf(h2f(pu[i]) + h2f(qu[i]) + d*carr[i] + barr[i], 0.f));
            afr[m][kk] = au.v;
        }
    }

    const bf16x8* __restrict__ w2tv = (const bf16x8*)w2t;
    bf16x8 bfr[4];
    #pragma unroll
    for (int kk = 0; kk < 4; ++kk)
        bfr[kk] = w2tv[(0*16 + mr)*16 + kk*4 + qd];

    #pragma unroll 1
    for (int t = 0; t < 8; ++t) {
        bf16x8 bnext[4];
        if (t < 7) {
            #pragma unroll
            for (int kk = 0; kk < 4; ++kk)
                bnext[kk] = w2tv[((t+1)*16 + mr)*16 + kk*4 + qd];
        }
        const int colg = t*16 + mr;
        const float bb = b2[colg];

        f32x4 acc[4];
        #pragma unroll
        for (int m = 0; m < 4; ++m) acc[m] = (f32x4){0.f, 0.f, 0.f, 0.f};
        #pragma unroll
        for (int kk = 0; kk < 4; ++kk)
            #pragma unroll
            for (int m = 0; m < 4; ++m)
                acc[m] = __builtin_amdgcn_mfma_f32_16x16x32_bf16(afr[m][kk], bfr[kk], acc[m], 0, 0, 0);

        int rprev = -1;
        float run = 0.f;
        #pragma unroll
        for (int m = 0; m < 4; ++m) {
            #pragma unroll
            for (int r4 = 0; r4 < 4; ++r4) {
                const int rw = (int)rcv[m*4 + r4];
                const float v = fmaxf(acc[m][r4] + bb, 0.f);
                if (rw != rprev) {
                    if (rprev >= 0) atomAdd(&msum[(long)rprev*HD + colg], run);
                    rprev = rw; run = v;
                } else {
                    run += v;
                }
            }
        }
        atomAdd(&msum[(long)rprev*HD + colg], run);

        #pragma unroll
        for (int kk = 0; kk < 4; ++kk) bfr[kk] = bnext[kk];
    }
}

// ---------------- ligand-masked per-graph sum of x (from hi/lo) ----------------
__global__ __launch_bounds__(256) void gsum_kernel(
    const unsigned short* __restrict__ xhi, const unsigned short* __restrict__ xlo,
    const int* __restrict__ batch,
    const int* __restrict__ ntype, float* __restrict__ gsum)
{
    const int idx = blockIdx.x * 256 + threadIdx.x;
    const int n = idx >> 5, k4 = idx & 31;
    if (ntype[n] != 1) return;
    const int b = batch[n];
    const ushort4 h = *(const ushort4*)&xhi[n*HD + k4*4];
    const ushort4 lo = *(const ushort4*)&xlo[n*HD + k4*4];
    float* dst = &gsum[b*HD + k4*4];
    atomAdd(dst+0, bf2f(h.x) + bf2f(lo.x));
    atomAdd(dst+1, bf2f(h.y) + bf2f(lo.y));
    atomAdd(dst+2, bf2f(h.z) + bf2f(lo.z));
    atomAdd(dst+3, bf2f(h.w) + bf2f(lo.w));
}

// ---------------- readout ----------------
__global__ __launch_bounds__(128) void readout_kernel(
    const float* __restrict__ gsum, const float* __restrict__ lcnt,
    const float* __restrict__ w1, const float* __restrict__ b1,
    const float* __restrict__ w2, const float* __restrict__ b2,
    float* __restrict__ out)
{
    __shared__ float gs[HD];
    __shared__ float red[2];
    const int b = blockIdx.x, j = threadIdx.x;
    gs[j] = gsum[b*HD + j] / fmaxf(lcnt[b], 1.f);
    __syncthreads();
    float acc = b1[j];
    for (int k = 0; k < HD; ++k) acc += gs[k]*w1[k*HD + j];
    float hg = fmaxf(acc, 0.f) * w2[j];
    #pragma unroll
    for (int off = 32; off > 0; off >>= 1) hg += __shfl_down(hg, off, 64);
    if ((j & 63) == 0) red[j >> 6] = hg;
    __syncthreads();
    if (j == 0) out[b] = red[0] + red[1] + b2[0];
}

extern "C" void kernel_launch(void* const* d_in, const int* in_sizes, int n_in,
                              void* d_out, int out_size, void* d_ws, size_t ws_size,
                              hipStream_t stream)
{
    const float* pos   = (const float*)d_in[0];
    const int*   z     = (const int*)d_in[1];
    const int*   batch = (const int*)d_in[2];
    const int*   eidx  = (const int*)d_in[3];
    const int*   ntype = (const int*)d_in[4];
    const float* emb   = (const float*)d_in[5];
    const float* lin_w = (const float*)d_in[6];
    const float* lin_b = (const float*)d_in[7];
    const float* mw1   = (const float*)d_in[8];
    const float* mb1   = (const float*)d_in[9];
    const float* mw2   = (const float*)d_in[10];
    const float* mb2   = (const float*)d_in[11];
    const float* uw    = (const float*)d_in[12];
    const float* ub    = (const float*)d_in[13];
    const float* rw1   = (const float*)d_in[14];
    const float* rb1   = (const float*)d_in[15];
    const float* rw2   = (const float*)d_in[16];
    const float* rb2   = (const float*)d_in[17];

    const int* row = eidx;
    const int* col = eidx + NE;

    float* ws     = (float*)d_ws;
    float* csum   = ws + O_CSUM;
    float* ccnt   = ws + O_CCNT;
    float* lcnt   = ws + O_LCNT;
    float* gsum   = ws + O_GSUM;
    int*   degi   = (int*)(ws + O_DEGI);
    float* posrel = ws + O_POSREL;
    unsigned int* rcS = (unsigned int*)(ws + O_RC);
    unsigned short* xhi = (unsigned short*)(ws + O_XHI);
    unsigned short* xlo = (unsigned short*)(ws + O_XLO);
    unsigned short* Ph  = (unsigned short*)(ws + O_P);
    unsigned short* Qh  = (unsigned short*)(ws + O_Q);
    float* msum   = ws + O_MSUM;
    unsigned short* w2t  = (unsigned short*)(ws + O_W2T);
    unsigned short* w1th = (unsigned short*)(ws + O_W1TH);
    unsigned short* w1tl = (unsigned short*)(ws + O_W1TL);
    unsigned short* wuth = (unsigned short*)(ws + O_WUTH);
    unsigned short* wutl = (unsigned short*)(ws + O_WUTL);
    int* chunkSum = (int*)(ws + O_CHK);
    int* rowStart = (int*)xhi;           // alias xhi head pre-lin_in
    int* cnt      = (int*)xhi + NN;

    (void)hipMemsetAsync(ws, 0, (size_t)(O_DEGI + NN) * sizeof(float), stream);
    (void)hipMemsetAsync(cnt, 0, (size_t)NN * sizeof(int), stream);

    stats_kernel  <<<NN/256, 256, 0, stream>>>(pos, batch, ntype, csum, ccnt, lcnt);
    deg_kernel    <<<NE/256, 256, 0, stream>>>(row, degi);
    posrel_kernel <<<NN/256, 256, 0, stream>>>(pos, batch, csum, ccnt, posrel);
    scanA_kernel  <<<256, 256, 0, stream>>>(degi, chunkSum);
    scanB_kernel  <<<1, 256, 0, stream>>>(chunkSum);
    scanC_kernel  <<<256, 256, 0, stream>>>(degi, chunkSum, rowStart);
    scatter_kernel<<<NE/256, 256, 0, stream>>>(row, col, rowStart, cnt, rcS);
    wprep_kernel  <<<384, 256, 0, stream>>>(mw1, uw, mw2, w1th, w1tl, wuth, wutl, w2t);

    lin_in_gemm<<<NN/32, 256, 0, stream>>>(emb, posrel, z, lin_w, lin_b, xhi, xlo);

    for (int l = 0; l < NL; ++l) {
        const float* W1 = mw1 + (size_t)l*257*HD;
        pq_gemm<<<NN/64, 256, 0, stream>>>(xhi, xlo, w1th + (size_t)l*32768, w1tl + (size_t)l*32768, Ph, Qh);
        (void)hipMemsetAsync(msum, 0, (size_t)NN*HD*sizeof(float), stream);
        edge_msg_kernel<<<NE/256, 256, 0, stream>>>(Ph, Qh, posrel, rcS,
                                                    W1 + 256*HD, mb1 + l*HD,
                                                    w2t + (size_t)l*16384, mb2 + l*HD, msum);
        upd_gemm<<<NN/64, 256, 0, stream>>>(xhi, xlo, msum, degi,
                                            wuth + (size_t)l*32768, wutl + (size_t)l*32768,
                                            ub + l*HD);
    }

    gsum_kernel   <<<NN*32/256, 256, 0, stream>>>(xhi, xlo, batch, ntype, gsum);
    readout_kernel<<<NB, 128, 0, stream>>>(gsum, lcnt, rw1, rb1, rw2, rb2, (float*)d_out);
}

// Round 12
// 1042.674 us; speedup vs baseline: 3.0219x; 1.0999x over previous
//
#include <hip/hip_runtime.h>
#include <hip/hip_bf16.h>
#include <hip/hip_fp16.h>
#include <math.h>

#define NN 65536
#define NE 1048576
#define NB 64
#define HD 128
#define NL 3

// ---- workspace layout (float offsets) ----
#define O_CSUM   0
#define O_CCNT   192
#define O_LCNT   256
#define O_GSUM   320         // -> 8512
#define O_DEGI   8512        // -> 74048
#define O_POSREL 74048       // -> 270656
#define O_RC     270656      // -> 1319232
#define O_XHI    1319232     // NN*128 ushort -> 5513536
#define O_XLO    5513536     // -> 9707840
#define O_P      9707840     // NN*128 fp16 -> 18096448
#define O_Q      18096448    // -> 26485056
#define O_MSUM   26485056    // -> 34873664
#define O_W2T    34873664    // -> 34898240
#define O_W1TH   34898240    // -> 34947392
#define O_W1TL   34947392    // -> 34996544
#define O_WUTH   34996544    // -> 35045696
#define O_WUTL   35045696    // -> 35094848
#define O_CHK    35094848    // 256 ints -> 35095104 (~140.4 MB)

typedef __attribute__((ext_vector_type(8))) short bf16x8;
typedef __attribute__((ext_vector_type(8))) unsigned short u16x8;
typedef __attribute__((ext_vector_type(4))) float f32x4;

__device__ __forceinline__ void atomAdd(float* p, float v) { unsafeAtomicAdd(p, v); }

__device__ __forceinline__ unsigned short f2bf(float f) {
    union { __hip_bfloat16 h; unsigned short u; } cv;
    cv.h = __float2bfloat16(f);
    return cv.u;
}
__device__ __forceinline__ float bf2f(unsigned short u) {
    union { float f; unsigned v; } c; c.v = ((unsigned)u) << 16; return c.f;
}
__device__ __forceinline__ void split2(float v, unsigned short& h, unsigned short& l) {
    h = f2bf(v); l = f2bf(v - bf2f(h));
}
__device__ __forceinline__ unsigned short f2h(float f) {
    union { __half h; unsigned short u; } c; c.h = __float2half(f); return c.u;
}
__device__ __forceinline__ float h2f(unsigned short u) {
    union { __half h; unsigned short u; } c; c.u = u; return __half2float(c.h);
}

// ---------------- stats ----------------
__global__ __launch_bounds__(256) void stats_kernel(
    const float* __restrict__ pos, const int* __restrict__ batch,
    const int* __restrict__ ntype,
    float* __restrict__ csum, float* __restrict__ ccnt, float* __restrict__ lcnt)
{
    __shared__ float s[NB * 5];
    const int tid = threadIdx.x;
    for (int i = tid; i < NB * 5; i += 256) s[i] = 0.f;
    __syncthreads();
    const int n = blockIdx.x * 256 + tid;
    const int b = batch[n];
    atomicAdd(&s[b*5+0], pos[n*3+0]);
    atomicAdd(&s[b*5+1], pos[n*3+1]);
    atomicAdd(&s[b*5+2], pos[n*3+2]);
    atomicAdd(&s[b*5+3], 1.f);
    if (ntype[n] == 1) atomicAdd(&s[b*5+4], 1.f);
    __syncthreads();
    for (int i = tid; i < NB * 5; i += 256) {
        float v = s[i];
        if (v != 0.f) {
            int b2 = i / 5, f = i - b2*5;
            if (f < 3)       atomAdd(&csum[b2*3+f], v);
            else if (f == 3) atomAdd(&ccnt[b2], v);
            else             atomAdd(&lcnt[b2], v);
        }
    }
}

// ---------------- degree histogram ----------------
__global__ __launch_bounds__(256) void deg_kernel(const int* __restrict__ row, int* __restrict__ degi)
{
    const int e = blockIdx.x * 256 + threadIdx.x;
    atomicAdd(&degi[row[e]], 1);
}

// ---------------- two-level scan ----------------
__global__ __launch_bounds__(256) void scanA_kernel(const int* __restrict__ degi, int* __restrict__ chunkSum)
{
    __shared__ int red[4];
    const int t = threadIdx.x, b = blockIdx.x;
    int v = degi[b*256 + t];
    #pragma unroll
    for (int off = 32; off > 0; off >>= 1) v += __shfl_down(v, off, 64);
    if ((t & 63) == 0) red[t >> 6] = v;
    __syncthreads();
    if (t == 0) chunkSum[b] = red[0] + red[1] + red[2] + red[3];
}

__global__ __launch_bounds__(256) void scanB_kernel(int* __restrict__ chunkSum)
{
    __shared__ int s[256];
    const int t = threadIdx.x;
    const int v = chunkSum[t];
    s[t] = v;
    __syncthreads();
    #pragma unroll
    for (int off = 1; off < 256; off <<= 1) {
        int u = (t >= off) ? s[t - off] : 0;
        __syncthreads();
        s[t] += u;
        __syncthreads();
    }
    chunkSum[t] = s[t] - v;   // exclusive
}

__global__ __launch_bounds__(256) void scanC_kernel(const int* __restrict__ degi,
                                                    const int* __restrict__ chunkOff,
                                                    int* __restrict__ rowStart)
{
    __shared__ int s[256];
    const int t = threadIdx.x, b = blockIdx.x;
    const int v = degi[b*256 + t];
    s[t] = v;
    __syncthreads();
    #pragma unroll
    for (int off = 1; off < 256; off <<= 1) {
        int u = (t >= off) ? s[t - off] : 0;
        __syncthreads();
        s[t] += u;
        __syncthreads();
    }
    rowStart[b*256 + t] = chunkOff[b] + s[t] - v;
}

// ---------------- counting-sort scatter ----------------
__global__ __launch_bounds__(256) void scatter_kernel(
    const int* __restrict__ row, const int* __restrict__ col,
    const int* __restrict__ rowStart, int* __restrict__ cnt,
    unsigned int* __restrict__ rcS)
{
    const int e = blockIdx.x * 256 + threadIdx.x;
    const int r = row[e], c = col[e];
    const int p = rowStart[r] + atomicAdd(&cnt[r], 1);
    rcS[p] = ((unsigned)r << 16) | (unsigned)c;
}

// ---------------- pos_rel ----------------
__global__ __launch_bounds__(256) void posrel_kernel(
    const float* __restrict__ pos, const int* __restrict__ batch,
    const float* __restrict__ csum, const float* __restrict__ ccnt,
    float* __restrict__ posrel)
{
    const int n = blockIdx.x * 256 + threadIdx.x;
    const int b = batch[n];
    const float inv = 1.f / fmaxf(ccnt[b], 1.f);
    posrel[n*3+0] = pos[n*3+0] - csum[b*3+0]*inv;
    posrel[n*3+1] = pos[n*3+1] - csum[b*3+1]*inv;
    posrel[n*3+2] = pos[n*3+2] - csum[b*3+2]*inv;
}

// ---------------- weight prep ----------------
__global__ __launch_bounds__(256) void wprep_kernel(
    const float* __restrict__ mw1, const float* __restrict__ uw,
    const float* __restrict__ mw2,
    unsigned short* __restrict__ w1th, unsigned short* __restrict__ w1tl,
    unsigned short* __restrict__ wuth, unsigned short* __restrict__ wutl,
    unsigned short* __restrict__ w2t)
{
    const int idx = blockIdx.x * 256 + threadIdx.x;   // 98304
    {   // W1T: [l][c<256][k<128]
        const int l = idx >> 15, rem = idx & 32767, c = rem >> 7, k = rem & 127;
        const int kk = (c < 128) ? k : (128 + k);
        const int cc = c & 127;
        const float v = mw1[l*257*128 + kk*128 + cc];
        unsigned short h, lo; split2(v, h, lo);
        w1th[idx] = h; w1tl[idx] = lo;
    }
    {   // WuT: [l][c<128][k<256] = uw[l][k][c]
        const int l = idx >> 15, rem = idx & 32767, c = rem >> 8, k = rem & 255;
        const float v = uw[l*256*128 + k*128 + c];
        unsigned short h, lo; split2(v, h, lo);
        wuth[idx] = h; wutl[idx] = lo;
    }
    if (idx < 49152) {   // W2T: [l][n][k] = mw2[l][k][n]
        const int l = idx >> 14, rem = idx & 16383, n = rem >> 7, k = rem & 127;
        w2t[idx] = f2bf(mw2[(l << 14) + k*128 + n]);
    }
}

// ---------------- lin_in ----------------
__global__ __launch_bounds__(256) void lin_in_gemm(
    const float* __restrict__ emb, const float* __restrict__ posrel,
    const int* __restrict__ zidx,
    const float* __restrict__ W, const float* __restrict__ bias,
    unsigned short* __restrict__ xhi, unsigned short* __restrict__ xlo)
{
    __shared__ __align__(16) float Asm[32][132];
    __shared__ __align__(16) float Wsm[32][128];
    const int tid = threadIdx.x;
    const int n0  = blockIdx.x * 32;
    const float4* __restrict__ A0f4 = (const float4*)emb;

    for (int idx4 = tid; idx4 < 1024; idx4 += 256) {
        int i = idx4 >> 5, k4 = idx4 & 31;
        int zz = zidx[n0 + i];
        *(float4*)&Asm[i][k4*4] = A0f4[zz*32 + k4];
    }
    if (tid < 96) { int i = tid / 3, d = tid - i*3; Asm[i][128+d] = posrel[(n0+i)*3 + d]; }
    else if (tid < 128) { Asm[tid-96][131] = 0.f; }

    const int tj = tid & 31;
    const int tn = tid >> 5;
    float acc[4][4];
    #pragma unroll
    for (int r = 0; r < 4; ++r)
        #pragma unroll
        for (int c = 0; c < 4; ++c) acc[r][c] = 0.f;

    const float4* __restrict__ Wf4 = (const float4*)W;
    #pragma unroll 1
    for (int kc = 0; kc < 131; kc += 32) {
        const int kend = (131 - kc < 32) ? (131 - kc) : 32;
        __syncthreads();
        for (int idx4 = tid; idx4 < kend*32; idx4 += 256) {
            int kk = idx4 >> 5, j4 = idx4 & 31;
            *(float4*)&Wsm[kk][j4*4] = Wf4[(kc+kk)*32 + j4];
        }
        __syncthreads();
        for (int kk = 0; kk < kend; ++kk) {
            const float4 w = *(const float4*)&Wsm[kk][tj*4];
            #pragma unroll
            for (int r = 0; r < 4; ++r) {
                const float a = Asm[tn*4+r][kc+kk];
                acc[r][0] += a*w.x; acc[r][1] += a*w.y; acc[r][2] += a*w.z; acc[r][3] += a*w.w;
            }
        }
    }

    const float4 bias4 = ((const float4*)bias)[tj];
    #pragma unroll
    for (int r = 0; r < 4; ++r) {
        const int node = n0 + tn*4 + r;
        const float o[4] = { acc[r][0] + bias4.x, acc[r][1] + bias4.y,
                             acc[r][2] + bias4.z, acc[r][3] + bias4.w };
        ushort4 h4, l4;
        split2(o[0], h4.x, l4.x); split2(o[1], h4.y, l4.y);
        split2(o[2], h4.z, l4.z); split2(o[3], h4.w, l4.w);
        *(ushort4*)&xhi[node*HD + tj*4] = h4;
        *(ushort4*)&xlo[node*HD + tj*4] = l4;
    }
}

// ---------------- pq GEMM (MFMA, split-bf16 3-pass) ----------------
__global__ __launch_bounds__(256) void pq_gemm(
    const unsigned short* __restrict__ xhi, const unsigned short* __restrict__ xlo,
    const unsigned short* __restrict__ w1th, const unsigned short* __restrict__ w1tl,
    unsigned short* __restrict__ Ph, unsigned short* __restrict__ Qh)
{
    const int tid = threadIdx.x;
    const int l = tid & 63, w = tid >> 6;
    const int mr = l & 15, qd = l >> 4;
    const int n0 = blockIdx.x * 64;
    const int c0 = w * 64;

    f32x4 acc[4][4];
    #pragma unroll
    for (int mt = 0; mt < 4; ++mt)
        #pragma unroll
        for (int nt = 0; nt < 4; ++nt) acc[mt][nt] = (f32x4){0.f,0.f,0.f,0.f};

    #pragma unroll
    for (int ks = 0; ks < 4; ++ks) {
        const int kof = ks*32 + qd*8;
        bf16x8 ah[4], al[4], bh[4], bl[4];
        #pragma unroll
        for (int mt = 0; mt < 4; ++mt) {
            const int node = n0 + mt*16 + mr;
            ah[mt] = *(const bf16x8*)&xhi[node*HD + kof];
            al[mt] = *(const bf16x8*)&xlo[node*HD + kof];
        }
        #pragma unroll
        for (int nt = 0; nt < 4; ++nt) {
            const int c = c0 + nt*16 + mr;
            bh[nt] = *(const bf16x8*)&w1th[c*HD + kof];
            bl[nt] = *(const bf16x8*)&w1tl[c*HD + kof];
        }
        #pragma unroll
        for (int mt = 0; mt < 4; ++mt)
            #pragma unroll
            for (int nt = 0; nt < 4; ++nt) {
                acc[mt][nt] = __builtin_amdgcn_mfma_f32_16x16x32_bf16(ah[mt], bh[nt], acc[mt][nt], 0,0,0);
                acc[mt][nt] = __builtin_amdgcn_mfma_f32_16x16x32_bf16(ah[mt], bl[nt], acc[mt][nt], 0,0,0);
                acc[mt][nt] = __builtin_amdgcn_mfma_f32_16x16x32_bf16(al[mt], bh[nt], acc[mt][nt], 0,0,0);
            }
    }

    unsigned short* __restrict__ dst = (w < 2) ? Ph : Qh;
    const int cbase = (w < 2) ? c0 : c0 - 128;
    #pragma unroll
    for (int mt = 0; mt < 4; ++mt)
        #pragma unroll
        for (int nt = 0; nt < 4; ++nt) {
            const int cc = cbase + nt*16 + mr;
            #pragma unroll
            for (int r = 0; r < 4; ++r) {
                const int node = n0 + mt*16 + qd*4 + r;
                dst[(long)node*HD + cc] = f2h(acc[mt][nt][r]);
            }
        }
}

// ---------------- update GEMM (MFMA, split-bf16 3-pass) ----------------
__global__ __launch_bounds__(256) void upd_gemm(
    unsigned short* __restrict__ xhi, unsigned short* __restrict__ xlo,
    const float* __restrict__ msum, const int* __restrict__ degi,
    const unsigned short* __restrict__ wuth, const unsigned short* __restrict__ wutl,
    const float* __restrict__ bias)
{
    const int tid = threadIdx.x;
    const int l = tid & 63, w = tid >> 6;
    const int mr = l & 15, qd = l >> 4;
    const int n0 = blockIdx.x * 64 + w*16;
    const int node = n0 + mr;
    const float inv = 1.f / fmaxf((float)degi[node], 1.f);

    f32x4 acc[8];
    #pragma unroll
    for (int nt = 0; nt < 8; ++nt) acc[nt] = (f32x4){0.f,0.f,0.f,0.f};

    #pragma unroll 1
    for (int ks = 0; ks < 8; ++ks) {
        const int kof = ks*32 + qd*8;
        bf16x8 ah, al;
        if (ks < 4) {
            ah = *(const bf16x8*)&xhi[node*HD + kof];
            al = *(const bf16x8*)&xlo[node*HD + kof];
        } else {
            const int mk = kof - 128;
            const float4 v0 = *(const float4*)&msum[(long)node*HD + mk];
            const float4 v1 = *(const float4*)&msum[(long)node*HD + mk + 4];
            union { bf16x8 v; unsigned short u[8]; } hh, ll;
            float vv[8] = { v0.x*inv, v0.y*inv, v0.z*inv, v0.w*inv,
                            v1.x*inv, v1.y*inv, v1.z*inv, v1.w*inv };
            #pragma unroll
            for (int i = 0; i < 8; ++i) split2(vv[i], hh.u[i], ll.u[i]);
            ah = hh.v; al = ll.v;
        }
        #pragma unroll
        for (int nt = 0; nt < 8; ++nt) {
            const int c = nt*16 + mr;
            const bf16x8 bh = *(const bf16x8*)&wuth[c*256 + kof];
            const bf16x8 bl = *(const bf16x8*)&wutl[c*256 + kof];
            acc[nt] = __builtin_amdgcn_mfma_f32_16x16x32_bf16(ah, bh, acc[nt], 0,0,0);
            acc[nt] = __builtin_amdgcn_mfma_f32_16x16x32_bf16(ah, bl, acc[nt], 0,0,0);
            acc[nt] = __builtin_amdgcn_mfma_f32_16x16x32_bf16(al, bh, acc[nt], 0,0,0);
        }
    }

    #pragma unroll
    for (int nt = 0; nt < 8; ++nt) {
        const int c = nt*16 + mr;
        const float bb = bias[c];
        #pragma unroll
        for (int r = 0; r < 4; ++r) {
            const int nd = n0 + qd*4 + r;
            const float o = fmaxf(acc[nt][r] + bb, 0.f);
            unsigned short h, lo; split2(o, h, lo);
            xhi[nd*HD + c] = h;
            xlo[nd*HD + c] = lo;
        }
    }
}

// ---------------- fused edge kernel (fp16 P/Q gathers) ----------------
__global__ __launch_bounds__(256) void edge_msg_kernel(
    const unsigned short* __restrict__ Ph, const unsigned short* __restrict__ Qh,
    const float* __restrict__ posrel,
    const unsigned int* __restrict__ rcS,
    const float* __restrict__ w1c, const float* __restrict__ b1,
    const unsigned short* __restrict__ w2t,
    const float* __restrict__ b2,
    float* __restrict__ msum)
{
    const int tid = threadIdx.x;
    const long e0 = (long)blockIdx.x * 256;
    const int l  = tid & 63;
    const int w  = tid >> 6;
    const int mr = l & 15;
    const int qd = l >> 4;
    const long ebase = e0 + w*64;

    const int aoff = ((mr >> 2) << 4) + (mr & 3);
    int ecol[4], erow[4];
    float edist[4];
    #pragma unroll
    for (int m = 0; m < 4; ++m) {
        const unsigned rc = rcS[ebase + aoff + m*4];
        erow[m] = (int)(rc >> 16); ecol[m] = (int)(rc & 0xffffu);
    }
    #pragma unroll
    for (int m = 0; m < 4; ++m) {
        const int c = ecol[m], r = erow[m];
        const float dx = posrel[c*3+0] - posrel[r*3+0];
        const float dy = posrel[c*3+1] - posrel[r*3+1];
        const float dz = posrel[c*3+2] - posrel[r*3+2];
        edist[m] = sqrtf(dx*dx + dy*dy + dz*dz);
    }

    unsigned rcv[16];
    {
        const uint4* rc4 = (const uint4*)&rcS[ebase + qd*16];
        #pragma unroll
        for (int i = 0; i < 4; ++i) {
            const uint4 v = rc4[i];
            rcv[i*4+0] = v.x >> 16; rcv[i*4+1] = v.y >> 16;
            rcv[i*4+2] = v.z >> 16; rcv[i*4+3] = v.w >> 16;
        }
    }

    bf16x8 afr[4][4];
    const float4* __restrict__ c1f4 = (const float4*)w1c;
    const float4* __restrict__ b1f4 = (const float4*)b1;
    #pragma unroll
    for (int kk = 0; kk < 4; ++kk) {
        const int kof = kk*32 + qd*8;
        const int kb4 = kof >> 2;
        const float4 c0  = c1f4[kb4],   c1v = c1f4[kb4+1];
        const float4 b0  = b1f4[kb4],   b1v = b1f4[kb4+1];
        const float carr[8] = { c0.x, c0.y, c0.z, c0.w, c1v.x, c1v.y, c1v.z, c1v.w };
        const float barr[8] = { b0.x, b0.y, b0.z, b0.w, b1v.x, b1v.y, b1v.z, b1v.w };
        #pragma unroll
        for (int m = 0; m < 4; ++m) {
            const u16x8 pu = *(const u16x8*)&Ph[(long)ecol[m]*HD + kof];
            const u16x8 qu = *(const u16x8*)&Qh[(long)erow[m]*HD + kof];
            const float d = edist[m];
            union { bf16x8 v; unsigned short u[8]; } au;
            #pragma unroll
            for (int i = 0; i < 8; ++i)
                au.u[i] = f2bf(fmaxf(h2f(pu[i]) + h2f(qu[i]) + d*carr[i] + barr[i], 0.f));
            afr[m][kk] = au.v;
        }
    }

    const bf16x8* __restrict__ w2tv = (const bf16x8*)w2t;
    bf16x8 bfr[4];
    #pragma unroll
    for (int kk = 0; kk < 4; ++kk)
        bfr[kk] = w2tv[(0*16 + mr)*16 + kk*4 + qd];

    #pragma unroll 1
    for (int t = 0; t < 8; ++t) {
        bf16x8 bnext[4];
        if (t < 7) {
            #pragma unroll
            for (int kk = 0; kk < 4; ++kk)
                bnext[kk] = w2tv[((t+1)*16 + mr)*16 + kk*4 + qd];
        }
        const int colg = t*16 + mr;
        const float bb = b2[colg];

        f32x4 acc[4];
        #pragma unroll
        for (int m = 0; m < 4; ++m) acc[m] = (f32x4){0.f, 0.f, 0.f, 0.f};
        #pragma unroll
        for (int kk = 0; kk < 4; ++kk)
            #pragma unroll
            for (int m = 0; m < 4; ++m)
                acc[m] = __builtin_amdgcn_mfma_f32_16x16x32_bf16(afr[m][kk], bfr[kk], acc[m], 0, 0, 0);

        int rprev = -1;
        float run = 0.f;
        #pragma unroll
        for (int m = 0; m < 4; ++m) {
            #pragma unroll
            for (int r4 = 0; r4 < 4; ++r4) {
                const int rw = (int)rcv[m*4 + r4];
                const float v = fmaxf(acc[m][r4] + bb, 0.f);
                if (rw != rprev) {
                    if (rprev >= 0) atomAdd(&msum[(long)rprev*HD + colg], run);
                    rprev = rw; run = v;
                } else {
                    run += v;
                }
            }
        }
        atomAdd(&msum[(long)rprev*HD + colg], run);

        #pragma unroll
        for (int kk = 0; kk < 4; ++kk) bfr[kk] = bnext[kk];
    }
}

// ---------------- ligand-masked per-graph sum: batch-sorted run aggregation ----------------
// block covers 512 contiguous nodes; thread = (col-group cg, 64-node strip ns).
// batch[] is sorted -> each strip spans ~1-2 graphs -> ~1-2 atomic4 per thread.
__global__ __launch_bounds__(256) void gsum_kernel(
    const unsigned short* __restrict__ xhi, const unsigned short* __restrict__ xlo,
    const int* __restrict__ batch,
    const int* __restrict__ ntype, float* __restrict__ gsum)
{
    const int tid = threadIdx.x;
    const int cg = tid & 31;          // float4 col group
    const int ns = tid >> 5;          // node strip 0..7
    const int n0 = blockIdx.x * 512 + ns * 64;

    int bprev = -1;
    float4 run = make_float4(0.f, 0.f, 0.f, 0.f);
    for (int i = 0; i < 64; ++i) {
        const int n = n0 + i;
        if (ntype[n] != 1) continue;
        const int b = batch[n];
        const ushort4 h  = *(const ushort4*)&xhi[(long)n*HD + cg*4];
        const ushort4 lo = *(const ushort4*)&xlo[(long)n*HD + cg*4];
        float4 v;
        v.x = bf2f(h.x) + bf2f(lo.x);
        v.y = bf2f(h.y) + bf2f(lo.y);
        v.z = bf2f(h.z) + bf2f(lo.z);
        v.w = bf2f(h.w) + bf2f(lo.w);
        if (b != bprev) {
            if (bprev >= 0) {
                float* dst = &gsum[bprev*HD + cg*4];
                atomAdd(dst+0, run.x); atomAdd(dst+1, run.y);
                atomAdd(dst+2, run.z); atomAdd(dst+3, run.w);
            }
            bprev = b; run = v;
        } else {
            run.x += v.x; run.y += v.y; run.z += v.z; run.w += v.w;
        }
    }
    if (bprev >= 0) {
        float* dst = &gsum[bprev*HD + cg*4];
        atomAdd(dst+0, run.x); atomAdd(dst+1, run.y);
        atomAdd(dst+2, run.z); atomAdd(dst+3, run.w);
    }
}

// ---------------- readout ----------------
__global__ __launch_bounds__(128) void readout_kernel(
    const float* __restrict__ gsum, const float* __restrict__ lcnt,
    const float* __restrict__ w1, const float* __restrict__ b1,
    const float* __restrict__ w2, const float* __restrict__ b2,
    float* __restrict__ out)
{
    __shared__ float gs[HD];
    __shared__ float red[2];
    const int b = blockIdx.x, j = threadIdx.x;
    gs[j] = gsum[b*HD + j] / fmaxf(lcnt[b], 1.f);
    __syncthreads();
    float acc = b1[j];
    for (int k = 0; k < HD; ++k) acc += gs[k]*w1[k*HD + j];
    float hg = fmaxf(acc, 0.f) * w2[j];
    #pragma unroll
    for (int off = 32; off > 0; off >>= 1) hg += __shfl_down(hg, off, 64);
    if ((j & 63) == 0) red[j >> 6] = hg;
    __syncthreads();
    if (j == 0) out[b] = red[0] + red[1] + b2[0];
}

extern "C" void kernel_launch(void* const* d_in, const int* in_sizes, int n_in,
                              void* d_out, int out_size, void* d_ws, size_t ws_size,
                              hipStream_t stream)
{
    const float* pos   = (const float*)d_in[0];
    const int*   z     = (const int*)d_in[1];
    const int*   batch = (const int*)d_in[2];
    const int*   eidx  = (const int*)d_in[3];
    const int*   ntype = (const int*)d_in[4];
    const float* emb   = (const float*)d_in[5];
    const float* lin_w = (const float*)d_in[6];
    const float* lin_b = (const float*)d_in[7];
    const float* mw1   = (const float*)d_in[8];
    const float* mb1   = (const float*)d_in[9];
    const float* mw2   = (const float*)d_in[10];
    const float* mb2   = (const float*)d_in[11];
    const float* uw    = (const float*)d_in[12];
    const float* ub    = (const float*)d_in[13];
    const float* rw1   = (const float*)d_in[14];
    const float* rb1   = (const float*)d_in[15];
    const float* rw2   = (const float*)d_in[16];
    const float* rb2   = (const float*)d_in[17];

    const int* row = eidx;
    const int* col = eidx + NE;

    float* ws     = (float*)d_ws;
    float* csum   = ws + O_CSUM;
    float* ccnt   = ws + O_CCNT;
    float* lcnt   = ws + O_LCNT;
    float* gsum   = ws + O_GSUM;
    int*   degi   = (int*)(ws + O_DEGI);
    float* posrel = ws + O_POSREL;
    unsigned int* rcS = (unsigned int*)(ws + O_RC);
    unsigned short* xhi = (unsigned short*)(ws + O_XHI);
    unsigned short* xlo = (unsigned short*)(ws + O_XLO);
    unsigned short* Ph  = (unsigned short*)(ws + O_P);
    unsigned short* Qh  = (unsigned short*)(ws + O_Q);
    float* msum   = ws + O_MSUM;
    unsigned short* w2t  = (unsigned short*)(ws + O_W2T);
    unsigned short* w1th = (unsigned short*)(ws + O_W1TH);
    unsigned short* w1tl = (unsigned short*)(ws + O_W1TL);
    unsigned short* wuth = (unsigned short*)(ws + O_WUTH);
    unsigned short* wutl = (unsigned short*)(ws + O_WUTL);
    int* chunkSum = (int*)(ws + O_CHK);
    int* rowStart = (int*)xhi;           // alias xhi head pre-lin_in
    int* cnt      = (int*)xhi + NN;

    (void)hipMemsetAsync(ws, 0, (size_t)(O_DEGI + NN) * sizeof(float), stream);
    (void)hipMemsetAsync(cnt, 0, (size_t)NN * sizeof(int), stream);

    stats_kernel  <<<NN/256, 256, 0, stream>>>(pos, batch, ntype, csum, ccnt, lcnt);
    deg_kernel    <<<NE/256, 256, 0, stream>>>(row, degi);
    posrel_kernel <<<NN/256, 256, 0, stream>>>(pos, batch, csum, ccnt, posrel);
    scanA_kernel  <<<256, 256, 0, stream>>>(degi, chunkSum);
    scanB_kernel  <<<1, 256, 0, stream>>>(chunkSum);
    scanC_kernel  <<<256, 256, 0, stream>>>(degi, chunkSum, rowStart);
    scatter_kernel<<<NE/256, 256, 0, stream>>>(row, col, rowStart, cnt, rcS);
    wprep_kernel  <<<384, 256, 0, stream>>>(mw1, uw, mw2, w1th, w1tl, wuth, wutl, w2t);

    lin_in_gemm<<<NN/32, 256, 0, stream>>>(emb, posrel, z, lin_w, lin_b, xhi, xlo);

    for (int l = 0; l < NL; ++l) {
        const float* W1 = mw1 + (size_t)l*257*HD;
        pq_gemm<<<NN/64, 256, 0, stream>>>(xhi, xlo, w1th + (size_t)l*32768, w1tl + (size_t)l*32768, Ph, Qh);
        (void)hipMemsetAsync(msum, 0, (size_t)NN*HD*sizeof(float), stream);
        edge_msg_kernel<<<NE/256, 256, 0, stream>>>(Ph, Qh, posrel, rcS,
                                                    W1 + 256*HD, mb1 + l*HD,
                                                    w2t + (size_t)l*16384, mb2 + l*HD, msum);
        upd_gemm<<<NN/64, 256, 0, stream>>>(xhi, xlo, msum, degi,
                                            wuth + (size_t)l*32768, wutl + (size_t)l*32768,
                                            ub + l*HD);
    }

    gsum_kernel   <<<NN/512, 256, 0, stream>>>(xhi, xlo, batch, ntype, gsum);
    readout_kernel<<<NB, 128, 0, stream>>>(gsum, lcnt, rw1, rb1, rw2, rb2, (float*)d_out);
}

// Round 14
// 999.228 us; speedup vs baseline: 3.1533x; 1.0435x over previous
//
#include <hip/hip_runtime.h>
#include <hip/hip_bf16.h>
#include <hip/hip_fp16.h>
#include <math.h>

#define NN 65536
#define NE 1048576
#define NB 64
#define HD 128
#define NL 3

// ---- workspace layout (float offsets) ----
#define O_CSUM   0
#define O_CCNT   192
#define O_LCNT   256
#define O_GSUM   320         // -> 8512
#define O_DEGI   8512        // -> 74048
#define O_POSREL 74048       // -> 270656
#define O_RC     270656      // -> 1319232
#define O_XHI    1319232     // NN*128 ushort -> 5513536
#define O_XLO    5513536     // -> 9707840
#define O_P      9707840     // NN*128 fp16 -> 18096448
#define O_Q      18096448    // -> 26485056
#define O_MSUM   26485056    // -> 34873664
#define O_W2T    34873664    // 3*128*128 fp16 -> 34898240
#define O_W1TH   34898240    // -> 34947392
#define O_W1TL   34947392    // -> 34996544
#define O_WUTH   34996544    // -> 35045696
#define O_WUTL   35045696    // -> 35094848
#define O_CHK    35094848    // 256 ints -> 35095104 (~140.4 MB)

typedef __attribute__((ext_vector_type(8))) short bf16x8;
typedef __attribute__((ext_vector_type(8))) _Float16 f16x8;
typedef __attribute__((ext_vector_type(8))) unsigned short u16x8;
typedef __attribute__((ext_vector_type(4))) float f32x4;

__device__ __forceinline__ void atomAdd(float* p, float v) { unsafeAtomicAdd(p, v); }

__device__ __forceinline__ unsigned short f2bf(float f) {
    union { __hip_bfloat16 h; unsigned short u; } cv;
    cv.h = __float2bfloat16(f);
    return cv.u;
}
__device__ __forceinline__ float bf2f(unsigned short u) {
    union { float f; unsigned v; } c; c.v = ((unsigned)u) << 16; return c.f;
}
__device__ __forceinline__ void split2(float v, unsigned short& h, unsigned short& l) {
    h = f2bf(v); l = f2bf(v - bf2f(h));
}
__device__ __forceinline__ unsigned short f2h(float f) {
    union { __half h; unsigned short u; } c; c.h = __float2half(f); return c.u;
}

// ---------------- stats ----------------
__global__ __launch_bounds__(256) void stats_kernel(
    const float* __restrict__ pos, const int* __restrict__ batch,
    const int* __restrict__ ntype,
    float* __restrict__ csum, float* __restrict__ ccnt, float* __restrict__ lcnt)
{
    __shared__ float s[NB * 5];
    const int tid = threadIdx.x;
    for (int i = tid; i < NB * 5; i += 256) s[i] = 0.f;
    __syncthreads();
    const int n = blockIdx.x * 256 + tid;
    const int b = batch[n];
    atomicAdd(&s[b*5+0], pos[n*3+0]);
    atomicAdd(&s[b*5+1], pos[n*3+1]);
    atomicAdd(&s[b*5+2], pos[n*3+2]);
    atomicAdd(&s[b*5+3], 1.f);
    if (ntype[n] == 1) atomicAdd(&s[b*5+4], 1.f);
    __syncthreads();
    for (int i = tid; i < NB * 5; i += 256) {
        float v = s[i];
        if (v != 0.f) {
            int b2 = i / 5, f = i - b2*5;
            if (f < 3)       atomAdd(&csum[b2*3+f], v);
            else if (f == 3) atomAdd(&ccnt[b2], v);
            else             atomAdd(&lcnt[b2], v);
        }
    }
}

// ---------------- degree histogram ----------------
__global__ __launch_bounds__(256) void deg_kernel(const int* __restrict__ row, int* __restrict__ degi)
{
    const int e = blockIdx.x * 256 + threadIdx.x;
    atomicAdd(&degi[row[e]], 1);
}

// ---------------- two-level scan ----------------
__global__ __launch_bounds__(256) void scanA_kernel(const int* __restrict__ degi, int* __restrict__ chunkSum)
{
    __shared__ int red[4];
    const int t = threadIdx.x, b = blockIdx.x;
    int v = degi[b*256 + t];
    #pragma unroll
    for (int off = 32; off > 0; off >>= 1) v += __shfl_down(v, off, 64);
    if ((t & 63) == 0) red[t >> 6] = v;
    __syncthreads();
    if (t == 0) chunkSum[b] = red[0] + red[1] + red[2] + red[3];
}

__global__ __launch_bounds__(256) void scanB_kernel(int* __restrict__ chunkSum)
{
    __shared__ int s[256];
    const int t = threadIdx.x;
    const int v = chunkSum[t];
    s[t] = v;
    __syncthreads();
    #pragma unroll
    for (int off = 1; off < 256; off <<= 1) {
        int u = (t >= off) ? s[t - off] : 0;
        __syncthreads();
        s[t] += u;
        __syncthreads();
    }
    chunkSum[t] = s[t] - v;   // exclusive
}

__global__ __launch_bounds__(256) void scanC_kernel(const int* __restrict__ degi,
                                                    const int* __restrict__ chunkOff,
                                                    int* __restrict__ rowStart)
{
    __shared__ int s[256];
    const int t = threadIdx.x, b = blockIdx.x;
    const int v = degi[b*256 + t];
    s[t] = v;
    __syncthreads();
    #pragma unroll
    for (int off = 1; off < 256; off <<= 1) {
        int u = (t >= off) ? s[t - off] : 0;
        __syncthreads();
        s[t] += u;
        __syncthreads();
    }
    rowStart[b*256 + t] = chunkOff[b] + s[t] - v;
}

// ---------------- counting-sort scatter ----------------
__global__ __launch_bounds__(256) void scatter_kernel(
    const int* __restrict__ row, const int* __restrict__ col,
    const int* __restrict__ rowStart, int* __restrict__ cnt,
    unsigned int* __restrict__ rcS)
{
    const int e = blockIdx.x * 256 + threadIdx.x;
    const int r = row[e], c = col[e];
    const int p = rowStart[r] + atomicAdd(&cnt[r], 1);
    rcS[p] = ((unsigned)r << 16) | (unsigned)c;
}

// ---------------- pos_rel ----------------
__global__ __launch_bounds__(256) void posrel_kernel(
    const float* __restrict__ pos, const int* __restrict__ batch,
    const float* __restrict__ csum, const float* __restrict__ ccnt,
    float* __restrict__ posrel)
{
    const int n = blockIdx.x * 256 + threadIdx.x;
    const int b = batch[n];
    const float inv = 1.f / fmaxf(ccnt[b], 1.f);
    posrel[n*3+0] = pos[n*3+0] - csum[b*3+0]*inv;
    posrel[n*3+1] = pos[n*3+1] - csum[b*3+1]*inv;
    posrel[n*3+2] = pos[n*3+2] - csum[b*3+2]*inv;
}

// ---------------- weight prep (W2T fp16) ----------------
__global__ __launch_bounds__(256) void wprep_kernel(
    const float* __restrict__ mw1, const float* __restrict__ uw,
    const float* __restrict__ mw2,
    unsigned short* __restrict__ w1th, unsigned short* __restrict__ w1tl,
    unsigned short* __restrict__ wuth, unsigned short* __restrict__ wutl,
    unsigned short* __restrict__ w2t)
{
    const int idx = blockIdx.x * 256 + threadIdx.x;   // 98304
    {   // W1T: [l][c<256][k<128]
        const int l = idx >> 15, rem = idx & 32767, c = rem >> 7, k = rem & 127;
        const int kk = (c < 128) ? k : (128 + k);
        const int cc = c & 127;
        const float v = mw1[l*257*128 + kk*128 + cc];
        unsigned short h, lo; split2(v, h, lo);
        w1th[idx] = h; w1tl[idx] = lo;
    }
    {   // WuT: [l][c<128][k<256] = uw[l][k][c]
        const int l = idx >> 15, rem = idx & 32767, c = rem >> 8, k = rem & 255;
        const float v = uw[l*256*128 + k*128 + c];
        unsigned short h, lo; split2(v, h, lo);
        wuth[idx] = h; wutl[idx] = lo;
    }
    if (idx < 49152) {   // W2T fp16: [l][n][k] = mw2[l][k][n]
        const int l = idx >> 14, rem = idx & 16383, n = rem >> 7, k = rem & 127;
        w2t[idx] = f2h(mw2[(l << 14) + k*128 + n]);
    }
}

// ---------------- lin_in ----------------
__global__ __launch_bounds__(256) void lin_in_gemm(
    const float* __restrict__ emb, const float* __restrict__ posrel,
    const int* __restrict__ zidx,
    const float* __restrict__ W, const float* __restrict__ bias,
    unsigned short* __restrict__ xhi, unsigned short* __restrict__ xlo)
{
    __shared__ __align__(16) float Asm[32][132];
    __shared__ __align__(16) float Wsm[32][128];
    const int tid = threadIdx.x;
    const int n0  = blockIdx.x * 32;
    const float4* __restrict__ A0f4 = (const float4*)emb;

    for (int idx4 = tid; idx4 < 1024; idx4 += 256) {
        int i = idx4 >> 5, k4 = idx4 & 31;
        int zz = zidx[n0 + i];
        *(float4*)&Asm[i][k4*4] = A0f4[zz*32 + k4];
    }
    if (tid < 96) { int i = tid / 3, d = tid - i*3; Asm[i][128+d] = posrel[(n0+i)*3 + d]; }
    else if (tid < 128) { Asm[tid-96][131] = 0.f; }

    const int tj = tid & 31;
    const int tn = tid >> 5;
    float acc[4][4];
    #pragma unroll
    for (int r = 0; r < 4; ++r)
        #pragma unroll
        for (int c = 0; c < 4; ++c) acc[r][c] = 0.f;

    const float4* __restrict__ Wf4 = (const float4*)W;
    #pragma unroll 1
    for (int kc = 0; kc < 131; kc += 32) {
        const int kend = (131 - kc < 32) ? (131 - kc) : 32;
        __syncthreads();
        for (int idx4 = tid; idx4 < kend*32; idx4 += 256) {
            int kk = idx4 >> 5, j4 = idx4 & 31;
            *(float4*)&Wsm[kk][j4*4] = Wf4[(kc+kk)*32 + j4];
        }
        __syncthreads();
        for (int kk = 0; kk < kend; ++kk) {
            const float4 w = *(const float4*)&Wsm[kk][tj*4];
            #pragma unroll
            for (int r = 0; r < 4; ++r) {
                const float a = Asm[tn*4+r][kc+kk];
                acc[r][0] += a*w.x; acc[r][1] += a*w.y; acc[r][2] += a*w.z; acc[r][3] += a*w.w;
            }
        }
    }

    const float4 bias4 = ((const float4*)bias)[tj];
    #pragma unroll
    for (int r = 0; r < 4; ++r) {
        const int node = n0 + tn*4 + r;
        const float o[4] = { acc[r][0] + bias4.x, acc[r][1] + bias4.y,
                             acc[r][2] + bias4.z, acc[r][3] + bias4.w };
        ushort4 h4, l4;
        split2(o[0], h4.x, l4.x); split2(o[1], h4.y, l4.y);
        split2(o[2], h4.z, l4.z); split2(o[3], h4.w, l4.w);
        *(ushort4*)&xhi[node*HD + tj*4] = h4;
        *(ushort4*)&xlo[node*HD + tj*4] = l4;
    }
}

// ---------------- pq GEMM (MFMA, split-bf16 3-pass) ----------------
__global__ __launch_bounds__(256) void pq_gemm(
    const unsigned short* __restrict__ xhi, const unsigned short* __restrict__ xlo,
    const unsigned short* __restrict__ w1th, const unsigned short* __restrict__ w1tl,
    unsigned short* __restrict__ Ph, unsigned short* __restrict__ Qh)
{
    const int tid = threadIdx.x;
    const int l = tid & 63, w = tid >> 6;
    const int mr = l & 15, qd = l >> 4;
    const int n0 = blockIdx.x * 64;
    const int c0 = w * 64;

    f32x4 acc[4][4];
    #pragma unroll
    for (int mt = 0; mt < 4; ++mt)
        #pragma unroll
        for (int nt = 0; nt < 4; ++nt) acc[mt][nt] = (f32x4){0.f,0.f,0.f,0.f};

    #pragma unroll
    for (int ks = 0; ks < 4; ++ks) {
        const int kof = ks*32 + qd*8;
        bf16x8 ah[4], al[4], bh[4], bl[4];
        #pragma unroll
        for (int mt = 0; mt < 4; ++mt) {
            const int node = n0 + mt*16 + mr;
            ah[mt] = *(const bf16x8*)&xhi[node*HD + kof];
            al[mt] = *(const bf16x8*)&xlo[node*HD + kof];
        }
        #pragma unroll
        for (int nt = 0; nt < 4; ++nt) {
            const int c = c0 + nt*16 + mr;
            bh[nt] = *(const bf16x8*)&w1th[c*HD + kof];
            bl[nt] = *(const bf16x8*)&w1tl[c*HD + kof];
        }
        #pragma unroll
        for (int mt = 0; mt < 4; ++mt)
            #pragma unroll
            for (int nt = 0; nt < 4; ++nt) {
                acc[mt][nt] = __builtin_amdgcn_mfma_f32_16x16x32_bf16(ah[mt], bh[nt], acc[mt][nt], 0,0,0);
                acc[mt][nt] = __builtin_amdgcn_mfma_f32_16x16x32_bf16(ah[mt], bl[nt], acc[mt][nt], 0,0,0);
                acc[mt][nt] = __builtin_amdgcn_mfma_f32_16x16x32_bf16(al[mt], bh[nt], acc[mt][nt], 0,0,0);
            }
    }

    unsigned short* __restrict__ dst = (w < 2) ? Ph : Qh;
    const int cbase = (w < 2) ? c0 : c0 - 128;
    #pragma unroll
    for (int mt = 0; mt < 4; ++mt)
        #pragma unroll
        for (int nt = 0; nt < 4; ++nt) {
            const int cc = cbase + nt*16 + mr;
            #pragma unroll
            for (int r = 0; r < 4; ++r) {
                const int node = n0 + mt*16 + qd*4 + r;
                dst[(long)node*HD + cc] = f2h(acc[mt][nt][r]);
            }
        }
}

// ---------------- update GEMM (MFMA, split-bf16 3-pass) ----------------
__global__ __launch_bounds__(256) void upd_gemm(
    unsigned short* __restrict__ xhi, unsigned short* __restrict__ xlo,
    const float* __restrict__ msum, const int* __restrict__ degi,
    const unsigned short* __restrict__ wuth, const unsigned short* __restrict__ wutl,
    const float* __restrict__ bias)
{
    const int tid = threadIdx.x;
    const int l = tid & 63, w = tid >> 6;
    const int mr = l & 15, qd = l >> 4;
    const int n0 = blockIdx.x * 64 + w*16;
    const int node = n0 + mr;
    const float inv = 1.f / fmaxf((float)degi[node], 1.f);

    f32x4 acc[8];
    #pragma unroll
    for (int nt = 0; nt < 8; ++nt) acc[nt] = (f32x4){0.f,0.f,0.f,0.f};

    #pragma unroll 1
    for (int ks = 0; ks < 8; ++ks) {
        const int kof = ks*32 + qd*8;
        bf16x8 ah, al;
        if (ks < 4) {
            ah = *(const bf16x8*)&xhi[node*HD + kof];
            al = *(const bf16x8*)&xlo[node*HD + kof];
        } else {
            const int mk = kof - 128;
            const float4 v0 = *(const float4*)&msum[(long)node*HD + mk];
            const float4 v1 = *(const float4*)&msum[(long)node*HD + mk + 4];
            union { bf16x8 v; unsigned short u[8]; } hh, ll;
            float vv[8] = { v0.x*inv, v0.y*inv, v0.z*inv, v0.w*inv,
                            v1.x*inv, v1.y*inv, v1.z*inv, v1.w*inv };
            #pragma unroll
            for (int i = 0; i < 8; ++i) split2(vv[i], hh.u[i], ll.u[i]);
            ah = hh.v; al = ll.v;
        }
        #pragma unroll
        for (int nt = 0; nt < 8; ++nt) {
            const int c = nt*16 + mr;
            const bf16x8 bh = *(const bf16x8*)&wuth[c*256 + kof];
            const bf16x8 bl = *(const bf16x8*)&wutl[c*256 + kof];
            acc[nt] = __builtin_amdgcn_mfma_f32_16x16x32_bf16(ah, bh, acc[nt], 0,0,0);
            acc[nt] = __builtin_amdgcn_mfma_f32_16x16x32_bf16(ah, bl, acc[nt], 0,0,0);
            acc[nt] = __builtin_amdgcn_mfma_f32_16x16x32_bf16(al, bh, acc[nt], 0,0,0);
        }
    }

    #pragma unroll
    for (int nt = 0; nt < 8; ++nt) {
        const int c = nt*16 + mr;
        const float bb = bias[c];
        #pragma unroll
        for (int r = 0; r < 4; ++r) {
            const int nd = n0 + qd*4 + r;
            const float o = fmaxf(acc[nt][r] + bb, 0.f);
            unsigned short h, lo; split2(o, h, lo);
            xhi[nd*HD + c] = h;
            xlo[nd*HD + c] = lo;
        }
    }
}

// ---------------- fused edge kernel: packed-fp16 H build (_Float16 vectors) + f16 MFMA ----
__global__ __launch_bounds__(256) void edge_msg_kernel(
    const unsigned short* __restrict__ Ph, const unsigned short* __restrict__ Qh,
    const float* __restrict__ posrel,
    const unsigned int* __restrict__ rcS,
    const float* __restrict__ w1c, const float* __restrict__ b1,
    const unsigned short* __restrict__ w2t,   // fp16 [128 n][128 k]
    const float* __restrict__ b2,
    float* __restrict__ msum)
{
    const int tid = threadIdx.x;
    const long e0 = (long)blockIdx.x * 256;
    const int l  = tid & 63;
    const int w  = tid >> 6;
    const int mr = l & 15;
    const int qd = l >> 4;
    const long ebase = e0 + w*64;

    const int aoff = ((mr >> 2) << 4) + (mr & 3);
    int ecol[4], erow[4];
    float edist[4];
    #pragma unroll
    for (int m = 0; m < 4; ++m) {
        const unsigned rc = rcS[ebase + aoff + m*4];
        erow[m] = (int)(rc >> 16); ecol[m] = (int)(rc & 0xffffu);
    }
    #pragma unroll
    for (int m = 0; m < 4; ++m) {
        const int c = ecol[m], r = erow[m];
        const float dx = posrel[c*3+0] - posrel[r*3+0];
        const float dy = posrel[c*3+1] - posrel[r*3+1];
        const float dz = posrel[c*3+2] - posrel[r*3+2];
        edist[m] = sqrtf(dx*dx + dy*dy + dz*dz);
    }

    unsigned rcv[16];
    {
        const uint4* rc4 = (const uint4*)&rcS[ebase + qd*16];
        #pragma unroll
        for (int i = 0; i < 4; ++i) {
            const uint4 v = rc4[i];
            rcv[i*4+0] = v.x >> 16; rcv[i*4+1] = v.y >> 16;
            rcv[i*4+2] = v.z >> 16; rcv[i*4+3] = v.w >> 16;
        }
    }

    // ---- phase 1: H fragments in packed fp16 (_Float16 ext-vector math) ----
    f16x8 afr[4][4];
    const float4* __restrict__ c1f4 = (const float4*)w1c;
    const float4* __restrict__ b1f4 = (const float4*)b1;
    const f16x8 z8 = {};
    #pragma unroll
    for (int kk = 0; kk < 4; ++kk) {
        const int kof = kk*32 + qd*8;
        const int kb4 = kof >> 2;
        const float4 c0  = c1f4[kb4],   c1v = c1f4[kb4+1];
        const float4 b0  = b1f4[kb4],   b1v = b1f4[kb4+1];
        f16x8 c8, b8;
        c8[0] = (_Float16)c0.x;  c8[1] = (_Float16)c0.y;
        c8[2] = (_Float16)c0.z;  c8[3] = (_Float16)c0.w;
        c8[4] = (_Float16)c1v.x; c8[5] = (_Float16)c1v.y;
        c8[6] = (_Float16)c1v.z; c8[7] = (_Float16)c1v.w;
        b8[0] = (_Float16)b0.x;  b8[1] = (_Float16)b0.y;
        b8[2] = (_Float16)b0.z;  b8[3] = (_Float16)b0.w;
        b8[4] = (_Float16)b1v.x; b8[5] = (_Float16)b1v.y;
        b8[6] = (_Float16)b1v.z; b8[7] = (_Float16)b1v.w;
        #pragma unroll
        for (int m = 0; m < 4; ++m) {
            union { u16x8 raw; f16x8 v; } pu, qu;
            pu.raw = *(const u16x8*)&Ph[(long)ecol[m]*HD + kof];
            qu.raw = *(const u16x8*)&Qh[(long)erow[m]*HD + kof];
            const _Float16 d16 = (_Float16)edist[m];
            f16x8 s = pu.v + qu.v + b8 + d16 * c8;
            afr[m][kk] = __builtin_elementwise_max(s, z8);
        }
    }

    const f16x8* __restrict__ w2tv = (const f16x8*)w2t;
    f16x8 bfr[4];
    #pragma unroll
    for (int kk = 0; kk < 4; ++kk)
        bfr[kk] = w2tv[(0*16 + mr)*16 + kk*4 + qd];

    #pragma unroll 1
    for (int t = 0; t < 8; ++t) {
        f16x8 bnext[4];
        if (t < 7) {
            #pragma unroll
            for (int kk = 0; kk < 4; ++kk)
                bnext[kk] = w2tv[((t+1)*16 + mr)*16 + kk*4 + qd];
        }
        const int colg = t*16 + mr;
        const float bb = b2[colg];

        f32x4 acc[4];
        #pragma unroll
        for (int m = 0; m < 4; ++m) acc[m] = (f32x4){0.f, 0.f, 0.f, 0.f};
        #pragma unroll
        for (int kk = 0; kk < 4; ++kk)
            #pragma unroll
            for (int m = 0; m < 4; ++m)
                acc[m] = __builtin_amdgcn_mfma_f32_16x16x32_f16(afr[m][kk], bfr[kk], acc[m], 0, 0, 0);

        int rprev = -1;
        float run = 0.f;
        #pragma unroll
        for (int m = 0; m < 4; ++m) {
            #pragma unroll
            for (int r4 = 0; r4 < 4; ++r4) {
                const int rw = (int)rcv[m*4 + r4];
                const float v = fmaxf(acc[m][r4] + bb, 0.f);
                if (rw != rprev) {
                    if (rprev >= 0) atomAdd(&msum[(long)rprev*HD + colg], run);
                    rprev = rw; run = v;
                } else {
                    run += v;
                }
            }
        }
        atomAdd(&msum[(long)rprev*HD + colg], run);

        #pragma unroll
        for (int kk = 0; kk < 4; ++kk) bfr[kk] = bnext[kk];
    }
}

// ---------------- ligand-masked per-graph sum: batch-sorted run aggregation --------------
__global__ __launch_bounds__(256) void gsum_kernel(
    const unsigned short* __restrict__ xhi, const unsigned short* __restrict__ xlo,
    const int* __restrict__ batch,
    const int* __restrict__ ntype, float* __restrict__ gsum)
{
    const int tid = threadIdx.x;
    const int cg = tid & 31;          // float4 col group
    const int ns = tid >> 5;          // node strip 0..7
    const int n0 = blockIdx.x * 512 + ns * 64;

    int bprev = -1;
    float4 run = make_float4(0.f, 0.f, 0.f, 0.f);
    for (int i = 0; i < 64; ++i) {
        const int n = n0 + i;
        if (ntype[n] != 1) continue;
        const int b = batch[n];
        const ushort4 h  = *(const ushort4*)&xhi[(long)n*HD + cg*4];
        const ushort4 lo = *(const ushort4*)&xlo[(long)n*HD + cg*4];
        float4 v;
        v.x = bf2f(h.x) + bf2f(lo.x);
        v.y = bf2f(h.y) + bf2f(lo.y);
        v.z = bf2f(h.z) + bf2f(lo.z);
        v.w = bf2f(h.w) + bf2f(lo.w);
        if (b != bprev) {
            if (bprev >= 0) {
                float* dst = &gsum[bprev*HD + cg*4];
                atomAdd(dst+0, run.x); atomAdd(dst+1, run.y);
                atomAdd(dst+2, run.z); atomAdd(dst+3, run.w);
            }
            bprev = b; run = v;
        } else {
            run.x += v.x; run.y += v.y; run.z += v.z; run.w += v.w;
        }
    }
    if (bprev >= 0) {
        float* dst = &gsum[bprev*HD + cg*4];
        atomAdd(dst+0, run.x); atomAdd(dst+1, run.y);
        atomAdd(dst+2, run.z); atomAdd(dst+3, run.w);
    }
}

// ---------------- readout ----------------
__global__ __launch_bounds__(128) void readout_kernel(
    const float* __restrict__ gsum, const float* __restrict__ lcnt,
    const float* __restrict__ w1, const float* __restrict__ b1,
    const float* __restrict__ w2, const float* __restrict__ b2,
    float* __restrict__ out)
{
    __shared__ float gs[HD];
    __shared__ float red[2];
    const int b = blockIdx.x, j = threadIdx.x;
    gs[j] = gsum[b*HD + j] / fmaxf(lcnt[b], 1.f);
    __syncthreads();
    float acc = b1[j];
    for (int k = 0; k < HD; ++k) acc += gs[k]*w1[k*HD + j];
    float hg = fmaxf(acc, 0.f) * w2[j];
    #pragma unroll
    for (int off = 32; off > 0; off >>= 1) hg += __shfl_down(hg, off, 64);
    if ((j & 63) == 0) red[j >> 6] = hg;
    __syncthreads();
    if (j == 0) out[b] = red[0] + red[1] + b2[0];
}

extern "C" void kernel_launch(void* const* d_in, const int* in_sizes, int n_in,
                              void* d_out, int out_size, void* d_ws, size_t ws_size,
                              hipStream_t stream)
{
    const float* pos   = (const float*)d_in[0];
    const int*   z     = (const int*)d_in[1];
    const int*   batch = (const int*)d_in[2];
    const int*   eidx  = (const int*)d_in[3];
    const int*   ntype = (const int*)d_in[4];
    const float* emb   = (const float*)d_in[5];
    const float* lin_w = (const float*)d_in[6];
    const float* lin_b = (const float*)d_in[7];
    const float* mw1   = (const float*)d_in[8];
    const float* mb1   = (const float*)d_in[9];
    const float* mw2   = (const float*)d_in[10];
    const float* mb2   = (const float*)d_in[11];
    const float* uw    = (const float*)d_in[12];
    const float* ub    = (const float*)d_in[13];
    const float* rw1   = (const float*)d_in[14];
    const float* rb1   = (const float*)d_in[15];
    const float* rw2   = (const float*)d_in[16];
    const float* rb2   = (const float*)d_in[17];

    const int* row = eidx;
    const int* col = eidx + NE;

    float* ws     = (float*)d_ws;
    float* csum   = ws + O_CSUM;
    float* ccnt   = ws + O_CCNT;
    float* lcnt   = ws + O_LCNT;
    float* gsum   = ws + O_GSUM;
    int*   degi   = (int*)(ws + O_DEGI);
    float* posrel = ws + O_POSREL;
    unsigned int* rcS = (unsigned int*)(ws + O_RC);
    unsigned short* xhi = (unsigned short*)(ws + O_XHI);
    unsigned short* xlo = (unsigned short*)(ws + O_XLO);
    unsigned short* Ph  = (unsigned short*)(ws + O_P);
    unsigned short* Qh  = (unsigned short*)(ws + O_Q);
    float* msum   = ws + O_MSUM;
    unsigned short* w2t  = (unsigned short*)(ws + O_W2T);
    unsigned short* w1th = (unsigned short*)(ws + O_W1TH);
    unsigned short* w1tl = (unsigned short*)(ws + O_W1TL);
    unsigned short* wuth = (unsigned short*)(ws + O_WUTH);
    unsigned short* wutl = (unsigned short*)(ws + O_WUTL);
    int* chunkSum = (int*)(ws + O_CHK);
    int* rowStart = (int*)xhi;           // alias xhi head pre-lin_in
    int* cnt      = (int*)xhi + NN;

    (void)hipMemsetAsync(ws, 0, (size_t)(O_DEGI + NN) * sizeof(float), stream);
    (void)hipMemsetAsync(cnt, 0, (size_t)NN * sizeof(int), stream);

    stats_kernel  <<<NN/256, 256, 0, stream>>>(pos, batch, ntype, csum, ccnt, lcnt);
    deg_kernel    <<<NE/256, 256, 0, stream>>>(row, degi);
    posrel_kernel <<<NN/256, 256, 0, stream>>>(pos, batch, csum, ccnt, posrel);
    scanA_kernel  <<<256, 256, 0, stream>>>(degi, chunkSum);
    scanB_kernel  <<<1, 256, 0, stream>>>(chunkSum);
    scanC_kernel  <<<256, 256, 0, stream>>>(degi, chunkSum, rowStart);
    scatter_kernel<<<NE/256, 256, 0, stream>>>(row, col, rowStart, cnt, rcS);
    wprep_kernel  <<<384, 256, 0, stream>>>(mw1, uw, mw2, w1th, w1tl, wuth, wutl, w2t);

    lin_in_gemm<<<NN/32, 256, 0, stream>>>(emb, posrel, z, lin_w, lin_b, xhi, xlo);

    for (int l = 0; l < NL; ++l) {
        const float* W1 = mw1 + (size_t)l*257*HD;
        pq_gemm<<<NN/64, 256, 0, stream>>>(xhi, xlo, w1th + (size_t)l*32768, w1tl + (size_t)l*32768, Ph, Qh);
        (void)hipMemsetAsync(msum, 0, (size_t)NN*HD*sizeof(float), stream);
        edge_msg_kernel<<<NE/256, 256, 0, stream>>>(Ph, Qh, posrel, rcS,
                                                    W1 + 256*HD, mb1 + l*HD,
                                                    w2t + (size_t)l*16384, mb2 + l*HD, msum);
        upd_gemm<<<NN/64, 256, 0, stream>>>(xhi, xlo, msum, degi,
                                            wuth + (size_t)l*32768, wutl + (size_t)l*32768,
                                            ub + l*HD);
    }

    gsum_kernel   <<<NN/512, 256, 0, stream>>>(xhi, xlo, batch, ntype, gsum);
    readout_kernel<<<NB, 128, 0, stream>>>(gsum, lcnt, rw1, rb1, rw2, rb2, (float*)d_out);
}